// Round 3
// baseline (560.976 us; speedup 1.0000x reference)
//
#include <hip/hip_runtime.h>

#define EPS 1e-5f
#define NRED 65536.0f   // B*H*W = 64*32*32
#define IMST 73984      // 34*34*64 halo image stride (elements)
#define PATCH 8704      // 136 px * 64 ci (swizzled, no pad)

typedef short bf16x8 __attribute__((ext_vector_type(8)));
typedef float f32x4 __attribute__((ext_vector_type(4)));
typedef unsigned short u16;

#define MFMA16(a, b, c) __builtin_amdgcn_mfma_f32_16x16x32_bf16(a, b, c, 0, 0, 0)
// XOR-swizzled LDS patch addressing: kills bank conflicts with zero padding.
#define SWZ(px, oct) ((px) * 64 + (((oct) ^ ((px) & 7)) * 8))

__device__ __forceinline__ u16 f2bf(float x) {  // RNE f32->bf16
  union { float f; unsigned u; } v; v.f = x;
  unsigned r = v.u + 0x7FFF + ((v.u >> 16) & 1);
  return (u16)(r >> 16);
}
__device__ __forceinline__ float bf2f(u16 h) {
  union { unsigned u; float f; } v; v.u = ((unsigned)h) << 16;
  return v.f;
}
__device__ __forceinline__ unsigned pk2(float a, float b) {
  return (unsigned)f2bf(a) | ((unsigned)f2bf(b) << 16);
}

// DPP row-shift reduce over 16-lane rows; sum valid in ln==15. Pure VALU.
template <int CTRL>
__device__ __forceinline__ float dpp_mov(float x) {
  int xi = __builtin_bit_cast(int, x);
  int r = __builtin_amdgcn_update_dpp(0, xi, CTRL, 0xF, 0xF, true);
  return __builtin_bit_cast(float, r);
}
__device__ __forceinline__ float row_reduce16(float x) {
  x += dpp_mov<0x111>(x);
  x += dpp_mov<0x112>(x);
  x += dpp_mov<0x114>(x);
  x += dpp_mov<0x118>(x);
  return x;
}

// ---- swizzled patch staging (4 rows x 34 cols x 64 ci) ----------------------
__device__ __forceinline__ void stage_mask(const u16* __restrict__ src,
                                           u16* __restrict__ shp, int tid, int R0) {
#pragma unroll
  for (int i = 0; i < 5; ++i) {
    int c = i * 256 + tid;
    if (i == 4 && tid >= 64) break;
    int px = c >> 3, oct = c & 7;
    int prow = px / 34, pcol = px - prow * 34;
    bool halo = (R0 + prow == 0) || (R0 + prow == 33) || (pcol == 0) || (pcol == 33);
    uint4 v = {0u, 0u, 0u, 0u};
    if (!halo) v = *(const uint4*)&src[(size_t)c * 8];
    *(uint4*)&shp[SWZ(px, oct)] = v;
  }
}

// Affine staging: h = t*s1[ci]+b1[ci] interior, 0 halo (renorm fused).
__device__ __forceinline__ void stage_affine(const u16* __restrict__ src,
                                             u16* __restrict__ shp, int tid, int R0,
                                             const float* __restrict__ stE) {
  const int oct0 = tid & 7;
  float s[8], bb[8];
#pragma unroll
  for (int j = 0; j < 8; ++j) { s[j] = stE[oct0 * 8 + j]; bb[j] = stE[64 + oct0 * 8 + j]; }
#pragma unroll
  for (int i = 0; i < 5; ++i) {
    int c = i * 256 + tid;
    if (i == 4 && tid >= 64) break;
    int px = c >> 3, oct = c & 7;
    int prow = px / 34, pcol = px - prow * 34;
    bool halo = (R0 + prow == 0) || (R0 + prow == 33) || (pcol == 0) || (pcol == 33);
    uint4 o = {0u, 0u, 0u, 0u};
    if (!halo) {
      uint4 u = *(const uint4*)&src[(size_t)c * 8];
      unsigned uv[4] = {u.x, u.y, u.z, u.w};
      unsigned rv[4];
#pragma unroll
      for (int p2 = 0; p2 < 4; ++p2) {
        float lo = bf2f((u16)(uv[p2] & 0xffff)) * s[p2 * 2] + bb[p2 * 2];
        float hi = bf2f((u16)(uv[p2] >> 16)) * s[p2 * 2 + 1] + bb[p2 * 2 + 1];
        rv[p2] = pk2(lo, hi);
      }
      o.x = rv[0]; o.y = rv[1]; o.z = rv[2]; o.w = rv[3];
    }
    *(uint4*)&shp[SWZ(px, oct)] = o;
  }
}

// st layout: per edge e at st+e*2048: [0,64) s1 | [64,128) b1 | [128,192) bias2.

__global__ void pack_wT1_k(const float* __restrict__ w0, const float* __restrict__ w1,
                           const float* __restrict__ w2, const float* __restrict__ w3,
                           u16* __restrict__ wT1) {
  int e = blockIdx.x / 9, tap = blockIdx.x % 9;
  const float* w = e == 0 ? w0 : e == 1 ? w1 : e == 2 ? w2 : w3;
  u16* dst = wT1 + e * 36864 + tap * 4096;
  for (int idx = threadIdx.x; idx < 4096; idx += 256) {
    int co = idx >> 6, ci = idx & 63;
    dst[idx] = f2bf(w[(co * 64 + ci) * 9 + tap]);
  }
}

// wG64[e][g*8+tap(0..7)][co64][cig8] and wT8[e][g][co64][cig8] (tap 8)
__global__ void pack_wG_k(const float* __restrict__ w0, const float* __restrict__ w1,
                          const float* __restrict__ w2, const float* __restrict__ w3,
                          u16* __restrict__ wG64, u16* __restrict__ wT8) {
  int e = blockIdx.y;
  const float* w = e == 0 ? w0 : e == 1 ? w1 : e == 2 ? w2 : w3;
  int bx = blockIdx.x;  // 0..71
  int g, tap;
  u16* dst;
  if (bx < 64) { g = bx >> 3; tap = bx & 7; dst = wG64 + e * 32768 + bx * 512; }
  else         { g = bx - 64; tap = 8;      dst = wT8 + e * 4096 + g * 512; }
  for (int idx = threadIdx.x; idx < 512; idx += 256) {
    int co = idx >> 3, cig = idx & 7;
    dst[idx] = f2bf(w[(co * 64 + g * 8 + cig) * 9 + tap]);
  }
}

// x (NCHW f32) -> xT = bf16(relu(x)) halo pixel-major (interior only).
__global__ __launch_bounds__(256) void transpose_k(const float* __restrict__ x,
                                                   u16* __restrict__ xT) {
  __shared__ __align__(16) u16 sh[64 * 72];
  const int tid = threadIdx.x;
  const int b = blockIdx.x >> 4, slab = blockIdx.x & 15;
  const int ln = tid & 63, w = tid >> 6;
  const float* xb = x + (size_t)b * 65536 + slab * 64;
#pragma unroll
  for (int i = 0; i < 16; ++i) {
    int ci = w + i * 4;
    float v = xb[ci * 1024 + ln];
    sh[ln * 72 + ci] = f2bf(fmaxf(v, 0.f));
  }
  __syncthreads();
  u16* dst = xT + (size_t)b * IMST;
#pragma unroll
  for (int j = 0; j < 2; ++j) {
    int idx = tid + j * 256;
    int p = idx >> 3, oct = idx & 7;
    int gp = slab * 64 + p;
    int R = gp >> 5, C = gp & 31;
    *(uint4*)&dst[((R + 1) * 34 + C + 1) * 64 + oct * 8] = *(const uint4*)&sh[p * 72 + oct * 8];
  }
}

// zero halo strips of n1T (pool reads raw global n1T incl. halo).
__global__ void zero_halo_k(u16* __restrict__ buf) {
  int b = blockIdx.x, tid = threadIdx.x;
  if (tid >= 132) return;
  int R, C;
  if (tid < 34) { R = 0; C = tid; }
  else if (tid < 68) { R = 33; C = tid - 34; }
  else if (tid < 100) { R = tid - 67; C = 0; }
  else { R = tid - 99; C = 33; }
  u16* p = buf + (size_t)b * IMST + (size_t)(R * 34 + C) * 64;
  uint4 z = {0u, 0u, 0u, 0u};
#pragma unroll
  for (int i = 0; i < 8; ++i) *(uint4*)&p[i * 8] = z;
}

// ---------------- convA (2-edge batched): t = conv3x3(xin, W1) + stats -------
__global__ __launch_bounds__(256, 2) void convA_k(const u16* __restrict__ in0,
                                                  const u16* __restrict__ in1,
                                                  const u16* __restrict__ wTa,
                                                  const u16* __restrict__ wTb,
                                                  u16* __restrict__ t0,
                                                  u16* __restrict__ t1,
                                                  float* __restrict__ pA) {
  __shared__ __align__(16) u16 shp[PATCH];
  __shared__ float sA[64], qA[64];
  const int tid = threadIdx.x;
  const int b = blockIdx.y, R0 = blockIdx.x * 2, z = blockIdx.z;
  const u16* xin = z ? in1 : in0;
  const u16* wT = z ? wTb : wTa;
  u16* t = z ? t1 : t0;
  if (tid < 64) { sA[tid] = 0.f; qA[tid] = 0.f; }
  stage_mask(xin + (size_t)b * IMST + (size_t)R0 * 2176, shp, tid, R0);
  const int lane = tid & 63, w = tid >> 6;
  const int ln = lane & 15, quad = lane >> 4;
  const int lr = w >> 1, mh = w & 1;
  bf16x8 A[9][2][2];
#pragma unroll
  for (int tap = 0; tap < 9; ++tap)
#pragma unroll
    for (int m2 = 0; m2 < 2; ++m2)
#pragma unroll
      for (int h = 0; h < 2; ++h)
        A[tap][m2][h] = *(const bf16x8*)&wT[(size_t)((tap * 64 + (mh * 2 + m2) * 16 + ln) * 64) + h * 32 + quad * 8];
  __syncthreads();
  f32x4 acc[2][2];
#pragma unroll
  for (int m2 = 0; m2 < 2; ++m2)
#pragma unroll
    for (int nf = 0; nf < 2; ++nf) acc[m2][nf] = (f32x4){0.f, 0.f, 0.f, 0.f};
#pragma unroll
  for (int tap = 0; tap < 9; ++tap) {
    const int dy = tap / 3, dx = tap % 3;
    const int px0 = (lr + dy) * 34 + ln + dx;
#pragma unroll
    for (int h = 0; h < 2; ++h) {
      const int oct = h * 4 + quad;
      bf16x8 b0 = *(const bf16x8*)&shp[SWZ(px0, oct)];
      bf16x8 b1 = *(const bf16x8*)&shp[SWZ(px0 + 16, oct)];
      acc[0][0] = MFMA16(A[tap][0][h], b0, acc[0][0]);
      acc[0][1] = MFMA16(A[tap][0][h], b1, acc[0][1]);
      acc[1][0] = MFMA16(A[tap][1][h], b0, acc[1][0]);
      acc[1][1] = MFMA16(A[tap][1][h], b1, acc[1][1]);
    }
  }
  const int R = R0 + lr;
#pragma unroll
  for (int m2 = 0; m2 < 2; ++m2) {
    const int cob = (mh * 2 + m2) * 16 + quad * 4;
#pragma unroll
    for (int nf = 0; nf < 2; ++nf) {
      u16* tb = t + (size_t)b * IMST + (size_t)((R + 1) * 34 + nf * 16 + ln + 1) * 64 + cob;
      uint2 pk;
      pk.x = pk2(acc[m2][nf][0], acc[m2][nf][1]);
      pk.y = pk2(acc[m2][nf][2], acc[m2][nf][3]);
      *(uint2*)tb = pk;
    }
#pragma unroll
    for (int r = 0; r < 4; ++r) {
      float v0 = acc[m2][0][r], v1 = acc[m2][1][r];
      float s = row_reduce16(v0) + row_reduce16(v1);
      float q = row_reduce16(v0 * v0) + row_reduce16(v1 * v1);
      if (ln == 15) {
        atomicAdd(&sA[cob + r], s);
        atomicAdd(&qA[cob + r], q);
      }
    }
  }
  __syncthreads();
  const int blk = z * 1024 + blockIdx.y * 16 + blockIdx.x;
  if (tid < 64) pA[blk * 128 + tid] = sA[tid];
  else if (tid < 128) pA[blk * 128 + tid] = qA[tid - 64];
}

// reducerA (batched): grid (64, 2); writes s1/b1 into stBase + z*2048.
__global__ __launch_bounds__(256) void reducerA_k(const float* __restrict__ pA,
                                                  const float* __restrict__ a1,
                                                  float* __restrict__ stBase) {
  const int tid = threadIdx.x, c = blockIdx.x, z = blockIdx.y;
  const float* pAe = pA + (size_t)z * 1024 * 128;
  float s = 0.f, q = 0.f;
  for (int i = tid; i < 1024; i += 256) {
    s += pAe[i * 128 + c];
    q += pAe[i * 128 + 64 + c];
  }
#pragma unroll
  for (int off = 32; off; off >>= 1) { s += __shfl_xor(s, off); q += __shfl_xor(q, off); }
  __shared__ float red[8];
  int wv = tid >> 6;
  if ((tid & 63) == 0) { red[wv] = s; red[4 + wv] = q; }
  __syncthreads();
  if (tid == 0) {
    float S = red[0] + red[1] + red[2] + red[3];
    float Q = red[4] + red[5] + red[6] + red[7];
    int g = c >> 3;
    float m = 0.f;
    for (int i = g; i < 8; ++i) m += a1[i];
    float mu = S * (1.f / NRED);
    float var = Q * (1.f / NRED) - mu * mu;
    float r = rsqrtf(var + EPS);
    float* stE = stBase + z * 2048;
    stE[c] = r * m;
    stE[64 + c] = -mu * r * m;
  }
}

// ---------------- convC: weights direct from L2, barrier-free coq loop -------
// grid (16, 64, 2): z = edge. Patch staged once (only barrier); per-lane MFMA
// A-fragments read straight from global each coq (wG 36KB/edge is L2-resident,
// shared by 1024 blocks). No shA, no restage, no inner barriers: waves proceed
// through all 4 coqs independently so memory stalls de-correlate. LDS 21.5KB.
__global__ __launch_bounds__(256, 5) void convC_k(const u16* __restrict__ t0,
                                                  const u16* __restrict__ t1,
                                                  const u16* __restrict__ wG64,
                                                  const u16* __restrict__ wT8,
                                                  const float* __restrict__ stBase,
                                                  float* __restrict__ pC) {
  __shared__ __align__(16) u16 shp[PATCH];        // 17408 B
  __shared__ float sC[4][128], qC[4][128];        // 4096 B
  const int tid = threadIdx.x;
  const int b = blockIdx.y, R0 = blockIdx.x * 2;
  const int edge = blockIdx.z;
  const u16* t = edge ? t1 : t0;
  const float* stE = stBase + edge * 2048;
  {
    float* scf = (float*)sC;
    float* qcf = (float*)qC;
#pragma unroll
    for (int i = 0; i < 2; ++i) { scf[i * 256 + tid] = 0.f; qcf[i * 256 + tid] = 0.f; }
  }
  stage_affine(t + (size_t)b * IMST + (size_t)R0 * 2176, shp, tid, R0, stE);
  __syncthreads();
  const int lane = tid & 63, w = tid >> 6;
  const int ln = lane & 15, quad = lane >> 4;
  const int lrow = w >> 1, colbase = (w & 1) * 16;
  // per-lane weight bases: wG64 elem ((g*8+ch*4+quad)*64 + coq*16+ln)*8
  const u16* wq = wG64 + (size_t)edge * 32768 + (size_t)quad * 512 + (size_t)ln * 8;
  const u16* wq8 = wT8 + (size_t)edge * 4096 + (size_t)ln * 8;
  int px[3];
#pragma unroll
  for (int ch = 0; ch < 3; ++ch) {
    int tp = ch * 4 + quad; if (tp > 8) tp = 8;
    px[ch] = (lrow + tp / 3) * 34 + colbase + ln + tp % 3;
  }
#pragma unroll 1
  for (int coq = 0; coq < 4; ++coq) {
    const u16* wqc = wq + (size_t)coq * 128;   // + coq*16 co
    const u16* wq8c = wq8 + (size_t)coq * 128;
    f32x4 acc[8];
#pragma unroll
    for (int g = 0; g < 8; ++g) acc[g] = (f32x4){0.f, 0.f, 0.f, 0.f};
#pragma unroll
    for (int g = 0; g < 8; ++g) {
#pragma unroll
      for (int ch = 0; ch < 3; ++ch) {
        bf16x8 bx = *(const bf16x8*)&shp[SWZ(px[ch], g)];
        bf16x8 aw;
        if (ch < 2) {
          aw = *(const bf16x8*)&wqc[(size_t)(g * 8 + ch * 4) * 512];
        } else {
          aw = (bf16x8){0, 0, 0, 0, 0, 0, 0, 0};
          if (quad == 0) aw = *(const bf16x8*)&wq8c[(size_t)g * 512];
        }
        acc[g] = MFMA16(aw, bx, acc[g]);
      }
    }
    f32x4 P = (f32x4){0.f, 0.f, 0.f, 0.f};
#pragma unroll
    for (int k = 0; k < 8; ++k) {
      P += acc[k];
#pragma unroll
      for (int r = 0; r < 4; ++r) {
        float v = P[r];
        float s = row_reduce16(v);
        float q = row_reduce16(v * v);
        if (ln == 15) {
          atomicAdd(&sC[coq][k * 16 + quad * 4 + r], s);
          atomicAdd(&qC[coq][k * 16 + quad * 4 + r], q);
        }
      }
    }
  }
  __syncthreads();
  const int blk = blockIdx.y * 16 + blockIdx.x;
#pragma unroll 1
  for (int coq = 0; coq < 4; ++coq) {
    const size_t base = ((size_t)(edge * 4 + coq) * 1024 + blk) * 256;
    if (tid < 128) pC[base + tid] = sC[coq][tid];
    else pC[base + 128 + (tid - 128)] = qC[coq][tid - 128];
  }
}

// redCprepE (batched): grid (64, 2): c, z(edge). finalizeC + fold g -> wE.
__global__ __launch_bounds__(256) void redCprepE_k(const float* __restrict__ pC,
                                                   const float* __restrict__ w2a,
                                                   const float* __restrict__ w2b,
                                                   const float* __restrict__ a1,
                                                   const float* __restrict__ a2,
                                                   float* __restrict__ stBase,
                                                   u16* __restrict__ wEbase,
                                                   float* __restrict__ cm) {
  const int tid = threadIdx.x, c = blockIdx.x, z = blockIdx.y;
  const int coq = c >> 4, cl = c & 15;
  const float* w2 = z ? w2b : w2a;
  float* stE = stBase + z * 2048;
  u16* wE = wEbase + z * 36864;
  float s[8], q[8];
#pragma unroll
  for (int k = 0; k < 8; ++k) { s[k] = 0.f; q[k] = 0.f; }
  for (int i = tid; i < 1024; i += 256) {
    const float* pb = pC + ((size_t)(z * 4 + coq) * 1024 + i) * 256;
#pragma unroll
    for (int k = 0; k < 8; ++k) {
      s[k] += pb[k * 16 + cl];
      q[k] += pb[128 + k * 16 + cl];
    }
  }
#pragma unroll
  for (int k = 0; k < 8; ++k) {
#pragma unroll
    for (int off = 32; off; off >>= 1) { s[k] += __shfl_xor(s[k], off); q[k] += __shfl_xor(q[k], off); }
  }
  __shared__ float red[4][16];
  __shared__ float gL[8];
  int wv = tid >> 6;
  if ((tid & 63) == 0) {
#pragma unroll
    for (int k = 0; k < 8; ++k) { red[wv][k * 2] = s[k]; red[wv][k * 2 + 1] = q[k]; }
  }
  __syncthreads();
  if (tid == 0) {
    float suf = 0.f, bias = 0.f;
    for (int k = 7; k >= 0; --k) {
      float S = red[0][k * 2] + red[1][k * 2] + red[2][k * 2] + red[3][k * 2];
      float Q = red[0][k * 2 + 1] + red[1][k * 2 + 1] + red[2][k * 2 + 1] + red[3][k * 2 + 1];
      float mu = S * (1.f / NRED);
      float var = Q * (1.f / NRED) - mu * mu;
      float rr = rsqrtf(var + EPS);
      bias -= a2[k] * mu * rr;
      suf += a2[k] * rr;
      gL[k] = suf;
    }
    stE[128 + c] = bias;
    if (z == 0) {
      int g = c >> 3;
      float m1 = 0.f, m2 = 0.f;
      for (int i = g; i < 8; ++i) { m1 += a1[i]; m2 += a2[i]; }
      cm[c] = m1 * m2;
    }
  }
  __syncthreads();
  for (int idx = tid; idx < 576; idx += 256) {
    int tap = idx >> 6, ci = idx & 63;
    wE[(tap * 64 + c) * 64 + ci] = f2bf(w2[(c * 64 + ci) * 9 + tap] * gL[ci >> 3]);
  }
}

// ---------------- convE (modes 0,1): conv2 + epilogue ------------------------
template <int MODE>
__global__ __launch_bounds__(256, 2) void convE_k(const u16* __restrict__ t,
                                                  const float* __restrict__ stE,
                                                  const u16* __restrict__ wEp,
                                                  u16* __restrict__ d1,
                                                  u16* __restrict__ d2,
                                                  const float* __restrict__ cm) {
  __shared__ __align__(16) u16 shp[PATCH];
  __shared__ float cmL[64], biasL[64];
  const int tid = threadIdx.x;
  const int b = blockIdx.y, R0 = blockIdx.x * 2;
  if (tid < 64) { cmL[tid] = cm[tid]; biasL[tid] = stE[128 + tid]; }
  stage_affine(t + (size_t)b * IMST + (size_t)R0 * 2176, shp, tid, R0, stE);
  const int lane = tid & 63, w = tid >> 6;
  const int ln = lane & 15, quad = lane >> 4;
  const int lr = w >> 1, mh = w & 1;
  bf16x8 A[9][2][2];
#pragma unroll
  for (int tap = 0; tap < 9; ++tap)
#pragma unroll
    for (int m2 = 0; m2 < 2; ++m2)
#pragma unroll
      for (int h = 0; h < 2; ++h)
        A[tap][m2][h] = *(const bf16x8*)&wEp[(size_t)((tap * 64 + (mh * 2 + m2) * 16 + ln) * 64) + h * 32 + quad * 8];
  __syncthreads();
  f32x4 acc[2][2];
#pragma unroll
  for (int m2 = 0; m2 < 2; ++m2)
#pragma unroll
    for (int nf = 0; nf < 2; ++nf) acc[m2][nf] = (f32x4){0.f, 0.f, 0.f, 0.f};
#pragma unroll
  for (int tap = 0; tap < 9; ++tap) {
    const int dy = tap / 3, dx = tap % 3;
    const int px0 = (lr + dy) * 34 + ln + dx;
#pragma unroll
    for (int h = 0; h < 2; ++h) {
      const int oct = h * 4 + quad;
      bf16x8 b0 = *(const bf16x8*)&shp[SWZ(px0, oct)];
      bf16x8 b1 = *(const bf16x8*)&shp[SWZ(px0 + 16, oct)];
      acc[0][0] = MFMA16(A[tap][0][h], b0, acc[0][0]);
      acc[0][1] = MFMA16(A[tap][0][h], b1, acc[0][1]);
      acc[1][0] = MFMA16(A[tap][1][h], b0, acc[1][0]);
      acc[1][1] = MFMA16(A[tap][1][h], b1, acc[1][1]);
    }
  }
  const int R = R0 + lr;
#pragma unroll
  for (int m2 = 0; m2 < 2; ++m2) {
    const int cob = (mh * 2 + m2) * 16 + quad * 4;
#pragma unroll
    for (int nf = 0; nf < 2; ++nf) {
      const int C = nf * 16 + ln;
      const size_t haloPx = (size_t)b * IMST + (size_t)((R + 1) * 34 + C + 1) * 64 + cob;
      float v[4];
#pragma unroll
      for (int r = 0; r < 4; ++r) v[r] = acc[m2][nf][r] + biasL[cob + r];
      if (MODE == 0) {
        uint2 pk, pkr;
        pk.x = pk2(v[0], v[1]); pk.y = pk2(v[2], v[3]);
        pkr.x = pk2(fmaxf(v[0], 0.f), fmaxf(v[1], 0.f));
        pkr.y = pk2(fmaxf(v[2], 0.f), fmaxf(v[3], 0.f));
        *(uint2*)&d1[haloPx] = pk;    // n1T (raw, for pool)
        *(uint2*)&d2[haloPx] = pkr;   // n1r (relu, e2 input)
      } else {
        float ps[4] = {0.f, 0.f, 0.f, 0.f};
        const size_t pb2 = (size_t)b * IMST + (size_t)(R * 34 + C) * 64 + cob;
#pragma unroll
        for (int dy = 0; dy < 3; ++dy)
#pragma unroll
          for (int dx = 0; dx < 3; ++dx) {
            uint2 u = *(const uint2*)&d2[pb2 + (size_t)(dy * 34 + dx) * 64];  // n1T
            ps[0] += bf2f((u16)(u.x & 0xffff));
            ps[1] += bf2f((u16)(u.x >> 16));
            ps[2] += bf2f((u16)(u.y & 0xffff));
            ps[3] += bf2f((u16)(u.y >> 16));
          }
        float rows = 3.f - (R == 0 ? 1.f : 0.f) - (R == 31 ? 1.f : 0.f);
        float cols = 3.f - (C == 0 ? 1.f : 0.f) - (C == 31 ? 1.f : 0.f);
        float inv = 1.f / (rows * cols);
        uint2 pkr;
        float t0v = fmaxf(v[0] + ps[0] * inv * cmL[cob], 0.f);
        float t1v = fmaxf(v[1] + ps[1] * inv * cmL[cob + 1], 0.f);
        float t2v = fmaxf(v[2] + ps[2] * inv * cmL[cob + 2], 0.f);
        float t3v = fmaxf(v[3] + ps[3] * inv * cmL[cob + 3], 0.f);
        pkr.x = pk2(t0v, t1v); pkr.y = pk2(t2v, t3v);
        *(uint2*)&d1[haloPx] = pkr;   // n2r
      }
    }
  }
}

// ---------------- convE23: fused final two convs + output --------------------
__global__ __launch_bounds__(256, 2) void convE23_k(const u16* __restrict__ t0,
                                                    const u16* __restrict__ t1,
                                                    const float* __restrict__ stBase,
                                                    const u16* __restrict__ wE2,
                                                    const u16* __restrict__ wE3,
                                                    float* __restrict__ outp,
                                                    const float* __restrict__ x,
                                                    const float* __restrict__ cm) {
  __shared__ __align__(16) u16 shp2[2 * PATCH];
  __shared__ float cmL[64], biasL[64];
  const int tid = threadIdx.x;
  const int b = blockIdx.y, R0 = blockIdx.x * 2;
  if (tid < 64) {
    cmL[tid] = cm[tid];
    biasL[tid] = stBase[128 + tid] + stBase[2048 + 128 + tid];
  }
  stage_affine(t0 + (size_t)b * IMST + (size_t)R0 * 2176, shp2, tid, R0, stBase);
  stage_affine(t1 + (size_t)b * IMST + (size_t)R0 * 2176, shp2 + PATCH, tid, R0, stBase + 2048);
  __syncthreads();
  const int lane = tid & 63, w = tid >> 6;
  const int ln = lane & 15, quad = lane >> 4;
  const int lr = w >> 1, mh = w & 1;
  f32x4 acc[2][2];
#pragma unroll
  for (int m2 = 0; m2 < 2; ++m2)
#pragma unroll
    for (int nf = 0; nf < 2; ++nf) acc[m2][nf] = (f32x4){0.f, 0.f, 0.f, 0.f};
#pragma unroll 1
  for (int ei = 0; ei < 2; ++ei) {
    const u16* wEp = ei ? wE3 : wE2;
    const u16* sp = &shp2[ei * PATCH];
    bf16x8 A[9][2][2];
#pragma unroll
    for (int tap = 0; tap < 9; ++tap)
#pragma unroll
      for (int m2 = 0; m2 < 2; ++m2)
#pragma unroll
        for (int h = 0; h < 2; ++h)
          A[tap][m2][h] = *(const bf16x8*)&wEp[(size_t)((tap * 64 + (mh * 2 + m2) * 16 + ln) * 64) + h * 32 + quad * 8];
#pragma unroll
    for (int tap = 0; tap < 9; ++tap) {
      const int dy = tap / 3, dx = tap % 3;
      const int px0 = (lr + dy) * 34 + ln + dx;
#pragma unroll
      for (int h = 0; h < 2; ++h) {
        const int oct = h * 4 + quad;
        bf16x8 b0 = *(const bf16x8*)&sp[SWZ(px0, oct)];
        bf16x8 b1 = *(const bf16x8*)&sp[SWZ(px0 + 16, oct)];
        acc[0][0] = MFMA16(A[tap][0][h], b0, acc[0][0]);
        acc[0][1] = MFMA16(A[tap][0][h], b1, acc[0][1]);
        acc[1][0] = MFMA16(A[tap][1][h], b0, acc[1][0]);
        acc[1][1] = MFMA16(A[tap][1][h], b1, acc[1][1]);
      }
    }
  }
  const int R = R0 + lr;
#pragma unroll
  for (int m2 = 0; m2 < 2; ++m2) {
    const int cob = (mh * 2 + m2) * 16 + quad * 4;
#pragma unroll
    for (int nf = 0; nf < 2; ++nf) {
      const int C = nf * 16 + ln;
      size_t base = (size_t)b * 65536 + (size_t)cob * 1024 + R * 32 + C;
#pragma unroll
      for (int r = 0; r < 4; ++r)
        outp[base + (size_t)r * 1024] =
            acc[m2][nf][r] + biasL[cob + r] + x[base + (size_t)r * 1024] * cmL[cob + r];
    }
  }
}

extern "C" void kernel_launch(void* const* d_in, const int* in_sizes, int n_in,
                              void* d_out, int out_size, void* d_ws, size_t ws_size,
                              hipStream_t stream) {
  const float* x  = (const float*)d_in[0];
  const float* a1 = (const float*)d_in[1];
  const float* a2 = (const float*)d_in[2];
  const float* W1[4] = {(const float*)d_in[3], (const float*)d_in[5],
                        (const float*)d_in[7], (const float*)d_in[9]};
  const float* W2[4] = {(const float*)d_in[4], (const float*)d_in[6],
                        (const float*)d_in[8], (const float*)d_in[10]};
  float* out = (float*)d_out;
  char* ws = (char*)d_ws;
  const size_t HB = (size_t)IMST * 64 * 2;  // 9,469,952 B per halo buffer
  u16* xT  = (u16*)ws;
  u16* t0  = (u16*)(ws + HB);
  u16* t1  = (u16*)(ws + 2 * HB);
  u16* n1T = (u16*)(ws + 3 * HB);
  u16* n1r = (u16*)(ws + 4 * HB);
  u16* n2r = (u16*)(ws + 5 * HB);
  char* p = ws + 6 * HB;
  float* st  = (float*)p;            p += 8256 * 4;
  u16* wT1   = (u16*)p;              p += 4 * 36864 * 2;
  u16* wG64  = (u16*)p;              p += 4 * 32768 * 2;
  u16* wT8   = (u16*)p;              p += 4 * 4096 * 2;
  u16* wE    = (u16*)p;              p += 4 * 36864 * 2;
  float* pA  = (float*)p;            p += 2 * 1024 * 128 * 4;
  float* pC  = (float*)p;            // 8 * 1024 * 256 * 4 = 8 MB
  float* cm  = st + 8192;

  pack_wT1_k<<<36, 256, 0, stream>>>(W1[0], W1[1], W1[2], W1[3], wT1);
  pack_wG_k<<<dim3(72, 4), 256, 0, stream>>>(W2[0], W2[1], W2[2], W2[3], wG64, wT8);
  transpose_k<<<1024, 256, 0, stream>>>(x, xT);
  zero_halo_k<<<64, 160, 0, stream>>>(n1T);

  dim3 gA(16, 64, 2), gC(16, 64, 2), gE(16, 64);
  // batch edges 0+1 (both consume xT)
  convA_k<<<gA, 256, 0, stream>>>(xT, xT, wT1, wT1 + 36864, t0, t1, pA);
  reducerA_k<<<dim3(64, 2), 256, 0, stream>>>(pA, a1, st);
  convC_k<<<gC, 256, 0, stream>>>(t0, t1, wG64, wT8, st, pC);
  redCprepE_k<<<dim3(64, 2), 256, 0, stream>>>(pC, W2[0], W2[1], a1, a2, st, wE, cm);
  convE_k<0><<<gE, 256, 0, stream>>>(t0, st, wE, n1T, n1r, cm);
  convE_k<1><<<gE, 256, 0, stream>>>(t1, st + 2048, wE + 36864, n2r, n1T, cm);
  // batch edges 2+3 (consume n1r, n2r)
  convA_k<<<gA, 256, 0, stream>>>(n1r, n2r, wT1 + 2 * 36864, wT1 + 3 * 36864, t0, t1, pA);
  reducerA_k<<<dim3(64, 2), 256, 0, stream>>>(pA, a1, st + 4096);
  convC_k<<<gC, 256, 0, stream>>>(t0, t1, wG64 + 2 * 32768, wT8 + 2 * 4096, st + 4096, pC);
  redCprepE_k<<<dim3(64, 2), 256, 0, stream>>>(pC, W2[2], W2[3], a1, a2, st + 4096,
                                               wE + 2 * 36864, cm);
  convE23_k<<<gE, 256, 0, stream>>>(t0, t1, st + 4096, wE + 2 * 36864, wE + 3 * 36864,
                                    out, x, cm);
}

// Round 4
// 495.452 us; speedup vs baseline: 1.1323x; 1.1323x over previous
//
#include <hip/hip_runtime.h>

#define EPS 1e-5f
#define NRED 65536.0f   // B*H*W = 64*32*32
#define IMST 73984      // 34*34*64 halo image stride (elements)
#define PATCH 8704      // 136 px * 64 ci (swizzled, no pad)

typedef short bf16x8 __attribute__((ext_vector_type(8)));
typedef float f32x4 __attribute__((ext_vector_type(4)));
typedef unsigned short u16;

#define MFMA16(a, b, c) __builtin_amdgcn_mfma_f32_16x16x32_bf16(a, b, c, 0, 0, 0)
// XOR-swizzled LDS patch addressing: kills bank conflicts with zero padding.
#define SWZ(px, oct) ((px) * 64 + (((oct) ^ ((px) & 7)) * 8))

__device__ __forceinline__ u16 f2bf(float x) {  // RNE f32->bf16
  union { float f; unsigned u; } v; v.f = x;
  unsigned r = v.u + 0x7FFF + ((v.u >> 16) & 1);
  return (u16)(r >> 16);
}
__device__ __forceinline__ float bf2f(u16 h) {
  union { unsigned u; float f; } v; v.u = ((unsigned)h) << 16;
  return v.f;
}
__device__ __forceinline__ unsigned pk2(float a, float b) {
  return (unsigned)f2bf(a) | ((unsigned)f2bf(b) << 16);
}

// DPP row-shift reduce over 16-lane rows; sum valid in ln==15. Pure VALU.
template <int CTRL>
__device__ __forceinline__ float dpp_mov(float x) {
  int xi = __builtin_bit_cast(int, x);
  int r = __builtin_amdgcn_update_dpp(0, xi, CTRL, 0xF, 0xF, true);
  return __builtin_bit_cast(float, r);
}
__device__ __forceinline__ float row_reduce16(float x) {
  x += dpp_mov<0x111>(x);
  x += dpp_mov<0x112>(x);
  x += dpp_mov<0x114>(x);
  x += dpp_mov<0x118>(x);
  return x;
}

// ---- swizzled patch staging (4 rows x 34 cols x 64 ci) ----------------------
__device__ __forceinline__ void stage_mask(const u16* __restrict__ src,
                                           u16* __restrict__ shp, int tid, int R0) {
#pragma unroll
  for (int i = 0; i < 5; ++i) {
    int c = i * 256 + tid;
    if (i == 4 && tid >= 64) break;
    int px = c >> 3, oct = c & 7;
    int prow = px / 34, pcol = px - prow * 34;
    bool halo = (R0 + prow == 0) || (R0 + prow == 33) || (pcol == 0) || (pcol == 33);
    uint4 v = {0u, 0u, 0u, 0u};
    if (!halo) v = *(const uint4*)&src[(size_t)c * 8];
    *(uint4*)&shp[SWZ(px, oct)] = v;
  }
}

// Affine staging: h = t*s1[ci]+b1[ci] interior, 0 halo (renorm fused).
__device__ __forceinline__ void stage_affine(const u16* __restrict__ src,
                                             u16* __restrict__ shp, int tid, int R0,
                                             const float* __restrict__ stE) {
  const int oct0 = tid & 7;
  float s[8], bb[8];
#pragma unroll
  for (int j = 0; j < 8; ++j) { s[j] = stE[oct0 * 8 + j]; bb[j] = stE[64 + oct0 * 8 + j]; }
#pragma unroll
  for (int i = 0; i < 5; ++i) {
    int c = i * 256 + tid;
    if (i == 4 && tid >= 64) break;
    int px = c >> 3, oct = c & 7;
    int prow = px / 34, pcol = px - prow * 34;
    bool halo = (R0 + prow == 0) || (R0 + prow == 33) || (pcol == 0) || (pcol == 33);
    uint4 o = {0u, 0u, 0u, 0u};
    if (!halo) {
      uint4 u = *(const uint4*)&src[(size_t)c * 8];
      unsigned uv[4] = {u.x, u.y, u.z, u.w};
      unsigned rv[4];
#pragma unroll
      for (int p2 = 0; p2 < 4; ++p2) {
        float lo = bf2f((u16)(uv[p2] & 0xffff)) * s[p2 * 2] + bb[p2 * 2];
        float hi = bf2f((u16)(uv[p2] >> 16)) * s[p2 * 2 + 1] + bb[p2 * 2 + 1];
        rv[p2] = pk2(lo, hi);
      }
      o.x = rv[0]; o.y = rv[1]; o.z = rv[2]; o.w = rv[3];
    }
    *(uint4*)&shp[SWZ(px, oct)] = o;
  }
}

// st layout: per edge e at st+e*2048: [0,64) s1 | [64,128) b1 | [128,192) bias2.

__global__ void pack_wT1_k(const float* __restrict__ w0, const float* __restrict__ w1,
                           const float* __restrict__ w2, const float* __restrict__ w3,
                           u16* __restrict__ wT1) {
  int e = blockIdx.x / 9, tap = blockIdx.x % 9;
  const float* w = e == 0 ? w0 : e == 1 ? w1 : e == 2 ? w2 : w3;
  u16* dst = wT1 + e * 36864 + tap * 4096;
  for (int idx = threadIdx.x; idx < 4096; idx += 256) {
    int co = idx >> 6, ci = idx & 63;
    dst[idx] = f2bf(w[(co * 64 + ci) * 9 + tap]);
  }
}

// wG64[e][g*8+tap(0..7)][co64][cig8] and wT8[e][g][co64][cig8] (tap 8)
__global__ void pack_wG_k(const float* __restrict__ w0, const float* __restrict__ w1,
                          const float* __restrict__ w2, const float* __restrict__ w3,
                          u16* __restrict__ wG64, u16* __restrict__ wT8) {
  int e = blockIdx.y;
  const float* w = e == 0 ? w0 : e == 1 ? w1 : e == 2 ? w2 : w3;
  int bx = blockIdx.x;  // 0..71
  int g, tap;
  u16* dst;
  if (bx < 64) { g = bx >> 3; tap = bx & 7; dst = wG64 + e * 32768 + bx * 512; }
  else         { g = bx - 64; tap = 8;      dst = wT8 + e * 4096 + g * 512; }
  for (int idx = threadIdx.x; idx < 512; idx += 256) {
    int co = idx >> 3, cig = idx & 7;
    dst[idx] = f2bf(w[(co * 64 + g * 8 + cig) * 9 + tap]);
  }
}

// x (NCHW f32) -> xT = bf16(relu(x)) halo pixel-major (interior only).
__global__ __launch_bounds__(256) void transpose_k(const float* __restrict__ x,
                                                   u16* __restrict__ xT) {
  __shared__ __align__(16) u16 sh[64 * 72];
  const int tid = threadIdx.x;
  const int b = blockIdx.x >> 4, slab = blockIdx.x & 15;
  const int ln = tid & 63, w = tid >> 6;
  const float* xb = x + (size_t)b * 65536 + slab * 64;
#pragma unroll
  for (int i = 0; i < 16; ++i) {
    int ci = w + i * 4;
    float v = xb[ci * 1024 + ln];
    sh[ln * 72 + ci] = f2bf(fmaxf(v, 0.f));
  }
  __syncthreads();
  u16* dst = xT + (size_t)b * IMST;
#pragma unroll
  for (int j = 0; j < 2; ++j) {
    int idx = tid + j * 256;
    int p = idx >> 3, oct = idx & 7;
    int gp = slab * 64 + p;
    int R = gp >> 5, C = gp & 31;
    *(uint4*)&dst[((R + 1) * 34 + C + 1) * 64 + oct * 8] = *(const uint4*)&sh[p * 72 + oct * 8];
  }
}

// zero halo strips of n1T (pool reads raw global n1T incl. halo).
__global__ void zero_halo_k(u16* __restrict__ buf) {
  int b = blockIdx.x, tid = threadIdx.x;
  if (tid >= 132) return;
  int R, C;
  if (tid < 34) { R = 0; C = tid; }
  else if (tid < 68) { R = 33; C = tid - 34; }
  else if (tid < 100) { R = tid - 67; C = 0; }
  else { R = tid - 99; C = 33; }
  u16* p = buf + (size_t)b * IMST + (size_t)(R * 34 + C) * 64;
  uint4 z = {0u, 0u, 0u, 0u};
#pragma unroll
  for (int i = 0; i < 8; ++i) *(uint4*)&p[i * 8] = z;
}

// ---------------- convA (2-edge batched): t = conv3x3(xin, W1) + stats -------
__global__ __launch_bounds__(256, 2) void convA_k(const u16* __restrict__ in0,
                                                  const u16* __restrict__ in1,
                                                  const u16* __restrict__ wTa,
                                                  const u16* __restrict__ wTb,
                                                  u16* __restrict__ t0,
                                                  u16* __restrict__ t1,
                                                  float* __restrict__ pA) {
  __shared__ __align__(16) u16 shp[PATCH];
  __shared__ float sA[64], qA[64];
  const int tid = threadIdx.x;
  const int b = blockIdx.y, R0 = blockIdx.x * 2, z = blockIdx.z;
  const u16* xin = z ? in1 : in0;
  const u16* wT = z ? wTb : wTa;
  u16* t = z ? t1 : t0;
  if (tid < 64) { sA[tid] = 0.f; qA[tid] = 0.f; }
  stage_mask(xin + (size_t)b * IMST + (size_t)R0 * 2176, shp, tid, R0);
  const int lane = tid & 63, w = tid >> 6;
  const int ln = lane & 15, quad = lane >> 4;
  const int lr = w >> 1, mh = w & 1;
  bf16x8 A[9][2][2];
#pragma unroll
  for (int tap = 0; tap < 9; ++tap)
#pragma unroll
    for (int m2 = 0; m2 < 2; ++m2)
#pragma unroll
      for (int h = 0; h < 2; ++h)
        A[tap][m2][h] = *(const bf16x8*)&wT[(size_t)((tap * 64 + (mh * 2 + m2) * 16 + ln) * 64) + h * 32 + quad * 8];
  __syncthreads();
  f32x4 acc[2][2];
#pragma unroll
  for (int m2 = 0; m2 < 2; ++m2)
#pragma unroll
    for (int nf = 0; nf < 2; ++nf) acc[m2][nf] = (f32x4){0.f, 0.f, 0.f, 0.f};
#pragma unroll
  for (int tap = 0; tap < 9; ++tap) {
    const int dy = tap / 3, dx = tap % 3;
    const int px0 = (lr + dy) * 34 + ln + dx;
#pragma unroll
    for (int h = 0; h < 2; ++h) {
      const int oct = h * 4 + quad;
      bf16x8 b0 = *(const bf16x8*)&shp[SWZ(px0, oct)];
      bf16x8 b1 = *(const bf16x8*)&shp[SWZ(px0 + 16, oct)];
      acc[0][0] = MFMA16(A[tap][0][h], b0, acc[0][0]);
      acc[0][1] = MFMA16(A[tap][0][h], b1, acc[0][1]);
      acc[1][0] = MFMA16(A[tap][1][h], b0, acc[1][0]);
      acc[1][1] = MFMA16(A[tap][1][h], b1, acc[1][1]);
    }
  }
  const int R = R0 + lr;
#pragma unroll
  for (int m2 = 0; m2 < 2; ++m2) {
    const int cob = (mh * 2 + m2) * 16 + quad * 4;
#pragma unroll
    for (int nf = 0; nf < 2; ++nf) {
      u16* tb = t + (size_t)b * IMST + (size_t)((R + 1) * 34 + nf * 16 + ln + 1) * 64 + cob;
      uint2 pk;
      pk.x = pk2(acc[m2][nf][0], acc[m2][nf][1]);
      pk.y = pk2(acc[m2][nf][2], acc[m2][nf][3]);
      *(uint2*)tb = pk;
    }
#pragma unroll
    for (int r = 0; r < 4; ++r) {
      float v0 = acc[m2][0][r], v1 = acc[m2][1][r];
      float s = row_reduce16(v0) + row_reduce16(v1);
      float q = row_reduce16(v0 * v0) + row_reduce16(v1 * v1);
      if (ln == 15) {
        atomicAdd(&sA[cob + r], s);
        atomicAdd(&qA[cob + r], q);
      }
    }
  }
  __syncthreads();
  const int blk = z * 1024 + blockIdx.y * 16 + blockIdx.x;
  if (tid < 64) pA[blk * 128 + tid] = sA[tid];
  else if (tid < 128) pA[blk * 128 + tid] = qA[tid - 64];
}

// reducerA (batched): grid (64, 2); writes s1/b1 into stBase + z*2048.
__global__ __launch_bounds__(256) void reducerA_k(const float* __restrict__ pA,
                                                  const float* __restrict__ a1,
                                                  float* __restrict__ stBase) {
  const int tid = threadIdx.x, c = blockIdx.x, z = blockIdx.y;
  const float* pAe = pA + (size_t)z * 1024 * 128;
  float s = 0.f, q = 0.f;
  for (int i = tid; i < 1024; i += 256) {
    s += pAe[i * 128 + c];
    q += pAe[i * 128 + 64 + c];
  }
#pragma unroll
  for (int off = 32; off; off >>= 1) { s += __shfl_xor(s, off); q += __shfl_xor(q, off); }
  __shared__ float red[8];
  int wv = tid >> 6;
  if ((tid & 63) == 0) { red[wv] = s; red[4 + wv] = q; }
  __syncthreads();
  if (tid == 0) {
    float S = red[0] + red[1] + red[2] + red[3];
    float Q = red[4] + red[5] + red[6] + red[7];
    int g = c >> 3;
    float m = 0.f;
    for (int i = g; i < 8; ++i) m += a1[i];
    float mu = S * (1.f / NRED);
    float var = Q * (1.f / NRED) - mu * mu;
    float r = rsqrtf(var + EPS);
    float* stE = stBase + z * 2048;
    stE[c] = r * m;
    stE[64 + c] = -mu * r * m;
  }
}

// ---------------- convC: 8-row blocks, per-lane moment accumulation ----------
// grid (4, 64, 8): z -> edge = z>>2, coq = z&3. Block = 8 rows x 32 cols x 16 co,
// looping 4 row-pair tiles. shA staged ONCE (r3 lesson: weights must be in LDS).
// Stats: per-lane partial moments accumulated across tiles (12 vec-ops/k/tile),
// single DPP reduction at the end -> ~2.4x less stats VALU + shorter dep chains.
// Patch loads for tile tau+1 prefetched into regs during tile tau's compute.
__global__ __launch_bounds__(256, 3) void convC_k(const u16* __restrict__ t0,
                                                  const u16* __restrict__ t1,
                                                  const u16* __restrict__ wG64,
                                                  const u16* __restrict__ wT8,
                                                  const float* __restrict__ stBase,
                                                  float* __restrict__ pC) {
  __shared__ __align__(16) u16 shp[PATCH];        // 17408 B
  __shared__ __align__(16) u16 shA[64 * 16 * 8];  // 16384 B (one co-quarter)
  __shared__ __align__(16) u16 shA2[8 * 16 * 8];  // 2048 B
  __shared__ float sC[128], qC[128];              // 1024 B
  const int tid = threadIdx.x;
  const int b = blockIdx.y, R0 = blockIdx.x * 8;
  const int edge = blockIdx.z >> 2, coq = blockIdx.z & 3;
  const u16* t = edge ? t1 : t0;
  const float* stE = stBase + edge * 2048;
  const u16* wGe = wG64 + edge * 32768;
  const u16* wT8e = wT8 + edge * 4096;
  const u16* src = t + (size_t)b * IMST;
  if (tid < 128) { sC[tid] = 0.f; qC[tid] = 0.f; }
  // affine constants (per-thread oct)
  const int oct0 = tid & 7;
  float sc[8], bc[8];
#pragma unroll
  for (int j = 0; j < 8; ++j) { sc[j] = stE[oct0 * 8 + j]; bc[j] = stE[64 + oct0 * 8 + j]; }
  // prefetch tile 0 patch into regs
  uint4 ld[5];
  int hmask = 0;
#pragma unroll
  for (int i = 0; i < 5; ++i) {
    int c = i * 256 + tid;
    uint4 v = {0u, 0u, 0u, 0u};
    if (!(i == 4 && tid >= 64)) {
      int px = c >> 3;
      int prow = px / 34, pcol = px - prow * 34;
      bool halo = (R0 + prow == 0) || (R0 + prow == 33) || (pcol == 0) || (pcol == 33);
      if (!halo) v = *(const uint4*)&src[(size_t)(R0 * 2176) + (size_t)c * 8];
      if (halo) hmask |= 1 << i;
    } else hmask |= 1 << i;
    ld[i] = v;
  }
  // stage shA once: 1024 chunks [row64][co16][cig8]
#pragma unroll
  for (int i = 0; i < 4; ++i) {
    int c = i * 256 + tid;
    int row = c >> 4, col = c & 15;
    *(uint4*)&shA[c * 8] = *(const uint4*)&wGe[(size_t)(row * 64 + coq * 16 + col) * 8];
  }
  if (tid < 128) {  // shA2: 128 chunks [g8][co16][cig8]
    int g = tid >> 4, col = tid & 15;
    *(uint4*)&shA2[tid * 8] = *(const uint4*)&wT8e[(size_t)(g * 64 + coq * 16 + col) * 8];
  }
  const int lane = tid & 63, w = tid >> 6;
  const int ln = lane & 15, quad = lane >> 4;
  const int lrow = w >> 1, colbase = (w & 1) * 16;
  int px[3];
#pragma unroll
  for (int ch = 0; ch < 3; ++ch) {
    int tp = ch * 4 + quad; if (tp > 8) tp = 8;
    px[ch] = (lrow + tp / 3) * 34 + colbase + ln + tp % 3;
  }
  f32x4 sL[8], qL[8];
#pragma unroll
  for (int k = 0; k < 8; ++k) { sL[k] = (f32x4){0.f, 0.f, 0.f, 0.f}; qL[k] = (f32x4){0.f, 0.f, 0.f, 0.f}; }
#pragma unroll 1
  for (int tau = 0; tau < 4; ++tau) {
    // write-part: repack prefetched regs -> swizzled LDS patch
#pragma unroll
    for (int i = 0; i < 5; ++i) {
      if (i == 4 && tid >= 64) break;
      int c = i * 256 + tid;
      int ppx = c >> 3, oct = c & 7;
      uint4 o = {0u, 0u, 0u, 0u};
      if (!((hmask >> i) & 1)) {
        unsigned uv[4] = {ld[i].x, ld[i].y, ld[i].z, ld[i].w};
        unsigned rv[4];
#pragma unroll
        for (int p2 = 0; p2 < 4; ++p2) {
          float lo = bf2f((u16)(uv[p2] & 0xffff)) * sc[p2 * 2] + bc[p2 * 2];
          float hi = bf2f((u16)(uv[p2] >> 16)) * sc[p2 * 2 + 1] + bc[p2 * 2 + 1];
          rv[p2] = pk2(lo, hi);
        }
        o.x = rv[0]; o.y = rv[1]; o.z = rv[2]; o.w = rv[3];
      }
      *(uint4*)&shp[SWZ(ppx, oct)] = o;
    }
    __syncthreads();  // shp (and on tau=0: shA) visible
    // prefetch next tile during compute
    if (tau < 3) {
      const int Rn = R0 + 2 * (tau + 1);
      hmask = 0;
#pragma unroll
      for (int i = 0; i < 5; ++i) {
        int c = i * 256 + tid;
        uint4 v = {0u, 0u, 0u, 0u};
        if (!(i == 4 && tid >= 64)) {
          int ppx = c >> 3;
          int prow = ppx / 34, pcol = ppx - prow * 34;
          bool halo = (Rn + prow == 0) || (Rn + prow == 33) || (pcol == 0) || (pcol == 33);
          if (!halo) v = *(const uint4*)&src[(size_t)(Rn * 2176) + (size_t)c * 8];
          if (halo) hmask |= 1 << i;
        } else hmask |= 1 << i;
        ld[i] = v;
      }
    }
    f32x4 acc[8];
#pragma unroll
    for (int g = 0; g < 8; ++g) acc[g] = (f32x4){0.f, 0.f, 0.f, 0.f};
#pragma unroll
    for (int g = 0; g < 8; ++g) {
#pragma unroll
      for (int ch = 0; ch < 3; ++ch) {
        bf16x8 bx = *(const bf16x8*)&shp[SWZ(px[ch], g)];
        bf16x8 aw;
        if (ch < 2) {
          aw = *(const bf16x8*)&shA[((g * 8 + ch * 4 + quad) * 16 + ln) * 8];
        } else {
          aw = (bf16x8){0, 0, 0, 0, 0, 0, 0, 0};
          if (quad == 0) aw = *(const bf16x8*)&shA2[(g * 16 + ln) * 8];
        }
        acc[g] = MFMA16(aw, bx, acc[g]);
      }
    }
    // per-lane moment accumulation (prefix over g folded in)
    f32x4 P = (f32x4){0.f, 0.f, 0.f, 0.f};
#pragma unroll
    for (int k = 0; k < 8; ++k) {
      P += acc[k];
      sL[k] += P;
      qL[k] += P * P;
    }
    __syncthreads();  // all shp reads done before next write-part
  }
  // final reduction: one DPP pass over per-lane partials
#pragma unroll
  for (int k = 0; k < 8; ++k) {
#pragma unroll
    for (int r = 0; r < 4; ++r) {
      float ss = row_reduce16(sL[k][r]);
      float qq = row_reduce16(qL[k][r]);
      if (ln == 15) {
        atomicAdd(&sC[k * 16 + quad * 4 + r], ss);
        atomicAdd(&qC[k * 16 + quad * 4 + r], qq);
      }
    }
  }
  __syncthreads();
  const int blk = blockIdx.y * 4 + blockIdx.x;  // 0..255
  const size_t base = ((size_t)(edge * 4 + coq) * 256 + blk) * 256;
  if (tid < 128) pC[base + tid] = sC[tid];
  else pC[base + 128 + (tid - 128)] = qC[tid - 128];
}

// redCprepE (batched): grid (64, 2): c, z(edge). finalizeC + fold g -> wE.
__global__ __launch_bounds__(256) void redCprepE_k(const float* __restrict__ pC,
                                                   const float* __restrict__ w2a,
                                                   const float* __restrict__ w2b,
                                                   const float* __restrict__ a1,
                                                   const float* __restrict__ a2,
                                                   float* __restrict__ stBase,
                                                   u16* __restrict__ wEbase,
                                                   float* __restrict__ cm) {
  const int tid = threadIdx.x, c = blockIdx.x, z = blockIdx.y;
  const int coq = c >> 4, cl = c & 15;
  const float* w2 = z ? w2b : w2a;
  float* stE = stBase + z * 2048;
  u16* wE = wEbase + z * 36864;
  float s[8], q[8];
#pragma unroll
  for (int k = 0; k < 8; ++k) { s[k] = 0.f; q[k] = 0.f; }
  for (int i = tid; i < 256; i += 256) {
    const float* pb = pC + ((size_t)(z * 4 + coq) * 256 + i) * 256;
#pragma unroll
    for (int k = 0; k < 8; ++k) {
      s[k] += pb[k * 16 + cl];
      q[k] += pb[128 + k * 16 + cl];
    }
  }
#pragma unroll
  for (int k = 0; k < 8; ++k) {
#pragma unroll
    for (int off = 32; off; off >>= 1) { s[k] += __shfl_xor(s[k], off); q[k] += __shfl_xor(q[k], off); }
  }
  __shared__ float red[4][16];
  __shared__ float gL[8];
  int wv = tid >> 6;
  if ((tid & 63) == 0) {
#pragma unroll
    for (int k = 0; k < 8; ++k) { red[wv][k * 2] = s[k]; red[wv][k * 2 + 1] = q[k]; }
  }
  __syncthreads();
  if (tid == 0) {
    float suf = 0.f, bias = 0.f;
    for (int k = 7; k >= 0; --k) {
      float S = red[0][k * 2] + red[1][k * 2] + red[2][k * 2] + red[3][k * 2];
      float Q = red[0][k * 2 + 1] + red[1][k * 2 + 1] + red[2][k * 2 + 1] + red[3][k * 2 + 1];
      float mu = S * (1.f / NRED);
      float var = Q * (1.f / NRED) - mu * mu;
      float rr = rsqrtf(var + EPS);
      bias -= a2[k] * mu * rr;
      suf += a2[k] * rr;
      gL[k] = suf;
    }
    stE[128 + c] = bias;
    if (z == 0) {
      int g = c >> 3;
      float m1 = 0.f, m2 = 0.f;
      for (int i = g; i < 8; ++i) { m1 += a1[i]; m2 += a2[i]; }
      cm[c] = m1 * m2;
    }
  }
  __syncthreads();
  for (int idx = tid; idx < 576; idx += 256) {
    int tap = idx >> 6, ci = idx & 63;
    wE[(tap * 64 + c) * 64 + ci] = f2bf(w2[(c * 64 + ci) * 9 + tap] * gL[ci >> 3]);
  }
}

// ---------------- convE (modes 0,1): conv2 + epilogue ------------------------
template <int MODE>
__global__ __launch_bounds__(256, 2) void convE_k(const u16* __restrict__ t,
                                                  const float* __restrict__ stE,
                                                  const u16* __restrict__ wEp,
                                                  u16* __restrict__ d1,
                                                  u16* __restrict__ d2,
                                                  const float* __restrict__ cm) {
  __shared__ __align__(16) u16 shp[PATCH];
  __shared__ float cmL[64], biasL[64];
  const int tid = threadIdx.x;
  const int b = blockIdx.y, R0 = blockIdx.x * 2;
  if (tid < 64) { cmL[tid] = cm[tid]; biasL[tid] = stE[128 + tid]; }
  stage_affine(t + (size_t)b * IMST + (size_t)R0 * 2176, shp, tid, R0, stE);
  const int lane = tid & 63, w = tid >> 6;
  const int ln = lane & 15, quad = lane >> 4;
  const int lr = w >> 1, mh = w & 1;
  bf16x8 A[9][2][2];
#pragma unroll
  for (int tap = 0; tap < 9; ++tap)
#pragma unroll
    for (int m2 = 0; m2 < 2; ++m2)
#pragma unroll
      for (int h = 0; h < 2; ++h)
        A[tap][m2][h] = *(const bf16x8*)&wEp[(size_t)((tap * 64 + (mh * 2 + m2) * 16 + ln) * 64) + h * 32 + quad * 8];
  __syncthreads();
  f32x4 acc[2][2];
#pragma unroll
  for (int m2 = 0; m2 < 2; ++m2)
#pragma unroll
    for (int nf = 0; nf < 2; ++nf) acc[m2][nf] = (f32x4){0.f, 0.f, 0.f, 0.f};
#pragma unroll
  for (int tap = 0; tap < 9; ++tap) {
    const int dy = tap / 3, dx = tap % 3;
    const int px0 = (lr + dy) * 34 + ln + dx;
#pragma unroll
    for (int h = 0; h < 2; ++h) {
      const int oct = h * 4 + quad;
      bf16x8 b0 = *(const bf16x8*)&shp[SWZ(px0, oct)];
      bf16x8 b1 = *(const bf16x8*)&shp[SWZ(px0 + 16, oct)];
      acc[0][0] = MFMA16(A[tap][0][h], b0, acc[0][0]);
      acc[0][1] = MFMA16(A[tap][0][h], b1, acc[0][1]);
      acc[1][0] = MFMA16(A[tap][1][h], b0, acc[1][0]);
      acc[1][1] = MFMA16(A[tap][1][h], b1, acc[1][1]);
    }
  }
  const int R = R0 + lr;
#pragma unroll
  for (int m2 = 0; m2 < 2; ++m2) {
    const int cob = (mh * 2 + m2) * 16 + quad * 4;
#pragma unroll
    for (int nf = 0; nf < 2; ++nf) {
      const int C = nf * 16 + ln;
      const size_t haloPx = (size_t)b * IMST + (size_t)((R + 1) * 34 + C + 1) * 64 + cob;
      float v[4];
#pragma unroll
      for (int r = 0; r < 4; ++r) v[r] = acc[m2][nf][r] + biasL[cob + r];
      if (MODE == 0) {
        uint2 pk, pkr;
        pk.x = pk2(v[0], v[1]); pk.y = pk2(v[2], v[3]);
        pkr.x = pk2(fmaxf(v[0], 0.f), fmaxf(v[1], 0.f));
        pkr.y = pk2(fmaxf(v[2], 0.f), fmaxf(v[3], 0.f));
        *(uint2*)&d1[haloPx] = pk;    // n1T (raw, for pool)
        *(uint2*)&d2[haloPx] = pkr;   // n1r (relu, e2 input)
      } else {
        float ps[4] = {0.f, 0.f, 0.f, 0.f};
        const size_t pb2 = (size_t)b * IMST + (size_t)(R * 34 + C) * 64 + cob;
#pragma unroll
        for (int dy = 0; dy < 3; ++dy)
#pragma unroll
          for (int dx = 0; dx < 3; ++dx) {
            uint2 u = *(const uint2*)&d2[pb2 + (size_t)(dy * 34 + dx) * 64];  // n1T
            ps[0] += bf2f((u16)(u.x & 0xffff));
            ps[1] += bf2f((u16)(u.x >> 16));
            ps[2] += bf2f((u16)(u.y & 0xffff));
            ps[3] += bf2f((u16)(u.y >> 16));
          }
        float rows = 3.f - (R == 0 ? 1.f : 0.f) - (R == 31 ? 1.f : 0.f);
        float cols = 3.f - (C == 0 ? 1.f : 0.f) - (C == 31 ? 1.f : 0.f);
        float inv = 1.f / (rows * cols);
        uint2 pkr;
        float t0v = fmaxf(v[0] + ps[0] * inv * cmL[cob], 0.f);
        float t1v = fmaxf(v[1] + ps[1] * inv * cmL[cob + 1], 0.f);
        float t2v = fmaxf(v[2] + ps[2] * inv * cmL[cob + 2], 0.f);
        float t3v = fmaxf(v[3] + ps[3] * inv * cmL[cob + 3], 0.f);
        pkr.x = pk2(t0v, t1v); pkr.y = pk2(t2v, t3v);
        *(uint2*)&d1[haloPx] = pkr;   // n2r
      }
    }
  }
}

// ---------------- convE23: fused final two convs + output --------------------
__global__ __launch_bounds__(256, 2) void convE23_k(const u16* __restrict__ t0,
                                                    const u16* __restrict__ t1,
                                                    const float* __restrict__ stBase,
                                                    const u16* __restrict__ wE2,
                                                    const u16* __restrict__ wE3,
                                                    float* __restrict__ outp,
                                                    const float* __restrict__ x,
                                                    const float* __restrict__ cm) {
  __shared__ __align__(16) u16 shp2[2 * PATCH];
  __shared__ float cmL[64], biasL[64];
  const int tid = threadIdx.x;
  const int b = blockIdx.y, R0 = blockIdx.x * 2;
  if (tid < 64) {
    cmL[tid] = cm[tid];
    biasL[tid] = stBase[128 + tid] + stBase[2048 + 128 + tid];
  }
  stage_affine(t0 + (size_t)b * IMST + (size_t)R0 * 2176, shp2, tid, R0, stBase);
  stage_affine(t1 + (size_t)b * IMST + (size_t)R0 * 2176, shp2 + PATCH, tid, R0, stBase + 2048);
  __syncthreads();
  const int lane = tid & 63, w = tid >> 6;
  const int ln = lane & 15, quad = lane >> 4;
  const int lr = w >> 1, mh = w & 1;
  f32x4 acc[2][2];
#pragma unroll
  for (int m2 = 0; m2 < 2; ++m2)
#pragma unroll
    for (int nf = 0; nf < 2; ++nf) acc[m2][nf] = (f32x4){0.f, 0.f, 0.f, 0.f};
#pragma unroll 1
  for (int ei = 0; ei < 2; ++ei) {
    const u16* wEp = ei ? wE3 : wE2;
    const u16* sp = &shp2[ei * PATCH];
    bf16x8 A[9][2][2];
#pragma unroll
    for (int tap = 0; tap < 9; ++tap)
#pragma unroll
      for (int m2 = 0; m2 < 2; ++m2)
#pragma unroll
        for (int h = 0; h < 2; ++h)
          A[tap][m2][h] = *(const bf16x8*)&wEp[(size_t)((tap * 64 + (mh * 2 + m2) * 16 + ln) * 64) + h * 32 + quad * 8];
#pragma unroll
    for (int tap = 0; tap < 9; ++tap) {
      const int dy = tap / 3, dx = tap % 3;
      const int px0 = (lr + dy) * 34 + ln + dx;
#pragma unroll
      for (int h = 0; h < 2; ++h) {
        const int oct = h * 4 + quad;
        bf16x8 b0 = *(const bf16x8*)&sp[SWZ(px0, oct)];
        bf16x8 b1 = *(const bf16x8*)&sp[SWZ(px0 + 16, oct)];
        acc[0][0] = MFMA16(A[tap][0][h], b0, acc[0][0]);
        acc[0][1] = MFMA16(A[tap][0][h], b1, acc[0][1]);
        acc[1][0] = MFMA16(A[tap][1][h], b0, acc[1][0]);
        acc[1][1] = MFMA16(A[tap][1][h], b1, acc[1][1]);
      }
    }
  }
  const int R = R0 + lr;
#pragma unroll
  for (int m2 = 0; m2 < 2; ++m2) {
    const int cob = (mh * 2 + m2) * 16 + quad * 4;
#pragma unroll
    for (int nf = 0; nf < 2; ++nf) {
      const int C = nf * 16 + ln;
      size_t base = (size_t)b * 65536 + (size_t)cob * 1024 + R * 32 + C;
#pragma unroll
      for (int r = 0; r < 4; ++r)
        outp[base + (size_t)r * 1024] =
            acc[m2][nf][r] + biasL[cob + r] + x[base + (size_t)r * 1024] * cmL[cob + r];
    }
  }
}

extern "C" void kernel_launch(void* const* d_in, const int* in_sizes, int n_in,
                              void* d_out, int out_size, void* d_ws, size_t ws_size,
                              hipStream_t stream) {
  const float* x  = (const float*)d_in[0];
  const float* a1 = (const float*)d_in[1];
  const float* a2 = (const float*)d_in[2];
  const float* W1[4] = {(const float*)d_in[3], (const float*)d_in[5],
                        (const float*)d_in[7], (const float*)d_in[9]};
  const float* W2[4] = {(const float*)d_in[4], (const float*)d_in[6],
                        (const float*)d_in[8], (const float*)d_in[10]};
  float* out = (float*)d_out;
  char* ws = (char*)d_ws;
  const size_t HB = (size_t)IMST * 64 * 2;  // 9,469,952 B per halo buffer
  u16* xT  = (u16*)ws;
  u16* t0  = (u16*)(ws + HB);
  u16* t1  = (u16*)(ws + 2 * HB);
  u16* n1T = (u16*)(ws + 3 * HB);
  u16* n1r = (u16*)(ws + 4 * HB);
  u16* n2r = (u16*)(ws + 5 * HB);
  char* p = ws + 6 * HB;
  float* st  = (float*)p;            p += 8256 * 4;
  u16* wT1   = (u16*)p;              p += 4 * 36864 * 2;
  u16* wG64  = (u16*)p;              p += 4 * 32768 * 2;
  u16* wT8   = (u16*)p;              p += 4 * 4096 * 2;
  u16* wE    = (u16*)p;              p += 4 * 36864 * 2;
  float* pA  = (float*)p;            p += 2 * 1024 * 128 * 4;
  float* pC  = (float*)p;            // 8 * 256 * 256 * 4 = 2 MB
  float* cm  = st + 8192;

  pack_wT1_k<<<36, 256, 0, stream>>>(W1[0], W1[1], W1[2], W1[3], wT1);
  pack_wG_k<<<dim3(72, 4), 256, 0, stream>>>(W2[0], W2[1], W2[2], W2[3], wG64, wT8);
  transpose_k<<<1024, 256, 0, stream>>>(x, xT);
  zero_halo_k<<<64, 160, 0, stream>>>(n1T);

  dim3 gA(16, 64, 2), gC(4, 64, 8), gE(16, 64);
  // batch edges 0+1 (both consume xT)
  convA_k<<<gA, 256, 0, stream>>>(xT, xT, wT1, wT1 + 36864, t0, t1, pA);
  reducerA_k<<<dim3(64, 2), 256, 0, stream>>>(pA, a1, st);
  convC_k<<<gC, 256, 0, stream>>>(t0, t1, wG64, wT8, st, pC);
  redCprepE_k<<<dim3(64, 2), 256, 0, stream>>>(pC, W2[0], W2[1], a1, a2, st, wE, cm);
  convE_k<0><<<gE, 256, 0, stream>>>(t0, st, wE, n1T, n1r, cm);
  convE_k<1><<<gE, 256, 0, stream>>>(t1, st + 2048, wE + 36864, n2r, n1T, cm);
  // batch edges 2+3 (consume n1r, n2r)
  convA_k<<<gA, 256, 0, stream>>>(n1r, n2r, wT1 + 2 * 36864, wT1 + 3 * 36864, t0, t1, pA);
  reducerA_k<<<dim3(64, 2), 256, 0, stream>>>(pA, a1, st + 4096);
  convC_k<<<gC, 256, 0, stream>>>(t0, t1, wG64 + 2 * 32768, wT8 + 2 * 4096, st + 4096, pC);
  redCprepE_k<<<dim3(64, 2), 256, 0, stream>>>(pC, W2[2], W2[3], a1, a2, st + 4096,
                                               wE + 2 * 36864, cm);
  convE23_k<<<gE, 256, 0, stream>>>(t0, t1, st + 4096, wE + 2 * 36864, wE + 3 * 36864,
                                    out, x, cm);
}

// Round 6
// 463.504 us; speedup vs baseline: 1.2103x; 1.0689x over previous
//
#include <hip/hip_runtime.h>

#define EPS 1e-5f
#define NRED 65536.0f   // B*H*W = 64*32*32
#define IMST 73984      // 34*34*64 halo image stride (elements)
#define PATCH 8704      // 136 px * 64 ci (swizzled, no pad)

typedef short bf16x8 __attribute__((ext_vector_type(8)));
typedef float f32x4 __attribute__((ext_vector_type(4)));
typedef unsigned short u16;

#define MFMA16(a, b, c) __builtin_amdgcn_mfma_f32_16x16x32_bf16(a, b, c, 0, 0, 0)
// XOR-swizzled LDS patch addressing: kills bank conflicts with zero padding.
#define SWZ(px, oct) ((px) * 64 + (((oct) ^ ((px) & 7)) * 8))

__device__ __forceinline__ u16 f2bf(float x) {  // RNE f32->bf16
  union { float f; unsigned u; } v; v.f = x;
  unsigned r = v.u + 0x7FFF + ((v.u >> 16) & 1);
  return (u16)(r >> 16);
}
__device__ __forceinline__ float bf2f(u16 h) {
  union { unsigned u; float f; } v; v.u = ((unsigned)h) << 16;
  return v.f;
}
__device__ __forceinline__ unsigned pk2(float a, float b) {
  return (unsigned)f2bf(a) | ((unsigned)f2bf(b) << 16);
}

// DPP row-shift reduce over 16-lane rows; sum valid in ln==15. Pure VALU.
template <int CTRL>
__device__ __forceinline__ float dpp_mov(float x) {
  int xi = __builtin_bit_cast(int, x);
  int r = __builtin_amdgcn_update_dpp(0, xi, CTRL, 0xF, 0xF, true);
  return __builtin_bit_cast(float, r);
}
__device__ __forceinline__ float row_reduce16(float x) {
  x += dpp_mov<0x111>(x);
  x += dpp_mov<0x112>(x);
  x += dpp_mov<0x114>(x);
  x += dpp_mov<0x118>(x);
  return x;
}

// ---- swizzled patch staging (4 rows x 34 cols x 64 ci) ----------------------
__device__ __forceinline__ void stage_mask(const u16* __restrict__ src,
                                           u16* __restrict__ shp, int tid, int R0) {
#pragma unroll
  for (int i = 0; i < 5; ++i) {
    int c = i * 256 + tid;
    if (i == 4 && tid >= 64) break;
    int px = c >> 3, oct = c & 7;
    int prow = px / 34, pcol = px - prow * 34;
    bool halo = (R0 + prow == 0) || (R0 + prow == 33) || (pcol == 0) || (pcol == 33);
    uint4 v = {0u, 0u, 0u, 0u};
    if (!halo) v = *(const uint4*)&src[(size_t)c * 8];
    *(uint4*)&shp[SWZ(px, oct)] = v;
  }
}

// Affine staging: h = t*s1[ci]+b1[ci] interior, 0 halo (renorm fused).
__device__ __forceinline__ void stage_affine(const u16* __restrict__ src,
                                             u16* __restrict__ shp, int tid, int R0,
                                             const float* __restrict__ stE) {
  const int oct0 = tid & 7;
  float s[8], bb[8];
#pragma unroll
  for (int j = 0; j < 8; ++j) { s[j] = stE[oct0 * 8 + j]; bb[j] = stE[64 + oct0 * 8 + j]; }
#pragma unroll
  for (int i = 0; i < 5; ++i) {
    int c = i * 256 + tid;
    if (i == 4 && tid >= 64) break;
    int px = c >> 3, oct = c & 7;
    int prow = px / 34, pcol = px - prow * 34;
    bool halo = (R0 + prow == 0) || (R0 + prow == 33) || (pcol == 0) || (pcol == 33);
    uint4 o = {0u, 0u, 0u, 0u};
    if (!halo) {
      uint4 u = *(const uint4*)&src[(size_t)c * 8];
      unsigned uv[4] = {u.x, u.y, u.z, u.w};
      unsigned rv[4];
#pragma unroll
      for (int p2 = 0; p2 < 4; ++p2) {
        float lo = bf2f((u16)(uv[p2] & 0xffff)) * s[p2 * 2] + bb[p2 * 2];
        float hi = bf2f((u16)(uv[p2] >> 16)) * s[p2 * 2 + 1] + bb[p2 * 2 + 1];
        rv[p2] = pk2(lo, hi);
      }
      o.x = rv[0]; o.y = rv[1]; o.z = rv[2]; o.w = rv[3];
    }
    *(uint4*)&shp[SWZ(px, oct)] = o;
  }
}

// st layout: per edge e at st+e*2048: [0,64) s1 | [64,128) b1 | [128,192) bias2.

__global__ void pack_wT1_k(const float* __restrict__ w0, const float* __restrict__ w1,
                           const float* __restrict__ w2, const float* __restrict__ w3,
                           u16* __restrict__ wT1) {
  int e = blockIdx.x / 9, tap = blockIdx.x % 9;
  const float* w = e == 0 ? w0 : e == 1 ? w1 : e == 2 ? w2 : w3;
  u16* dst = wT1 + e * 36864 + tap * 4096;
  for (int idx = threadIdx.x; idx < 4096; idx += 256) {
    int co = idx >> 6, ci = idx & 63;
    dst[idx] = f2bf(w[(co * 64 + ci) * 9 + tap]);
  }
}

// wG64[e][g*8+tap(0..7)][co64][cig8] and wT8[e][g][co64][cig8] (tap 8)
__global__ void pack_wG_k(const float* __restrict__ w0, const float* __restrict__ w1,
                          const float* __restrict__ w2, const float* __restrict__ w3,
                          u16* __restrict__ wG64, u16* __restrict__ wT8) {
  int e = blockIdx.y;
  const float* w = e == 0 ? w0 : e == 1 ? w1 : e == 2 ? w2 : w3;
  int bx = blockIdx.x;  // 0..71
  int g, tap;
  u16* dst;
  if (bx < 64) { g = bx >> 3; tap = bx & 7; dst = wG64 + e * 32768 + bx * 512; }
  else         { g = bx - 64; tap = 8;      dst = wT8 + e * 4096 + g * 512; }
  for (int idx = threadIdx.x; idx < 512; idx += 256) {
    int co = idx >> 3, cig = idx & 7;
    dst[idx] = f2bf(w[(co * 64 + g * 8 + cig) * 9 + tap]);
  }
}

// x (NCHW f32) -> xT = bf16(relu(x)) halo pixel-major (interior only).
__global__ __launch_bounds__(256) void transpose_k(const float* __restrict__ x,
                                                   u16* __restrict__ xT) {
  __shared__ __align__(16) u16 sh[64 * 72];
  const int tid = threadIdx.x;
  const int b = blockIdx.x >> 4, slab = blockIdx.x & 15;
  const int ln = tid & 63, w = tid >> 6;
  const float* xb = x + (size_t)b * 65536 + slab * 64;
#pragma unroll
  for (int i = 0; i < 16; ++i) {
    int ci = w + i * 4;
    float v = xb[ci * 1024 + ln];
    sh[ln * 72 + ci] = f2bf(fmaxf(v, 0.f));
  }
  __syncthreads();
  u16* dst = xT + (size_t)b * IMST;
#pragma unroll
  for (int j = 0; j < 2; ++j) {
    int idx = tid + j * 256;
    int p = idx >> 3, oct = idx & 7;
    int gp = slab * 64 + p;
    int R = gp >> 5, C = gp & 31;
    *(uint4*)&dst[((R + 1) * 34 + C + 1) * 64 + oct * 8] = *(const uint4*)&sh[p * 72 + oct * 8];
  }
}

// zero halo strips of n1T (pool reads raw global n1T incl. halo).
__global__ void zero_halo_k(u16* __restrict__ buf) {
  int b = blockIdx.x, tid = threadIdx.x;
  if (tid >= 132) return;
  int R, C;
  if (tid < 34) { R = 0; C = tid; }
  else if (tid < 68) { R = 33; C = tid - 34; }
  else if (tid < 100) { R = tid - 67; C = 0; }
  else { R = tid - 99; C = 33; }
  u16* p = buf + (size_t)b * IMST + (size_t)(R * 34 + C) * 64;
  uint4 z = {0u, 0u, 0u, 0u};
#pragma unroll
  for (int i = 0; i < 8; ++i) *(uint4*)&p[i * 8] = z;
}

// ---------------- convA (2-edge batched): t = conv3x3(xin, W1) + stats -------
// A-fragments streamed from global per tap (coalesced [tap][co][ci] layout,
// L2-resident 147KB) instead of 144-VGPR register cache -> occupancy 2->4+ blk/CU.
__global__ __launch_bounds__(256, 4) void convA_k(const u16* __restrict__ in0,
                                                  const u16* __restrict__ in1,
                                                  const u16* __restrict__ wTa,
                                                  const u16* __restrict__ wTb,
                                                  u16* __restrict__ t0,
                                                  u16* __restrict__ t1,
                                                  float* __restrict__ pA) {
  __shared__ __align__(16) u16 shp[PATCH];
  __shared__ float sA[64], qA[64];
  const int tid = threadIdx.x;
  const int b = blockIdx.y, R0 = blockIdx.x * 2, z = blockIdx.z;
  const u16* xin = z ? in1 : in0;
  const u16* wT = z ? wTb : wTa;
  u16* t = z ? t1 : t0;
  if (tid < 64) { sA[tid] = 0.f; qA[tid] = 0.f; }
  stage_mask(xin + (size_t)b * IMST + (size_t)R0 * 2176, shp, tid, R0);
  const int lane = tid & 63, w = tid >> 6;
  const int ln = lane & 15, quad = lane >> 4;
  const int lr = w >> 1, mh = w & 1;
  const u16* wbase = wT + (size_t)((mh * 2) * 16 + ln) * 64 + quad * 8;
  __syncthreads();
  f32x4 acc[2][2];
#pragma unroll
  for (int m2 = 0; m2 < 2; ++m2)
#pragma unroll
    for (int nf = 0; nf < 2; ++nf) acc[m2][nf] = (f32x4){0.f, 0.f, 0.f, 0.f};
#pragma unroll 3
  for (int tap = 0; tap < 9; ++tap) {
    const int dy = tap / 3, dx = tap % 3;
    const int px0 = (lr + dy) * 34 + ln + dx;
    bf16x8 A[2][2];
#pragma unroll
    for (int m2 = 0; m2 < 2; ++m2)
#pragma unroll
      for (int h = 0; h < 2; ++h)
        A[m2][h] = *(const bf16x8*)&wbase[(size_t)(tap * 64 + m2 * 16) * 64 + h * 32];
#pragma unroll
    for (int h = 0; h < 2; ++h) {
      const int oct = h * 4 + quad;
      bf16x8 b0 = *(const bf16x8*)&shp[SWZ(px0, oct)];
      bf16x8 b1 = *(const bf16x8*)&shp[SWZ(px0 + 16, oct)];
      acc[0][0] = MFMA16(A[0][h], b0, acc[0][0]);
      acc[0][1] = MFMA16(A[0][h], b1, acc[0][1]);
      acc[1][0] = MFMA16(A[1][h], b0, acc[1][0]);
      acc[1][1] = MFMA16(A[1][h], b1, acc[1][1]);
    }
  }
  const int R = R0 + lr;
#pragma unroll
  for (int m2 = 0; m2 < 2; ++m2) {
    const int cob = (mh * 2 + m2) * 16 + quad * 4;
#pragma unroll
    for (int nf = 0; nf < 2; ++nf) {
      u16* tb = t + (size_t)b * IMST + (size_t)((R + 1) * 34 + nf * 16 + ln + 1) * 64 + cob;
      uint2 pk;
      pk.x = pk2(acc[m2][nf][0], acc[m2][nf][1]);
      pk.y = pk2(acc[m2][nf][2], acc[m2][nf][3]);
      *(uint2*)tb = pk;
    }
#pragma unroll
    for (int r = 0; r < 4; ++r) {
      float v0 = acc[m2][0][r], v1 = acc[m2][1][r];
      float s = row_reduce16(v0) + row_reduce16(v1);
      float q = row_reduce16(v0 * v0) + row_reduce16(v1 * v1);
      if (ln == 15) {
        atomicAdd(&sA[cob + r], s);
        atomicAdd(&qA[cob + r], q);
      }
    }
  }
  __syncthreads();
  const int blk = z * 1024 + blockIdx.y * 16 + blockIdx.x;
  if (tid < 64) pA[blk * 128 + tid] = sA[tid];
  else if (tid < 128) pA[blk * 128 + tid] = qA[tid - 64];
}

// reducerA (batched): grid (64, 2); writes s1/b1 into stBase + z*2048.
__global__ __launch_bounds__(256) void reducerA_k(const float* __restrict__ pA,
                                                  const float* __restrict__ a1,
                                                  float* __restrict__ stBase) {
  const int tid = threadIdx.x, c = blockIdx.x, z = blockIdx.y;
  const float* pAe = pA + (size_t)z * 1024 * 128;
  float s = 0.f, q = 0.f;
  for (int i = tid; i < 1024; i += 256) {
    s += pAe[i * 128 + c];
    q += pAe[i * 128 + 64 + c];
  }
#pragma unroll
  for (int off = 32; off; off >>= 1) { s += __shfl_xor(s, off); q += __shfl_xor(q, off); }
  __shared__ float red[8];
  int wv = tid >> 6;
  if ((tid & 63) == 0) { red[wv] = s; red[4 + wv] = q; }
  __syncthreads();
  if (tid == 0) {
    float S = red[0] + red[1] + red[2] + red[3];
    float Q = red[4] + red[5] + red[6] + red[7];
    int g = c >> 3;
    float m = 0.f;
    for (int i = g; i < 8; ++i) m += a1[i];
    float mu = S * (1.f / NRED);
    float var = Q * (1.f / NRED) - mu * mu;
    float r = rsqrtf(var + EPS);
    float* stE = stBase + z * 2048;
    stE[c] = r * m;
    stE[64 + c] = -mu * r * m;
  }
}

// ---------------- convC: per-group prefix stats, coq-loop version (r2 best) --
// grid (16, 64, 2): z = edge. Patch staged once; shA (16KB) restaged per coq.
__global__ __launch_bounds__(256, 4) void convC_k(const u16* __restrict__ t0,
                                                  const u16* __restrict__ t1,
                                                  const u16* __restrict__ wG64,
                                                  const u16* __restrict__ wT8,
                                                  const float* __restrict__ stBase,
                                                  float* __restrict__ pC) {
  __shared__ __align__(16) u16 shp[PATCH];        // 17408 B
  __shared__ __align__(16) u16 shA[64 * 16 * 8];  // 16384 B (one co-quarter)
  __shared__ __align__(16) u16 shA2[8 * 16 * 8];  // 2048 B
  __shared__ float sC[4][128], qC[4][128];        // 4096 B
  const int tid = threadIdx.x;
  const int b = blockIdx.y, R0 = blockIdx.x * 2;
  const int edge = blockIdx.z;
  const u16* t = edge ? t1 : t0;
  const float* stE = stBase + edge * 2048;
  const u16* wGe = wG64 + edge * 32768;
  const u16* wT8e = wT8 + edge * 4096;
  {
    float* scf = (float*)sC;
    float* qcf = (float*)qC;
#pragma unroll
    for (int i = 0; i < 2; ++i) { scf[i * 256 + tid] = 0.f; qcf[i * 256 + tid] = 0.f; }
  }
  stage_affine(t + (size_t)b * IMST + (size_t)R0 * 2176, shp, tid, R0, stE);
  // stage shA for coq=0: 1024 chunks [row64][co16][cig8]
#pragma unroll
  for (int i = 0; i < 4; ++i) {
    int c = i * 256 + tid;
    int row = c >> 4, col = c & 15;
    *(uint4*)&shA[c * 8] = *(const uint4*)&wGe[(size_t)(row * 64 + col) * 8];
  }
  if (tid < 128) {  // shA2: 128 chunks [g8][co16][cig8]
    int g = tid >> 4, col = tid & 15;
    *(uint4*)&shA2[tid * 8] = *(const uint4*)&wT8e[(size_t)(g * 64 + col) * 8];
  }
  __syncthreads();
  const int lane = tid & 63, w = tid >> 6;
  const int ln = lane & 15, quad = lane >> 4;
  const int lrow = w >> 1, colbase = (w & 1) * 16;
  int px[3];
#pragma unroll
  for (int ch = 0; ch < 3; ++ch) {
    int tp = ch * 4 + quad; if (tp > 8) tp = 8;
    px[ch] = (lrow + tp / 3) * 34 + colbase + ln + tp % 3;
  }
#pragma unroll 1
  for (int coq = 0; coq < 4; ++coq) {
    f32x4 acc[8];
#pragma unroll
    for (int g = 0; g < 8; ++g) acc[g] = (f32x4){0.f, 0.f, 0.f, 0.f};
#pragma unroll
    for (int g = 0; g < 8; ++g) {
#pragma unroll
      for (int ch = 0; ch < 3; ++ch) {
        bf16x8 bx = *(const bf16x8*)&shp[SWZ(px[ch], g)];
        bf16x8 aw;
        if (ch < 2) {
          aw = *(const bf16x8*)&shA[((g * 8 + ch * 4 + quad) * 16 + ln) * 8];
        } else {
          aw = (bf16x8){0, 0, 0, 0, 0, 0, 0, 0};
          if (quad == 0) aw = *(const bf16x8*)&shA2[(g * 16 + ln) * 8];
        }
        acc[g] = MFMA16(aw, bx, acc[g]);
      }
    }
    f32x4 P = (f32x4){0.f, 0.f, 0.f, 0.f};
#pragma unroll
    for (int k = 0; k < 8; ++k) {
      P += acc[k];
#pragma unroll
      for (int r = 0; r < 4; ++r) {
        float v = P[r];
        float s = row_reduce16(v);
        float q = row_reduce16(v * v);
        if (ln == 15) {
          atomicAdd(&sC[coq][k * 16 + quad * 4 + r], s);
          atomicAdd(&qC[coq][k * 16 + quad * 4 + r], q);
        }
      }
    }
    __syncthreads();  // all reads of shA done + stats visible
    if (coq < 3) {    // restage shA/shA2 for next co-quarter
      const int nq = coq + 1;
#pragma unroll
      for (int i = 0; i < 4; ++i) {
        int c = i * 256 + tid;
        int row = c >> 4, col = c & 15;
        *(uint4*)&shA[c * 8] = *(const uint4*)&wGe[(size_t)(row * 64 + nq * 16 + col) * 8];
      }
      if (tid < 128) {
        int g = tid >> 4, col = tid & 15;
        *(uint4*)&shA2[tid * 8] = *(const uint4*)&wT8e[(size_t)(g * 64 + nq * 16 + col) * 8];
      }
      __syncthreads();
    }
  }
  const int blk = blockIdx.y * 16 + blockIdx.x;
#pragma unroll 1
  for (int coq = 0; coq < 4; ++coq) {
    const size_t base = ((size_t)(edge * 4 + coq) * 1024 + blk) * 256;
    if (tid < 128) pC[base + tid] = sC[coq][tid];
    else pC[base + 128 + (tid - 128)] = qC[coq][tid - 128];
  }
}

// redCprepE (batched): grid (64, 2): c, z(edge). finalizeC + fold g -> wE.
__global__ __launch_bounds__(256) void redCprepE_k(const float* __restrict__ pC,
                                                   const float* __restrict__ w2a,
                                                   const float* __restrict__ w2b,
                                                   const float* __restrict__ a1,
                                                   const float* __restrict__ a2,
                                                   float* __restrict__ stBase,
                                                   u16* __restrict__ wEbase,
                                                   float* __restrict__ cm) {
  const int tid = threadIdx.x, c = blockIdx.x, z = blockIdx.y;
  const int coq = c >> 4, cl = c & 15;
  const float* w2 = z ? w2b : w2a;
  float* stE = stBase + z * 2048;
  u16* wE = wEbase + z * 36864;
  float s[8], q[8];
#pragma unroll
  for (int k = 0; k < 8; ++k) { s[k] = 0.f; q[k] = 0.f; }
  for (int i = tid; i < 1024; i += 256) {
    const float* pb = pC + ((size_t)(z * 4 + coq) * 1024 + i) * 256;
#pragma unroll
    for (int k = 0; k < 8; ++k) {
      s[k] += pb[k * 16 + cl];
      q[k] += pb[128 + k * 16 + cl];
    }
  }
#pragma unroll
  for (int k = 0; k < 8; ++k) {
#pragma unroll
    for (int off = 32; off; off >>= 1) { s[k] += __shfl_xor(s[k], off); q[k] += __shfl_xor(q[k], off); }
  }
  __shared__ float red[4][16];
  __shared__ float gL[8];
  int wv = tid >> 6;
  if ((tid & 63) == 0) {
#pragma unroll
    for (int k = 0; k < 8; ++k) { red[wv][k * 2] = s[k]; red[wv][k * 2 + 1] = q[k]; }
  }
  __syncthreads();
  if (tid == 0) {
    float suf = 0.f, bias = 0.f;
    for (int k = 7; k >= 0; --k) {
      float S = red[0][k * 2] + red[1][k * 2] + red[2][k * 2] + red[3][k * 2];
      float Q = red[0][k * 2 + 1] + red[1][k * 2 + 1] + red[2][k * 2 + 1] + red[3][k * 2 + 1];
      float mu = S * (1.f / NRED);
      float var = Q * (1.f / NRED) - mu * mu;
      float rr = rsqrtf(var + EPS);
      bias -= a2[k] * mu * rr;
      suf += a2[k] * rr;
      gL[k] = suf;
    }
    stE[128 + c] = bias;
    if (z == 0) {
      int g = c >> 3;
      float m1 = 0.f, m2 = 0.f;
      for (int i = g; i < 8; ++i) { m1 += a1[i]; m2 += a2[i]; }
      cm[c] = m1 * m2;
    }
  }
  __syncthreads();
  for (int idx = tid; idx < 576; idx += 256) {
    int tap = idx >> 6, ci = idx & 63;
    wE[(tap * 64 + c) * 64 + ci] = f2bf(w2[(c * 64 + ci) * 9 + tap] * gL[ci >> 3]);
  }
}

// ---------------- convE (modes 0,1): conv2 + epilogue ------------------------
// A-fragments streamed from global per tap (same coalesced layout as convA).
template <int MODE>
__global__ __launch_bounds__(256, 4) void convE_k(const u16* __restrict__ t,
                                                  const float* __restrict__ stE,
                                                  const u16* __restrict__ wEp,
                                                  u16* __restrict__ d1,
                                                  u16* __restrict__ d2,
                                                  const float* __restrict__ cm) {
  __shared__ __align__(16) u16 shp[PATCH];
  __shared__ float cmL[64], biasL[64];
  const int tid = threadIdx.x;
  const int b = blockIdx.y, R0 = blockIdx.x * 2;
  if (tid < 64) { cmL[tid] = cm[tid]; biasL[tid] = stE[128 + tid]; }
  stage_affine(t + (size_t)b * IMST + (size_t)R0 * 2176, shp, tid, R0, stE);
  const int lane = tid & 63, w = tid >> 6;
  const int ln = lane & 15, quad = lane >> 4;
  const int lr = w >> 1, mh = w & 1;
  const u16* wbase = wEp + (size_t)((mh * 2) * 16 + ln) * 64 + quad * 8;
  __syncthreads();
  f32x4 acc[2][2];
#pragma unroll
  for (int m2 = 0; m2 < 2; ++m2)
#pragma unroll
    for (int nf = 0; nf < 2; ++nf) acc[m2][nf] = (f32x4){0.f, 0.f, 0.f, 0.f};
#pragma unroll 3
  for (int tap = 0; tap < 9; ++tap) {
    const int dy = tap / 3, dx = tap % 3;
    const int px0 = (lr + dy) * 34 + ln + dx;
    bf16x8 A[2][2];
#pragma unroll
    for (int m2 = 0; m2 < 2; ++m2)
#pragma unroll
      for (int h = 0; h < 2; ++h)
        A[m2][h] = *(const bf16x8*)&wbase[(size_t)(tap * 64 + m2 * 16) * 64 + h * 32];
#pragma unroll
    for (int h = 0; h < 2; ++h) {
      const int oct = h * 4 + quad;
      bf16x8 b0 = *(const bf16x8*)&shp[SWZ(px0, oct)];
      bf16x8 b1 = *(const bf16x8*)&shp[SWZ(px0 + 16, oct)];
      acc[0][0] = MFMA16(A[0][h], b0, acc[0][0]);
      acc[0][1] = MFMA16(A[0][h], b1, acc[0][1]);
      acc[1][0] = MFMA16(A[1][h], b0, acc[1][0]);
      acc[1][1] = MFMA16(A[1][h], b1, acc[1][1]);
    }
  }
  const int R = R0 + lr;
#pragma unroll
  for (int m2 = 0; m2 < 2; ++m2) {
    const int cob = (mh * 2 + m2) * 16 + quad * 4;
#pragma unroll
    for (int nf = 0; nf < 2; ++nf) {
      const int C = nf * 16 + ln;
      const size_t haloPx = (size_t)b * IMST + (size_t)((R + 1) * 34 + C + 1) * 64 + cob;
      float v[4];
#pragma unroll
      for (int r = 0; r < 4; ++r) v[r] = acc[m2][nf][r] + biasL[cob + r];
      if (MODE == 0) {
        uint2 pk, pkr;
        pk.x = pk2(v[0], v[1]); pk.y = pk2(v[2], v[3]);
        pkr.x = pk2(fmaxf(v[0], 0.f), fmaxf(v[1], 0.f));
        pkr.y = pk2(fmaxf(v[2], 0.f), fmaxf(v[3], 0.f));
        *(uint2*)&d1[haloPx] = pk;    // n1T (raw, for pool)
        *(uint2*)&d2[haloPx] = pkr;   // n1r (relu, e2 input)
      } else {
        float ps[4] = {0.f, 0.f, 0.f, 0.f};
        const size_t pb2 = (size_t)b * IMST + (size_t)(R * 34 + C) * 64 + cob;
#pragma unroll
        for (int dy = 0; dy < 3; ++dy)
#pragma unroll
          for (int dx = 0; dx < 3; ++dx) {
            uint2 u = *(const uint2*)&d2[pb2 + (size_t)(dy * 34 + dx) * 64];  // n1T
            ps[0] += bf2f((u16)(u.x & 0xffff));
            ps[1] += bf2f((u16)(u.x >> 16));
            ps[2] += bf2f((u16)(u.y & 0xffff));
            ps[3] += bf2f((u16)(u.y >> 16));
          }
        float rows = 3.f - (R == 0 ? 1.f : 0.f) - (R == 31 ? 1.f : 0.f);
        float cols = 3.f - (C == 0 ? 1.f : 0.f) - (C == 31 ? 1.f : 0.f);
        float inv = 1.f / (rows * cols);
        uint2 pkr;
        float t0v = fmaxf(v[0] + ps[0] * inv * cmL[cob], 0.f);
        float t1v = fmaxf(v[1] + ps[1] * inv * cmL[cob + 1], 0.f);
        float t2v = fmaxf(v[2] + ps[2] * inv * cmL[cob + 2], 0.f);
        float t3v = fmaxf(v[3] + ps[3] * inv * cmL[cob + 3], 0.f);
        pkr.x = pk2(t0v, t1v); pkr.y = pk2(t2v, t3v);
        *(uint2*)&d1[haloPx] = pkr;   // n2r
      }
    }
  }
}

// ---------------- convE23: fused final two convs + output --------------------
__global__ __launch_bounds__(256, 4) void convE23_k(const u16* __restrict__ t0,
                                                    const u16* __restrict__ t1,
                                                    const float* __restrict__ stBase,
                                                    const u16* __restrict__ wE2,
                                                    const u16* __restrict__ wE3,
                                                    float* __restrict__ outp,
                                                    const float* __restrict__ x,
                                                    const float* __restrict__ cm) {
  __shared__ __align__(16) u16 shp2[2 * PATCH];
  __shared__ float cmL[64], biasL[64];
  const int tid = threadIdx.x;
  const int b = blockIdx.y, R0 = blockIdx.x * 2;
  if (tid < 64) {
    cmL[tid] = cm[tid];
    biasL[tid] = stBase[128 + tid] + stBase[2048 + 128 + tid];
  }
  stage_affine(t0 + (size_t)b * IMST + (size_t)R0 * 2176, shp2, tid, R0, stBase);
  stage_affine(t1 + (size_t)b * IMST + (size_t)R0 * 2176, shp2 + PATCH, tid, R0, stBase + 2048);
  __syncthreads();
  const int lane = tid & 63, w = tid >> 6;
  const int ln = lane & 15, quad = lane >> 4;
  const int lr = w >> 1, mh = w & 1;
  f32x4 acc[2][2];
#pragma unroll
  for (int m2 = 0; m2 < 2; ++m2)
#pragma unroll
    for (int nf = 0; nf < 2; ++nf) acc[m2][nf] = (f32x4){0.f, 0.f, 0.f, 0.f};
#pragma unroll 1
  for (int ei = 0; ei < 2; ++ei) {
    const u16* wEp = ei ? wE3 : wE2;
    const u16* sp = &shp2[ei * PATCH];
    const u16* wbase = wEp + (size_t)((mh * 2) * 16 + ln) * 64 + quad * 8;
#pragma unroll 3
    for (int tap = 0; tap < 9; ++tap) {
      const int dy = tap / 3, dx = tap % 3;
      const int px0 = (lr + dy) * 34 + ln + dx;
      bf16x8 A[2][2];
#pragma unroll
      for (int m2 = 0; m2 < 2; ++m2)
#pragma unroll
        for (int h = 0; h < 2; ++h)
          A[m2][h] = *(const bf16x8*)&wbase[(size_t)(tap * 64 + m2 * 16) * 64 + h * 32];
#pragma unroll
      for (int h = 0; h < 2; ++h) {
        const int oct = h * 4 + quad;
        bf16x8 b0 = *(const bf16x8*)&sp[SWZ(px0, oct)];
        bf16x8 b1 = *(const bf16x8*)&sp[SWZ(px0 + 16, oct)];
        acc[0][0] = MFMA16(A[0][h], b0, acc[0][0]);
        acc[0][1] = MFMA16(A[0][h], b1, acc[0][1]);
        acc[1][0] = MFMA16(A[1][h], b0, acc[1][0]);
        acc[1][1] = MFMA16(A[1][h], b1, acc[1][1]);
      }
    }
  }
  const int R = R0 + lr;
#pragma unroll
  for (int m2 = 0; m2 < 2; ++m2) {
    const int cob = (mh * 2 + m2) * 16 + quad * 4;
#pragma unroll
    for (int nf = 0; nf < 2; ++nf) {
      const int C = nf * 16 + ln;
      size_t base = (size_t)b * 65536 + (size_t)cob * 1024 + R * 32 + C;
#pragma unroll
      for (int r = 0; r < 4; ++r)
        outp[base + (size_t)r * 1024] =
            acc[m2][nf][r] + biasL[cob + r] + x[base + (size_t)r * 1024] * cmL[cob + r];
    }
  }
}

extern "C" void kernel_launch(void* const* d_in, const int* in_sizes, int n_in,
                              void* d_out, int out_size, void* d_ws, size_t ws_size,
                              hipStream_t stream) {
  const float* x  = (const float*)d_in[0];
  const float* a1 = (const float*)d_in[1];
  const float* a2 = (const float*)d_in[2];
  const float* W1[4] = {(const float*)d_in[3], (const float*)d_in[5],
                        (const float*)d_in[7], (const float*)d_in[9]};
  const float* W2[4] = {(const float*)d_in[4], (const float*)d_in[6],
                        (const float*)d_in[8], (const float*)d_in[10]};
  float* out = (float*)d_out;
  char* ws = (char*)d_ws;
  const size_t HB = (size_t)IMST * 64 * 2;  // 9,469,952 B per halo buffer
  u16* xT  = (u16*)ws;
  u16* t0  = (u16*)(ws + HB);
  u16* t1  = (u16*)(ws + 2 * HB);
  u16* n1T = (u16*)(ws + 3 * HB);
  u16* n1r = (u16*)(ws + 4 * HB);
  u16* n2r = (u16*)(ws + 5 * HB);
  char* p = ws + 6 * HB;
  float* st  = (float*)p;            p += 8256 * 4;
  u16* wT1   = (u16*)p;              p += 4 * 36864 * 2;
  u16* wG64  = (u16*)p;              p += 4 * 32768 * 2;
  u16* wT8   = (u16*)p;              p += 4 * 4096 * 2;
  u16* wE    = (u16*)p;              p += 4 * 36864 * 2;
  float* pA  = (float*)p;            p += 2 * 1024 * 128 * 4;
  float* pC  = (float*)p;            // 8 * 1024 * 256 * 4 = 8 MB
  float* cm  = st + 8192;

  pack_wT1_k<<<36, 256, 0, stream>>>(W1[0], W1[1], W1[2], W1[3], wT1);
  pack_wG_k<<<dim3(72, 4), 256, 0, stream>>>(W2[0], W2[1], W2[2], W2[3], wG64, wT8);
  transpose_k<<<1024, 256, 0, stream>>>(x, xT);
  zero_halo_k<<<64, 160, 0, stream>>>(n1T);

  dim3 gA(16, 64, 2), gC(16, 64, 2), gE(16, 64);
  // batch edges 0+1 (both consume xT)
  convA_k<<<gA, 256, 0, stream>>>(xT, xT, wT1, wT1 + 36864, t0, t1, pA);
  reducerA_k<<<dim3(64, 2), 256, 0, stream>>>(pA, a1, st);
  convC_k<<<gC, 256, 0, stream>>>(t0, t1, wG64, wT8, st, pC);
  redCprepE_k<<<dim3(64, 2), 256, 0, stream>>>(pC, W2[0], W2[1], a1, a2, st, wE, cm);
  convE_k<0><<<gE, 256, 0, stream>>>(t0, st, wE, n1T, n1r, cm);
  convE_k<1><<<gE, 256, 0, stream>>>(t1, st + 2048, wE + 36864, n2r, n1T, cm);
  // batch edges 2+3 (consume n1r, n2r)
  convA_k<<<gA, 256, 0, stream>>>(n1r, n2r, wT1 + 2 * 36864, wT1 + 3 * 36864, t0, t1, pA);
  reducerA_k<<<dim3(64, 2), 256, 0, stream>>>(pA, a1, st + 4096);
  convC_k<<<gC, 256, 0, stream>>>(t0, t1, wG64 + 2 * 32768, wT8 + 2 * 4096, st + 4096, pC);
  redCprepE_k<<<dim3(64, 2), 256, 0, stream>>>(pC, W2[2], W2[3], a1, a2, st + 4096,
                                               wE + 2 * 36864, cm);
  convE23_k<<<gE, 256, 0, stream>>>(t0, t1, st + 4096, wE + 2 * 36864, wE + 3 * 36864,
                                    out, x, cm);
}

// Round 7
// 458.560 us; speedup vs baseline: 1.2233x; 1.0108x over previous
//
#include <hip/hip_runtime.h>

#define EPS 1e-5f
#define NRED 65536.0f   // B*H*W = 64*32*32
#define IMST 73984      // 34*34*64 halo image stride (elements)
#define PATCH 8704      // 136 px * 64 ci (swizzled, no pad)
#define PATCH6 13056    // 204 px * 64 ci (6-row patch for convC)

typedef short bf16x8 __attribute__((ext_vector_type(8)));
typedef float f32x4 __attribute__((ext_vector_type(4)));
typedef unsigned short u16;

#define MFMA16(a, b, c) __builtin_amdgcn_mfma_f32_16x16x32_bf16(a, b, c, 0, 0, 0)
// XOR-swizzled LDS patch addressing: kills bank conflicts with zero padding.
#define SWZ(px, oct) ((px) * 64 + (((oct) ^ ((px) & 7)) * 8))

__device__ __forceinline__ u16 f2bf(float x) {  // RNE f32->bf16
  union { float f; unsigned u; } v; v.f = x;
  unsigned r = v.u + 0x7FFF + ((v.u >> 16) & 1);
  return (u16)(r >> 16);
}
__device__ __forceinline__ float bf2f(u16 h) {
  union { unsigned u; float f; } v; v.u = ((unsigned)h) << 16;
  return v.f;
}
__device__ __forceinline__ unsigned pk2(float a, float b) {
  return (unsigned)f2bf(a) | ((unsigned)f2bf(b) << 16);
}

// DPP row-shift reduce over 16-lane rows; sum valid in ln==15. Pure VALU.
template <int CTRL>
__device__ __forceinline__ float dpp_mov(float x) {
  int xi = __builtin_bit_cast(int, x);
  int r = __builtin_amdgcn_update_dpp(0, xi, CTRL, 0xF, 0xF, true);
  return __builtin_bit_cast(float, r);
}
__device__ __forceinline__ float row_reduce16(float x) {
  x += dpp_mov<0x111>(x);
  x += dpp_mov<0x112>(x);
  x += dpp_mov<0x114>(x);
  x += dpp_mov<0x118>(x);
  return x;
}

// ---- swizzled patch staging (4 rows x 34 cols x 64 ci) ----------------------
__device__ __forceinline__ void stage_mask(const u16* __restrict__ src,
                                           u16* __restrict__ shp, int tid, int R0) {
#pragma unroll
  for (int i = 0; i < 5; ++i) {
    int c = i * 256 + tid;
    if (i == 4 && tid >= 64) break;
    int px = c >> 3, oct = c & 7;
    int prow = px / 34, pcol = px - prow * 34;
    bool halo = (R0 + prow == 0) || (R0 + prow == 33) || (pcol == 0) || (pcol == 33);
    uint4 v = {0u, 0u, 0u, 0u};
    if (!halo) v = *(const uint4*)&src[(size_t)c * 8];
    *(uint4*)&shp[SWZ(px, oct)] = v;
  }
}

// Affine staging: h = t*s1[ci]+b1[ci] interior, 0 halo (renorm fused).
__device__ __forceinline__ void stage_affine(const u16* __restrict__ src,
                                             u16* __restrict__ shp, int tid, int R0,
                                             const float* __restrict__ stE) {
  const int oct0 = tid & 7;
  float s[8], bb[8];
#pragma unroll
  for (int j = 0; j < 8; ++j) { s[j] = stE[oct0 * 8 + j]; bb[j] = stE[64 + oct0 * 8 + j]; }
#pragma unroll
  for (int i = 0; i < 5; ++i) {
    int c = i * 256 + tid;
    if (i == 4 && tid >= 64) break;
    int px = c >> 3, oct = c & 7;
    int prow = px / 34, pcol = px - prow * 34;
    bool halo = (R0 + prow == 0) || (R0 + prow == 33) || (pcol == 0) || (pcol == 33);
    uint4 o = {0u, 0u, 0u, 0u};
    if (!halo) {
      uint4 u = *(const uint4*)&src[(size_t)c * 8];
      unsigned uv[4] = {u.x, u.y, u.z, u.w};
      unsigned rv[4];
#pragma unroll
      for (int p2 = 0; p2 < 4; ++p2) {
        float lo = bf2f((u16)(uv[p2] & 0xffff)) * s[p2 * 2] + bb[p2 * 2];
        float hi = bf2f((u16)(uv[p2] >> 16)) * s[p2 * 2 + 1] + bb[p2 * 2 + 1];
        rv[p2] = pk2(lo, hi);
      }
      o.x = rv[0]; o.y = rv[1]; o.z = rv[2]; o.w = rv[3];
    }
    *(uint4*)&shp[SWZ(px, oct)] = o;
  }
}

// st layout: per edge e at st+e*2048: [0,64) s1 | [64,128) b1 | [128,192) bias2.

__global__ void pack_wT1_k(const float* __restrict__ w0, const float* __restrict__ w1,
                           const float* __restrict__ w2, const float* __restrict__ w3,
                           u16* __restrict__ wT1) {
  int e = blockIdx.x / 9, tap = blockIdx.x % 9;
  const float* w = e == 0 ? w0 : e == 1 ? w1 : e == 2 ? w2 : w3;
  u16* dst = wT1 + e * 36864 + tap * 4096;
  for (int idx = threadIdx.x; idx < 4096; idx += 256) {
    int co = idx >> 6, ci = idx & 63;
    dst[idx] = f2bf(w[(co * 64 + ci) * 9 + tap]);
  }
}

// wG64[e][g*8+tap(0..7)][co64][cig8] and wT8[e][g][co64][cig8] (tap 8)
__global__ void pack_wG_k(const float* __restrict__ w0, const float* __restrict__ w1,
                          const float* __restrict__ w2, const float* __restrict__ w3,
                          u16* __restrict__ wG64, u16* __restrict__ wT8) {
  int e = blockIdx.y;
  const float* w = e == 0 ? w0 : e == 1 ? w1 : e == 2 ? w2 : w3;
  int bx = blockIdx.x;  // 0..71
  int g, tap;
  u16* dst;
  if (bx < 64) { g = bx >> 3; tap = bx & 7; dst = wG64 + e * 32768 + bx * 512; }
  else         { g = bx - 64; tap = 8;      dst = wT8 + e * 4096 + g * 512; }
  for (int idx = threadIdx.x; idx < 512; idx += 256) {
    int co = idx >> 3, cig = idx & 7;
    dst[idx] = f2bf(w[(co * 64 + g * 8 + cig) * 9 + tap]);
  }
}

// x (NCHW f32) -> xT = bf16(relu(x)) halo pixel-major (interior only).
__global__ __launch_bounds__(256) void transpose_k(const float* __restrict__ x,
                                                   u16* __restrict__ xT) {
  __shared__ __align__(16) u16 sh[64 * 72];
  const int tid = threadIdx.x;
  const int b = blockIdx.x >> 4, slab = blockIdx.x & 15;
  const int ln = tid & 63, w = tid >> 6;
  const float* xb = x + (size_t)b * 65536 + slab * 64;
#pragma unroll
  for (int i = 0; i < 16; ++i) {
    int ci = w + i * 4;
    float v = xb[ci * 1024 + ln];
    sh[ln * 72 + ci] = f2bf(fmaxf(v, 0.f));
  }
  __syncthreads();
  u16* dst = xT + (size_t)b * IMST;
#pragma unroll
  for (int j = 0; j < 2; ++j) {
    int idx = tid + j * 256;
    int p = idx >> 3, oct = idx & 7;
    int gp = slab * 64 + p;
    int R = gp >> 5, C = gp & 31;
    *(uint4*)&dst[((R + 1) * 34 + C + 1) * 64 + oct * 8] = *(const uint4*)&sh[p * 72 + oct * 8];
  }
}

// zero halo strips of n1T (pool reads raw global n1T incl. halo).
__global__ void zero_halo_k(u16* __restrict__ buf) {
  int b = blockIdx.x, tid = threadIdx.x;
  if (tid >= 132) return;
  int R, C;
  if (tid < 34) { R = 0; C = tid; }
  else if (tid < 68) { R = 33; C = tid - 34; }
  else if (tid < 100) { R = tid - 67; C = 0; }
  else { R = tid - 99; C = 33; }
  u16* p = buf + (size_t)b * IMST + (size_t)(R * 34 + C) * 64;
  uint4 z = {0u, 0u, 0u, 0u};
#pragma unroll
  for (int i = 0; i < 8; ++i) *(uint4*)&p[i * 8] = z;
}

// ---------------- convA (2-edge batched): t = conv3x3(xin, W1) + stats -------
// A-fragments streamed from global per tap (coalesced [tap][co][ci] layout,
// L2-resident 147KB) instead of 144-VGPR register cache.
__global__ __launch_bounds__(256, 4) void convA_k(const u16* __restrict__ in0,
                                                  const u16* __restrict__ in1,
                                                  const u16* __restrict__ wTa,
                                                  const u16* __restrict__ wTb,
                                                  u16* __restrict__ t0,
                                                  u16* __restrict__ t1,
                                                  float* __restrict__ pA) {
  __shared__ __align__(16) u16 shp[PATCH];
  __shared__ float sA[64], qA[64];
  const int tid = threadIdx.x;
  const int b = blockIdx.y, R0 = blockIdx.x * 2, z = blockIdx.z;
  const u16* xin = z ? in1 : in0;
  const u16* wT = z ? wTb : wTa;
  u16* t = z ? t1 : t0;
  if (tid < 64) { sA[tid] = 0.f; qA[tid] = 0.f; }
  stage_mask(xin + (size_t)b * IMST + (size_t)R0 * 2176, shp, tid, R0);
  const int lane = tid & 63, w = tid >> 6;
  const int ln = lane & 15, quad = lane >> 4;
  const int lr = w >> 1, mh = w & 1;
  const u16* wbase = wT + (size_t)((mh * 2) * 16 + ln) * 64 + quad * 8;
  __syncthreads();
  f32x4 acc[2][2];
#pragma unroll
  for (int m2 = 0; m2 < 2; ++m2)
#pragma unroll
    for (int nf = 0; nf < 2; ++nf) acc[m2][nf] = (f32x4){0.f, 0.f, 0.f, 0.f};
#pragma unroll 3
  for (int tap = 0; tap < 9; ++tap) {
    const int dy = tap / 3, dx = tap % 3;
    const int px0 = (lr + dy) * 34 + ln + dx;
    bf16x8 A[2][2];
#pragma unroll
    for (int m2 = 0; m2 < 2; ++m2)
#pragma unroll
      for (int h = 0; h < 2; ++h)
        A[m2][h] = *(const bf16x8*)&wbase[(size_t)(tap * 64 + m2 * 16) * 64 + h * 32];
#pragma unroll
    for (int h = 0; h < 2; ++h) {
      const int oct = h * 4 + quad;
      bf16x8 b0 = *(const bf16x8*)&shp[SWZ(px0, oct)];
      bf16x8 b1 = *(const bf16x8*)&shp[SWZ(px0 + 16, oct)];
      acc[0][0] = MFMA16(A[0][h], b0, acc[0][0]);
      acc[0][1] = MFMA16(A[0][h], b1, acc[0][1]);
      acc[1][0] = MFMA16(A[1][h], b0, acc[1][0]);
      acc[1][1] = MFMA16(A[1][h], b1, acc[1][1]);
    }
  }
  const int R = R0 + lr;
#pragma unroll
  for (int m2 = 0; m2 < 2; ++m2) {
    const int cob = (mh * 2 + m2) * 16 + quad * 4;
#pragma unroll
    for (int nf = 0; nf < 2; ++nf) {
      u16* tb = t + (size_t)b * IMST + (size_t)((R + 1) * 34 + nf * 16 + ln + 1) * 64 + cob;
      uint2 pk;
      pk.x = pk2(acc[m2][nf][0], acc[m2][nf][1]);
      pk.y = pk2(acc[m2][nf][2], acc[m2][nf][3]);
      *(uint2*)tb = pk;
    }
#pragma unroll
    for (int r = 0; r < 4; ++r) {
      float v0 = acc[m2][0][r], v1 = acc[m2][1][r];
      float s = row_reduce16(v0) + row_reduce16(v1);
      float q = row_reduce16(v0 * v0) + row_reduce16(v1 * v1);
      if (ln == 15) {
        atomicAdd(&sA[cob + r], s);
        atomicAdd(&qA[cob + r], q);
      }
    }
  }
  __syncthreads();
  const int blk = z * 1024 + blockIdx.y * 16 + blockIdx.x;
  if (tid < 64) pA[blk * 128 + tid] = sA[tid];
  else if (tid < 128) pA[blk * 128 + tid] = qA[tid - 64];
}

// reducerA (batched): grid (64, 2); writes s1/b1 into stBase + z*2048.
__global__ __launch_bounds__(256) void reducerA_k(const float* __restrict__ pA,
                                                  const float* __restrict__ a1,
                                                  float* __restrict__ stBase) {
  const int tid = threadIdx.x, c = blockIdx.x, z = blockIdx.y;
  const float* pAe = pA + (size_t)z * 1024 * 128;
  float s = 0.f, q = 0.f;
  for (int i = tid; i < 1024; i += 256) {
    s += pAe[i * 128 + c];
    q += pAe[i * 128 + 64 + c];
  }
#pragma unroll
  for (int off = 32; off; off >>= 1) { s += __shfl_xor(s, off); q += __shfl_xor(q, off); }
  __shared__ float red[8];
  int wv = tid >> 6;
  if ((tid & 63) == 0) { red[wv] = s; red[4 + wv] = q; }
  __syncthreads();
  if (tid == 0) {
    float S = red[0] + red[1] + red[2] + red[3];
    float Q = red[4] + red[5] + red[6] + red[7];
    int g = c >> 3;
    float m = 0.f;
    for (int i = g; i < 8; ++i) m += a1[i];
    float mu = S * (1.f / NRED);
    float var = Q * (1.f / NRED) - mu * mu;
    float r = rsqrtf(var + EPS);
    float* stE = stBase + z * 2048;
    stE[c] = r * m;
    stE[64 + c] = -mu * r * m;
  }
}

// ---------------- convC: 4-row tile, 8 waves, T14 async shA restage ----------
// grid (8, 64, 2): z = edge. Block 512 thr = 8 waves over 4 out rows x 32 cols.
// Patch 6x34 (26KB) staged once; shA(coq+1) global loads issued into regs
// BEFORE coq's compute (latency hidden under MFMA+stats), ds_write after the
// post-compute barrier. LDS 48.6KB -> 3 blocks/CU = 24 waves (vs 16 before).
__global__ __launch_bounds__(512, 6) void convC_k(const u16* __restrict__ t0,
                                                  const u16* __restrict__ t1,
                                                  const u16* __restrict__ wG64,
                                                  const u16* __restrict__ wT8,
                                                  const float* __restrict__ stBase,
                                                  float* __restrict__ pC) {
  __shared__ __align__(16) u16 shp[PATCH6];       // 26112 B
  __shared__ __align__(16) u16 shA[64 * 16 * 8];  // 16384 B (one co-quarter)
  __shared__ __align__(16) u16 shA2[8 * 16 * 8];  // 2048 B
  __shared__ float sC[4][128], qC[4][128];        // 4096 B
  const int tid = threadIdx.x;
  const int b = blockIdx.y, R0 = blockIdx.x * 4;
  const int edge = blockIdx.z;
  const u16* t = edge ? t1 : t0;
  const float* stE = stBase + edge * 2048;
  const u16* wGe = wG64 + edge * 32768;
  const u16* wT8e = wT8 + edge * 4096;
  ((float*)sC)[tid] = 0.f;
  ((float*)qC)[tid] = 0.f;
  // ---- stage 6-row affine patch (1632 chunks, 512 threads) ----
  {
    const int oct0 = tid & 7;
    float sc[8], bc[8];
#pragma unroll
    for (int j = 0; j < 8; ++j) { sc[j] = stE[oct0 * 8 + j]; bc[j] = stE[64 + oct0 * 8 + j]; }
    const u16* src = t + (size_t)b * IMST + (size_t)R0 * 2176;
#pragma unroll
    for (int i = 0; i < 4; ++i) {
      int c = i * 512 + tid;
      if (i == 3 && tid >= 96) break;
      int px = c >> 3, oct = c & 7;
      int prow = px / 34, pcol = px - prow * 34;
      bool halo = (R0 + prow == 0) || (R0 + prow == 33) || (pcol == 0) || (pcol == 33);
      uint4 o = {0u, 0u, 0u, 0u};
      if (!halo) {
        uint4 u = *(const uint4*)&src[(size_t)c * 8];
        unsigned uv[4] = {u.x, u.y, u.z, u.w};
        unsigned rv[4];
#pragma unroll
        for (int p2 = 0; p2 < 4; ++p2) {
          float lo = bf2f((u16)(uv[p2] & 0xffff)) * sc[p2 * 2] + bc[p2 * 2];
          float hi = bf2f((u16)(uv[p2] >> 16)) * sc[p2 * 2 + 1] + bc[p2 * 2 + 1];
          rv[p2] = pk2(lo, hi);
        }
        o.x = rv[0]; o.y = rv[1]; o.z = rv[2]; o.w = rv[3];
      }
      *(uint4*)&shp[SWZ(px, oct)] = o;
    }
  }
  // ---- stage shA/shA2 for coq=0 (1024 chunks / 128 chunks) ----
#pragma unroll
  for (int i = 0; i < 2; ++i) {
    int c = i * 512 + tid;
    int row = c >> 4, col = c & 15;
    *(uint4*)&shA[c * 8] = *(const uint4*)&wGe[(size_t)(row * 64 + col) * 8];
  }
  if (tid < 128) {
    int g = tid >> 4, col = tid & 15;
    *(uint4*)&shA2[tid * 8] = *(const uint4*)&wT8e[(size_t)(g * 64 + col) * 8];
  }
  __syncthreads();
  const int lane = tid & 63, w = tid >> 6;
  const int ln = lane & 15, quad = lane >> 4;
  const int lrow = w >> 1, colbase = (w & 1) * 16;
  int px[3];
#pragma unroll
  for (int ch = 0; ch < 3; ++ch) {
    int tp = ch * 4 + quad; if (tp > 8) tp = 8;
    px[ch] = (lrow + tp / 3) * 34 + colbase + ln + tp % 3;
  }
#pragma unroll 1
  for (int coq = 0; coq < 4; ++coq) {
    // T14: issue next co-quarter's weight loads into regs before compute
    uint4 wr0, wr1, wr2;
    if (coq < 3) {
      const int nq = coq + 1;
      {
        int c = tid;
        wr0 = *(const uint4*)&wGe[(size_t)((c >> 4) * 64 + nq * 16 + (c & 15)) * 8];
      }
      {
        int c = 512 + tid;
        wr1 = *(const uint4*)&wGe[(size_t)((c >> 4) * 64 + nq * 16 + (c & 15)) * 8];
      }
      if (tid < 128)
        wr2 = *(const uint4*)&wT8e[(size_t)((tid >> 4) * 64 + nq * 16 + (tid & 15)) * 8];
    }
    f32x4 acc[8];
#pragma unroll
    for (int g = 0; g < 8; ++g) acc[g] = (f32x4){0.f, 0.f, 0.f, 0.f};
#pragma unroll
    for (int g = 0; g < 8; ++g) {
#pragma unroll
      for (int ch = 0; ch < 3; ++ch) {
        bf16x8 bx = *(const bf16x8*)&shp[SWZ(px[ch], g)];
        bf16x8 aw;
        if (ch < 2) {
          aw = *(const bf16x8*)&shA[((g * 8 + ch * 4 + quad) * 16 + ln) * 8];
        } else {
          aw = (bf16x8){0, 0, 0, 0, 0, 0, 0, 0};
          if (quad == 0) aw = *(const bf16x8*)&shA2[(g * 16 + ln) * 8];
        }
        acc[g] = MFMA16(aw, bx, acc[g]);
      }
    }
    f32x4 P = (f32x4){0.f, 0.f, 0.f, 0.f};
#pragma unroll
    for (int k = 0; k < 8; ++k) {
      P += acc[k];
#pragma unroll
      for (int r = 0; r < 4; ++r) {
        float v = P[r];
        float s = row_reduce16(v);
        float q = row_reduce16(v * v);
        if (ln == 15) {
          atomicAdd(&sC[coq][k * 16 + quad * 4 + r], s);
          atomicAdd(&qC[coq][k * 16 + quad * 4 + r], q);
        }
      }
    }
    __syncthreads();  // all reads of shA/shA2 for this coq done
    if (coq < 3) {    // write prefetched regs -> LDS
      *(uint4*)&shA[(size_t)tid * 8] = wr0;
      *(uint4*)&shA[(size_t)(512 + tid) * 8] = wr1;
      if (tid < 128) *(uint4*)&shA2[tid * 8] = wr2;
      __syncthreads();
    }
  }
  __syncthreads();
  const int blk = blockIdx.y * 8 + blockIdx.x;  // 0..511
#pragma unroll 1
  for (int coq = 0; coq < 4; ++coq) {
    const size_t base = ((size_t)(edge * 4 + coq) * 512 + blk) * 256;
    if (tid < 128) pC[base + tid] = sC[coq][tid];
    else if (tid < 256) pC[base + 128 + (tid - 128)] = qC[coq][tid - 128];
  }
}

// redCprepE (batched): grid (64, 2): c, z(edge). finalizeC + fold g -> wE.
__global__ __launch_bounds__(256) void redCprepE_k(const float* __restrict__ pC,
                                                   const float* __restrict__ w2a,
                                                   const float* __restrict__ w2b,
                                                   const float* __restrict__ a1,
                                                   const float* __restrict__ a2,
                                                   float* __restrict__ stBase,
                                                   u16* __restrict__ wEbase,
                                                   float* __restrict__ cm) {
  const int tid = threadIdx.x, c = blockIdx.x, z = blockIdx.y;
  const int coq = c >> 4, cl = c & 15;
  const float* w2 = z ? w2b : w2a;
  float* stE = stBase + z * 2048;
  u16* wE = wEbase + z * 36864;
  float s[8], q[8];
#pragma unroll
  for (int k = 0; k < 8; ++k) { s[k] = 0.f; q[k] = 0.f; }
  for (int i = tid; i < 512; i += 256) {
    const float* pb = pC + ((size_t)(z * 4 + coq) * 512 + i) * 256;
#pragma unroll
    for (int k = 0; k < 8; ++k) {
      s[k] += pb[k * 16 + cl];
      q[k] += pb[128 + k * 16 + cl];
    }
  }
#pragma unroll
  for (int k = 0; k < 8; ++k) {
#pragma unroll
    for (int off = 32; off; off >>= 1) { s[k] += __shfl_xor(s[k], off); q[k] += __shfl_xor(q[k], off); }
  }
  __shared__ float red[4][16];
  __shared__ float gL[8];
  int wv = tid >> 6;
  if ((tid & 63) == 0) {
#pragma unroll
    for (int k = 0; k < 8; ++k) { red[wv][k * 2] = s[k]; red[wv][k * 2 + 1] = q[k]; }
  }
  __syncthreads();
  if (tid == 0) {
    float suf = 0.f, bias = 0.f;
    for (int k = 7; k >= 0; --k) {
      float S = red[0][k * 2] + red[1][k * 2] + red[2][k * 2] + red[3][k * 2];
      float Q = red[0][k * 2 + 1] + red[1][k * 2 + 1] + red[2][k * 2 + 1] + red[3][k * 2 + 1];
      float mu = S * (1.f / NRED);
      float var = Q * (1.f / NRED) - mu * mu;
      float rr = rsqrtf(var + EPS);
      bias -= a2[k] * mu * rr;
      suf += a2[k] * rr;
      gL[k] = suf;
    }
    stE[128 + c] = bias;
    if (z == 0) {
      int g = c >> 3;
      float m1 = 0.f, m2 = 0.f;
      for (int i = g; i < 8; ++i) { m1 += a1[i]; m2 += a2[i]; }
      cm[c] = m1 * m2;
    }
  }
  __syncthreads();
  for (int idx = tid; idx < 576; idx += 256) {
    int tap = idx >> 6, ci = idx & 63;
    wE[(tap * 64 + c) * 64 + ci] = f2bf(w2[(c * 64 + ci) * 9 + tap] * gL[ci >> 3]);
  }
}

// ---------------- convE (modes 0,1): conv2 + epilogue ------------------------
// A-fragments streamed from global per tap (same coalesced layout as convA).
template <int MODE>
__global__ __launch_bounds__(256, 4) void convE_k(const u16* __restrict__ t,
                                                  const float* __restrict__ stE,
                                                  const u16* __restrict__ wEp,
                                                  u16* __restrict__ d1,
                                                  u16* __restrict__ d2,
                                                  const float* __restrict__ cm) {
  __shared__ __align__(16) u16 shp[PATCH];
  __shared__ float cmL[64], biasL[64];
  const int tid = threadIdx.x;
  const int b = blockIdx.y, R0 = blockIdx.x * 2;
  if (tid < 64) { cmL[tid] = cm[tid]; biasL[tid] = stE[128 + tid]; }
  stage_affine(t + (size_t)b * IMST + (size_t)R0 * 2176, shp, tid, R0, stE);
  const int lane = tid & 63, w = tid >> 6;
  const int ln = lane & 15, quad = lane >> 4;
  const int lr = w >> 1, mh = w & 1;
  const u16* wbase = wEp + (size_t)((mh * 2) * 16 + ln) * 64 + quad * 8;
  __syncthreads();
  f32x4 acc[2][2];
#pragma unroll
  for (int m2 = 0; m2 < 2; ++m2)
#pragma unroll
    for (int nf = 0; nf < 2; ++nf) acc[m2][nf] = (f32x4){0.f, 0.f, 0.f, 0.f};
#pragma unroll 3
  for (int tap = 0; tap < 9; ++tap) {
    const int dy = tap / 3, dx = tap % 3;
    const int px0 = (lr + dy) * 34 + ln + dx;
    bf16x8 A[2][2];
#pragma unroll
    for (int m2 = 0; m2 < 2; ++m2)
#pragma unroll
      for (int h = 0; h < 2; ++h)
        A[m2][h] = *(const bf16x8*)&wbase[(size_t)(tap * 64 + m2 * 16) * 64 + h * 32];
#pragma unroll
    for (int h = 0; h < 2; ++h) {
      const int oct = h * 4 + quad;
      bf16x8 b0 = *(const bf16x8*)&shp[SWZ(px0, oct)];
      bf16x8 b1 = *(const bf16x8*)&shp[SWZ(px0 + 16, oct)];
      acc[0][0] = MFMA16(A[0][h], b0, acc[0][0]);
      acc[0][1] = MFMA16(A[0][h], b1, acc[0][1]);
      acc[1][0] = MFMA16(A[1][h], b0, acc[1][0]);
      acc[1][1] = MFMA16(A[1][h], b1, acc[1][1]);
    }
  }
  const int R = R0 + lr;
#pragma unroll
  for (int m2 = 0; m2 < 2; ++m2) {
    const int cob = (mh * 2 + m2) * 16 + quad * 4;
#pragma unroll
    for (int nf = 0; nf < 2; ++nf) {
      const int C = nf * 16 + ln;
      const size_t haloPx = (size_t)b * IMST + (size_t)((R + 1) * 34 + C + 1) * 64 + cob;
      float v[4];
#pragma unroll
      for (int r = 0; r < 4; ++r) v[r] = acc[m2][nf][r] + biasL[cob + r];
      if (MODE == 0) {
        uint2 pk, pkr;
        pk.x = pk2(v[0], v[1]); pk.y = pk2(v[2], v[3]);
        pkr.x = pk2(fmaxf(v[0], 0.f), fmaxf(v[1], 0.f));
        pkr.y = pk2(fmaxf(v[2], 0.f), fmaxf(v[3], 0.f));
        *(uint2*)&d1[haloPx] = pk;    // n1T (raw, for pool)
        *(uint2*)&d2[haloPx] = pkr;   // n1r (relu, e2 input)
      } else {
        float ps[4] = {0.f, 0.f, 0.f, 0.f};
        const size_t pb2 = (size_t)b * IMST + (size_t)(R * 34 + C) * 64 + cob;
#pragma unroll
        for (int dy = 0; dy < 3; ++dy)
#pragma unroll
          for (int dx = 0; dx < 3; ++dx) {
            uint2 u = *(const uint2*)&d2[pb2 + (size_t)(dy * 34 + dx) * 64];  // n1T
            ps[0] += bf2f((u16)(u.x & 0xffff));
            ps[1] += bf2f((u16)(u.x >> 16));
            ps[2] += bf2f((u16)(u.y & 0xffff));
            ps[3] += bf2f((u16)(u.y >> 16));
          }
        float rows = 3.f - (R == 0 ? 1.f : 0.f) - (R == 31 ? 1.f : 0.f);
        float cols = 3.f - (C == 0 ? 1.f : 0.f) - (C == 31 ? 1.f : 0.f);
        float inv = 1.f / (rows * cols);
        uint2 pkr;
        float t0v = fmaxf(v[0] + ps[0] * inv * cmL[cob], 0.f);
        float t1v = fmaxf(v[1] + ps[1] * inv * cmL[cob + 1], 0.f);
        float t2v = fmaxf(v[2] + ps[2] * inv * cmL[cob + 2], 0.f);
        float t3v = fmaxf(v[3] + ps[3] * inv * cmL[cob + 3], 0.f);
        pkr.x = pk2(t0v, t1v); pkr.y = pk2(t2v, t3v);
        *(uint2*)&d1[haloPx] = pkr;   // n2r
      }
    }
  }
}

// ---------------- convE23: fused final two convs + output --------------------
__global__ __launch_bounds__(256, 4) void convE23_k(const u16* __restrict__ t0,
                                                    const u16* __restrict__ t1,
                                                    const float* __restrict__ stBase,
                                                    const u16* __restrict__ wE2,
                                                    const u16* __restrict__ wE3,
                                                    float* __restrict__ outp,
                                                    const float* __restrict__ x,
                                                    const float* __restrict__ cm) {
  __shared__ __align__(16) u16 shp2[2 * PATCH];
  __shared__ float cmL[64], biasL[64];
  const int tid = threadIdx.x;
  const int b = blockIdx.y, R0 = blockIdx.x * 2;
  if (tid < 64) {
    cmL[tid] = cm[tid];
    biasL[tid] = stBase[128 + tid] + stBase[2048 + 128 + tid];
  }
  stage_affine(t0 + (size_t)b * IMST + (size_t)R0 * 2176, shp2, tid, R0, stBase);
  stage_affine(t1 + (size_t)b * IMST + (size_t)R0 * 2176, shp2 + PATCH, tid, R0, stBase + 2048);
  __syncthreads();
  const int lane = tid & 63, w = tid >> 6;
  const int ln = lane & 15, quad = lane >> 4;
  const int lr = w >> 1, mh = w & 1;
  f32x4 acc[2][2];
#pragma unroll
  for (int m2 = 0; m2 < 2; ++m2)
#pragma unroll
    for (int nf = 0; nf < 2; ++nf) acc[m2][nf] = (f32x4){0.f, 0.f, 0.f, 0.f};
#pragma unroll 1
  for (int ei = 0; ei < 2; ++ei) {
    const u16* wEp = ei ? wE3 : wE2;
    const u16* sp = &shp2[ei * PATCH];
    const u16* wbase = wEp + (size_t)((mh * 2) * 16 + ln) * 64 + quad * 8;
#pragma unroll 3
    for (int tap = 0; tap < 9; ++tap) {
      const int dy = tap / 3, dx = tap % 3;
      const int px0 = (lr + dy) * 34 + ln + dx;
      bf16x8 A[2][2];
#pragma unroll
      for (int m2 = 0; m2 < 2; ++m2)
#pragma unroll
        for (int h = 0; h < 2; ++h)
          A[m2][h] = *(const bf16x8*)&wbase[(size_t)(tap * 64 + m2 * 16) * 64 + h * 32];
#pragma unroll
      for (int h = 0; h < 2; ++h) {
        const int oct = h * 4 + quad;
        bf16x8 b0 = *(const bf16x8*)&sp[SWZ(px0, oct)];
        bf16x8 b1 = *(const bf16x8*)&sp[SWZ(px0 + 16, oct)];
        acc[0][0] = MFMA16(A[0][h], b0, acc[0][0]);
        acc[0][1] = MFMA16(A[0][h], b1, acc[0][1]);
        acc[1][0] = MFMA16(A[1][h], b0, acc[1][0]);
        acc[1][1] = MFMA16(A[1][h], b1, acc[1][1]);
      }
    }
  }
  const int R = R0 + lr;
#pragma unroll
  for (int m2 = 0; m2 < 2; ++m2) {
    const int cob = (mh * 2 + m2) * 16 + quad * 4;
#pragma unroll
    for (int nf = 0; nf < 2; ++nf) {
      const int C = nf * 16 + ln;
      size_t base = (size_t)b * 65536 + (size_t)cob * 1024 + R * 32 + C;
#pragma unroll
      for (int r = 0; r < 4; ++r)
        outp[base + (size_t)r * 1024] =
            acc[m2][nf][r] + biasL[cob + r] + x[base + (size_t)r * 1024] * cmL[cob + r];
    }
  }
}

extern "C" void kernel_launch(void* const* d_in, const int* in_sizes, int n_in,
                              void* d_out, int out_size, void* d_ws, size_t ws_size,
                              hipStream_t stream) {
  const float* x  = (const float*)d_in[0];
  const float* a1 = (const float*)d_in[1];
  const float* a2 = (const float*)d_in[2];
  const float* W1[4] = {(const float*)d_in[3], (const float*)d_in[5],
                        (const float*)d_in[7], (const float*)d_in[9]};
  const float* W2[4] = {(const float*)d_in[4], (const float*)d_in[6],
                        (const float*)d_in[8], (const float*)d_in[10]};
  float* out = (float*)d_out;
  char* ws = (char*)d_ws;
  const size_t HB = (size_t)IMST * 64 * 2;  // 9,469,952 B per halo buffer
  u16* xT  = (u16*)ws;
  u16* t0  = (u16*)(ws + HB);
  u16* t1  = (u16*)(ws + 2 * HB);
  u16* n1T = (u16*)(ws + 3 * HB);
  u16* n1r = (u16*)(ws + 4 * HB);
  u16* n2r = (u16*)(ws + 5 * HB);
  char* p = ws + 6 * HB;
  float* st  = (float*)p;            p += 8256 * 4;
  u16* wT1   = (u16*)p;              p += 4 * 36864 * 2;
  u16* wG64  = (u16*)p;              p += 4 * 32768 * 2;
  u16* wT8   = (u16*)p;              p += 4 * 4096 * 2;
  u16* wE    = (u16*)p;              p += 4 * 36864 * 2;
  float* pA  = (float*)p;            p += 2 * 1024 * 128 * 4;
  float* pC  = (float*)p;            // 8 * 512 * 256 * 4 = 4 MB
  float* cm  = st + 8192;

  pack_wT1_k<<<36, 256, 0, stream>>>(W1[0], W1[1], W1[2], W1[3], wT1);
  pack_wG_k<<<dim3(72, 4), 256, 0, stream>>>(W2[0], W2[1], W2[2], W2[3], wG64, wT8);
  transpose_k<<<1024, 256, 0, stream>>>(x, xT);
  zero_halo_k<<<64, 160, 0, stream>>>(n1T);

  dim3 gA(16, 64, 2), gC(8, 64, 2), gE(16, 64);
  // batch edges 0+1 (both consume xT)
  convA_k<<<gA, 256, 0, stream>>>(xT, xT, wT1, wT1 + 36864, t0, t1, pA);
  reducerA_k<<<dim3(64, 2), 256, 0, stream>>>(pA, a1, st);
  convC_k<<<gC, 512, 0, stream>>>(t0, t1, wG64, wT8, st, pC);
  redCprepE_k<<<dim3(64, 2), 256, 0, stream>>>(pC, W2[0], W2[1], a1, a2, st, wE, cm);
  convE_k<0><<<gE, 256, 0, stream>>>(t0, st, wE, n1T, n1r, cm);
  convE_k<1><<<gE, 256, 0, stream>>>(t1, st + 2048, wE + 36864, n2r, n1T, cm);
  // batch edges 2+3 (consume n1r, n2r)
  convA_k<<<gA, 256, 0, stream>>>(n1r, n2r, wT1 + 2 * 36864, wT1 + 3 * 36864, t0, t1, pA);
  reducerA_k<<<dim3(64, 2), 256, 0, stream>>>(pA, a1, st + 4096);
  convC_k<<<gC, 512, 0, stream>>>(t0, t1, wG64 + 2 * 32768, wT8 + 2 * 4096, st + 4096, pC);
  redCprepE_k<<<dim3(64, 2), 256, 0, stream>>>(pC, W2[2], W2[3], a1, a2, st + 4096,
                                               wE + 2 * 36864, cm);
  convE23_k<<<gE, 256, 0, stream>>>(t0, t1, st + 4096, wE + 2 * 36864, wE + 3 * 36864,
                                    out, x, cm);
}

// Round 8
// 445.181 us; speedup vs baseline: 1.2601x; 1.0301x over previous
//
#include <hip/hip_runtime.h>

#define EPS 1e-5f
#define NRED 65536.0f   // B*H*W = 64*32*32
#define IMST 73984      // 34*34*64 halo image stride (elements)
#define PATCH 8704      // 136 px * 64 ci (swizzled, no pad)
#define PATCH6 13056    // 204 px * 64 ci (6-row patch for convC)

typedef short bf16x8 __attribute__((ext_vector_type(8)));
typedef float f32x4 __attribute__((ext_vector_type(4)));
typedef unsigned short u16;

#define MFMA16(a, b, c) __builtin_amdgcn_mfma_f32_16x16x32_bf16(a, b, c, 0, 0, 0)
// XOR-swizzled LDS patch addressing: kills bank conflicts with zero padding.
#define SWZ(px, oct) ((px) * 64 + (((oct) ^ ((px) & 7)) * 8))

__device__ __forceinline__ u16 f2bf(float x) {  // RNE f32->bf16
  union { float f; unsigned u; } v; v.f = x;
  unsigned r = v.u + 0x7FFF + ((v.u >> 16) & 1);
  return (u16)(r >> 16);
}
__device__ __forceinline__ float bf2f(u16 h) {
  union { unsigned u; float f; } v; v.u = ((unsigned)h) << 16;
  return v.f;
}
__device__ __forceinline__ unsigned pk2(float a, float b) {
  return (unsigned)f2bf(a) | ((unsigned)f2bf(b) << 16);
}

// DPP row-shift reduce over 16-lane rows; sum valid in ln==15. Pure VALU.
template <int CTRL>
__device__ __forceinline__ float dpp_mov(float x) {
  int xi = __builtin_bit_cast(int, x);
  int r = __builtin_amdgcn_update_dpp(0, xi, CTRL, 0xF, 0xF, true);
  return __builtin_bit_cast(float, r);
}
__device__ __forceinline__ float row_reduce16(float x) {
  x += dpp_mov<0x111>(x);
  x += dpp_mov<0x112>(x);
  x += dpp_mov<0x114>(x);
  x += dpp_mov<0x118>(x);
  return x;
}

// ---- swizzled patch staging (4 rows x 34 cols x 64 ci) ----------------------
__device__ __forceinline__ void stage_mask(const u16* __restrict__ src,
                                           u16* __restrict__ shp, int tid, int R0) {
#pragma unroll
  for (int i = 0; i < 5; ++i) {
    int c = i * 256 + tid;
    if (i == 4 && tid >= 64) break;
    int px = c >> 3, oct = c & 7;
    int prow = px / 34, pcol = px - prow * 34;
    bool halo = (R0 + prow == 0) || (R0 + prow == 33) || (pcol == 0) || (pcol == 33);
    uint4 v = {0u, 0u, 0u, 0u};
    if (!halo) v = *(const uint4*)&src[(size_t)c * 8];
    *(uint4*)&shp[SWZ(px, oct)] = v;
  }
}

// Affine staging: h = t*s1[ci]+b1[ci] interior, 0 halo (renorm fused).
__device__ __forceinline__ void stage_affine(const u16* __restrict__ src,
                                             u16* __restrict__ shp, int tid, int R0,
                                             const float* __restrict__ stE) {
  const int oct0 = tid & 7;
  float s[8], bb[8];
#pragma unroll
  for (int j = 0; j < 8; ++j) { s[j] = stE[oct0 * 8 + j]; bb[j] = stE[64 + oct0 * 8 + j]; }
#pragma unroll
  for (int i = 0; i < 5; ++i) {
    int c = i * 256 + tid;
    if (i == 4 && tid >= 64) break;
    int px = c >> 3, oct = c & 7;
    int prow = px / 34, pcol = px - prow * 34;
    bool halo = (R0 + prow == 0) || (R0 + prow == 33) || (pcol == 0) || (pcol == 33);
    uint4 o = {0u, 0u, 0u, 0u};
    if (!halo) {
      uint4 u = *(const uint4*)&src[(size_t)c * 8];
      unsigned uv[4] = {u.x, u.y, u.z, u.w};
      unsigned rv[4];
#pragma unroll
      for (int p2 = 0; p2 < 4; ++p2) {
        float lo = bf2f((u16)(uv[p2] & 0xffff)) * s[p2 * 2] + bb[p2 * 2];
        float hi = bf2f((u16)(uv[p2] >> 16)) * s[p2 * 2 + 1] + bb[p2 * 2 + 1];
        rv[p2] = pk2(lo, hi);
      }
      o.x = rv[0]; o.y = rv[1]; o.z = rv[2]; o.w = rv[3];
    }
    *(uint4*)&shp[SWZ(px, oct)] = o;
  }
}

// st layout: per edge e at st+e*2048: [0,64) s1 | [64,128) b1 | [128,192) bias2.

__global__ void pack_wT1_k(const float* __restrict__ w0, const float* __restrict__ w1,
                           const float* __restrict__ w2, const float* __restrict__ w3,
                           u16* __restrict__ wT1) {
  int e = blockIdx.x / 9, tap = blockIdx.x % 9;
  const float* w = e == 0 ? w0 : e == 1 ? w1 : e == 2 ? w2 : w3;
  u16* dst = wT1 + e * 36864 + tap * 4096;
  for (int idx = threadIdx.x; idx < 4096; idx += 256) {
    int co = idx >> 6, ci = idx & 63;
    dst[idx] = f2bf(w[(co * 64 + ci) * 9 + tap]);
  }
}

// wG64[e][g*8+tap(0..7)][co64][cig8] and wT8[e][g][co64][cig8] (tap 8)
__global__ void pack_wG_k(const float* __restrict__ w0, const float* __restrict__ w1,
                          const float* __restrict__ w2, const float* __restrict__ w3,
                          u16* __restrict__ wG64, u16* __restrict__ wT8) {
  int e = blockIdx.y;
  const float* w = e == 0 ? w0 : e == 1 ? w1 : e == 2 ? w2 : w3;
  int bx = blockIdx.x;  // 0..71
  int g, tap;
  u16* dst;
  if (bx < 64) { g = bx >> 3; tap = bx & 7; dst = wG64 + e * 32768 + bx * 512; }
  else         { g = bx - 64; tap = 8;      dst = wT8 + e * 4096 + g * 512; }
  for (int idx = threadIdx.x; idx < 512; idx += 256) {
    int co = idx >> 3, cig = idx & 7;
    dst[idx] = f2bf(w[(co * 64 + g * 8 + cig) * 9 + tap]);
  }
}

// x (NCHW f32) -> xT = bf16(relu(x)) halo pixel-major (interior only).
__global__ __launch_bounds__(256) void transpose_k(const float* __restrict__ x,
                                                   u16* __restrict__ xT) {
  __shared__ __align__(16) u16 sh[64 * 72];
  const int tid = threadIdx.x;
  const int b = blockIdx.x >> 4, slab = blockIdx.x & 15;
  const int ln = tid & 63, w = tid >> 6;
  const float* xb = x + (size_t)b * 65536 + slab * 64;
#pragma unroll
  for (int i = 0; i < 16; ++i) {
    int ci = w + i * 4;
    float v = xb[ci * 1024 + ln];
    sh[ln * 72 + ci] = f2bf(fmaxf(v, 0.f));
  }
  __syncthreads();
  u16* dst = xT + (size_t)b * IMST;
#pragma unroll
  for (int j = 0; j < 2; ++j) {
    int idx = tid + j * 256;
    int p = idx >> 3, oct = idx & 7;
    int gp = slab * 64 + p;
    int R = gp >> 5, C = gp & 31;
    *(uint4*)&dst[((R + 1) * 34 + C + 1) * 64 + oct * 8] = *(const uint4*)&sh[p * 72 + oct * 8];
  }
}

// zero halo strips of n1T (pool reads raw global n1T incl. halo).
__global__ void zero_halo_k(u16* __restrict__ buf) {
  int b = blockIdx.x, tid = threadIdx.x;
  if (tid >= 132) return;
  int R, C;
  if (tid < 34) { R = 0; C = tid; }
  else if (tid < 68) { R = 33; C = tid - 34; }
  else if (tid < 100) { R = tid - 67; C = 0; }
  else { R = tid - 99; C = 33; }
  u16* p = buf + (size_t)b * IMST + (size_t)(R * 34 + C) * 64;
  uint4 z = {0u, 0u, 0u, 0u};
#pragma unroll
  for (int i = 0; i < 8; ++i) *(uint4*)&p[i * 8] = z;
}

// ---------------- convA (2-edge batched): t = conv3x3(xin, W1) + stats -------
// A-fragments streamed from global per tap (coalesced [tap][co][ci] layout,
// L2-resident 147KB) instead of 144-VGPR register cache.
__global__ __launch_bounds__(256, 4) void convA_k(const u16* __restrict__ in0,
                                                  const u16* __restrict__ in1,
                                                  const u16* __restrict__ wTa,
                                                  const u16* __restrict__ wTb,
                                                  u16* __restrict__ t0,
                                                  u16* __restrict__ t1,
                                                  float* __restrict__ pA) {
  __shared__ __align__(16) u16 shp[PATCH];
  __shared__ float sA[64], qA[64];
  const int tid = threadIdx.x;
  const int b = blockIdx.y, R0 = blockIdx.x * 2, z = blockIdx.z;
  const u16* xin = z ? in1 : in0;
  const u16* wT = z ? wTb : wTa;
  u16* t = z ? t1 : t0;
  if (tid < 64) { sA[tid] = 0.f; qA[tid] = 0.f; }
  stage_mask(xin + (size_t)b * IMST + (size_t)R0 * 2176, shp, tid, R0);
  const int lane = tid & 63, w = tid >> 6;
  const int ln = lane & 15, quad = lane >> 4;
  const int lr = w >> 1, mh = w & 1;
  const u16* wbase = wT + (size_t)((mh * 2) * 16 + ln) * 64 + quad * 8;
  __syncthreads();
  f32x4 acc[2][2];
#pragma unroll
  for (int m2 = 0; m2 < 2; ++m2)
#pragma unroll
    for (int nf = 0; nf < 2; ++nf) acc[m2][nf] = (f32x4){0.f, 0.f, 0.f, 0.f};
#pragma unroll 3
  for (int tap = 0; tap < 9; ++tap) {
    const int dy = tap / 3, dx = tap % 3;
    const int px0 = (lr + dy) * 34 + ln + dx;
    bf16x8 A[2][2];
#pragma unroll
    for (int m2 = 0; m2 < 2; ++m2)
#pragma unroll
      for (int h = 0; h < 2; ++h)
        A[m2][h] = *(const bf16x8*)&wbase[(size_t)(tap * 64 + m2 * 16) * 64 + h * 32];
#pragma unroll
    for (int h = 0; h < 2; ++h) {
      const int oct = h * 4 + quad;
      bf16x8 b0 = *(const bf16x8*)&shp[SWZ(px0, oct)];
      bf16x8 b1 = *(const bf16x8*)&shp[SWZ(px0 + 16, oct)];
      acc[0][0] = MFMA16(A[0][h], b0, acc[0][0]);
      acc[0][1] = MFMA16(A[0][h], b1, acc[0][1]);
      acc[1][0] = MFMA16(A[1][h], b0, acc[1][0]);
      acc[1][1] = MFMA16(A[1][h], b1, acc[1][1]);
    }
  }
  const int R = R0 + lr;
#pragma unroll
  for (int m2 = 0; m2 < 2; ++m2) {
    const int cob = (mh * 2 + m2) * 16 + quad * 4;
#pragma unroll
    for (int nf = 0; nf < 2; ++nf) {
      u16* tb = t + (size_t)b * IMST + (size_t)((R + 1) * 34 + nf * 16 + ln + 1) * 64 + cob;
      uint2 pk;
      pk.x = pk2(acc[m2][nf][0], acc[m2][nf][1]);
      pk.y = pk2(acc[m2][nf][2], acc[m2][nf][3]);
      *(uint2*)tb = pk;
    }
#pragma unroll
    for (int r = 0; r < 4; ++r) {
      float v0 = acc[m2][0][r], v1 = acc[m2][1][r];
      float s = row_reduce16(v0) + row_reduce16(v1);
      float q = row_reduce16(v0 * v0) + row_reduce16(v1 * v1);
      if (ln == 15) {
        atomicAdd(&sA[cob + r], s);
        atomicAdd(&qA[cob + r], q);
      }
    }
  }
  __syncthreads();
  const int blk = z * 1024 + blockIdx.y * 16 + blockIdx.x;
  if (tid < 64) pA[blk * 128 + tid] = sA[tid];
  else if (tid < 128) pA[blk * 128 + tid] = qA[tid - 64];
}

// reducerA (batched): grid (64, 2); writes s1/b1 into stBase + z*2048.
__global__ __launch_bounds__(256) void reducerA_k(const float* __restrict__ pA,
                                                  const float* __restrict__ a1,
                                                  float* __restrict__ stBase) {
  const int tid = threadIdx.x, c = blockIdx.x, z = blockIdx.y;
  const float* pAe = pA + (size_t)z * 1024 * 128;
  float s = 0.f, q = 0.f;
  for (int i = tid; i < 1024; i += 256) {
    s += pAe[i * 128 + c];
    q += pAe[i * 128 + 64 + c];
  }
#pragma unroll
  for (int off = 32; off; off >>= 1) { s += __shfl_xor(s, off); q += __shfl_xor(q, off); }
  __shared__ float red[8];
  int wv = tid >> 6;
  if ((tid & 63) == 0) { red[wv] = s; red[4 + wv] = q; }
  __syncthreads();
  if (tid == 0) {
    float S = red[0] + red[1] + red[2] + red[3];
    float Q = red[4] + red[5] + red[6] + red[7];
    int g = c >> 3;
    float m = 0.f;
    for (int i = g; i < 8; ++i) m += a1[i];
    float mu = S * (1.f / NRED);
    float var = Q * (1.f / NRED) - mu * mu;
    float r = rsqrtf(var + EPS);
    float* stE = stBase + z * 2048;
    stE[c] = r * m;
    stE[64 + c] = -mu * r * m;
  }
}

// ---------------- convC: 4-row tile, 8 waves, T14 async shA restage ----------
// grid (8, 64, 2): z = edge. Block 512 thr = 8 waves over 4 out rows x 32 cols.
// Patch 6x34 (26KB) staged once; shA(coq+1) global loads issued into regs
// BEFORE coq's compute (latency hidden under MFMA+stats), ds_write after the
// post-compute barrier. LDS 48.6KB -> 3 blocks/CU if VGPR<=85.
// (512,6) in r7 forced a 40-VGPR allocation that spilled the prefetch regs
// (WRITE_SIZE 4MB->40MB); (512,4) caps at 128 so the ~70-reg live set fits.
__global__ __launch_bounds__(512, 4) void convC_k(const u16* __restrict__ t0,
                                                  const u16* __restrict__ t1,
                                                  const u16* __restrict__ wG64,
                                                  const u16* __restrict__ wT8,
                                                  const float* __restrict__ stBase,
                                                  float* __restrict__ pC) {
  __shared__ __align__(16) u16 shp[PATCH6];       // 26112 B
  __shared__ __align__(16) u16 shA[64 * 16 * 8];  // 16384 B (one co-quarter)
  __shared__ __align__(16) u16 shA2[8 * 16 * 8];  // 2048 B
  __shared__ float sC[4][128], qC[4][128];        // 4096 B
  const int tid = threadIdx.x;
  const int b = blockIdx.y, R0 = blockIdx.x * 4;
  const int edge = blockIdx.z;
  const u16* t = edge ? t1 : t0;
  const float* stE = stBase + edge * 2048;
  const u16* wGe = wG64 + edge * 32768;
  const u16* wT8e = wT8 + edge * 4096;
  ((float*)sC)[tid] = 0.f;
  ((float*)qC)[tid] = 0.f;
  // ---- stage 6-row affine patch (1632 chunks, 512 threads) ----
  {
    const int oct0 = tid & 7;
    float sc[8], bc[8];
#pragma unroll
    for (int j = 0; j < 8; ++j) { sc[j] = stE[oct0 * 8 + j]; bc[j] = stE[64 + oct0 * 8 + j]; }
    const u16* src = t + (size_t)b * IMST + (size_t)R0 * 2176;
#pragma unroll
    for (int i = 0; i < 4; ++i) {
      int c = i * 512 + tid;
      if (i == 3 && tid >= 96) break;
      int px = c >> 3, oct = c & 7;
      int prow = px / 34, pcol = px - prow * 34;
      bool halo = (R0 + prow == 0) || (R0 + prow == 33) || (pcol == 0) || (pcol == 33);
      uint4 o = {0u, 0u, 0u, 0u};
      if (!halo) {
        uint4 u = *(const uint4*)&src[(size_t)c * 8];
        unsigned uv[4] = {u.x, u.y, u.z, u.w};
        unsigned rv[4];
#pragma unroll
        for (int p2 = 0; p2 < 4; ++p2) {
          float lo = bf2f((u16)(uv[p2] & 0xffff)) * sc[p2 * 2] + bc[p2 * 2];
          float hi = bf2f((u16)(uv[p2] >> 16)) * sc[p2 * 2 + 1] + bc[p2 * 2 + 1];
          rv[p2] = pk2(lo, hi);
        }
        o.x = rv[0]; o.y = rv[1]; o.z = rv[2]; o.w = rv[3];
      }
      *(uint4*)&shp[SWZ(px, oct)] = o;
    }
  }
  // ---- stage shA/shA2 for coq=0 (1024 chunks / 128 chunks) ----
#pragma unroll
  for (int i = 0; i < 2; ++i) {
    int c = i * 512 + tid;
    int row = c >> 4, col = c & 15;
    *(uint4*)&shA[c * 8] = *(const uint4*)&wGe[(size_t)(row * 64 + col) * 8];
  }
  if (tid < 128) {
    int g = tid >> 4, col = tid & 15;
    *(uint4*)&shA2[tid * 8] = *(const uint4*)&wT8e[(size_t)(g * 64 + col) * 8];
  }
  __syncthreads();
  const int lane = tid & 63, w = tid >> 6;
  const int ln = lane & 15, quad = lane >> 4;
  const int lrow = w >> 1, colbase = (w & 1) * 16;
  int px[3];
#pragma unroll
  for (int ch = 0; ch < 3; ++ch) {
    int tp = ch * 4 + quad; if (tp > 8) tp = 8;
    px[ch] = (lrow + tp / 3) * 34 + colbase + ln + tp % 3;
  }
#pragma unroll 1
  for (int coq = 0; coq < 4; ++coq) {
    // T14: issue next co-quarter's weight loads into regs before compute
    uint4 wr0, wr1, wr2;
    if (coq < 3) {
      const int nq = coq + 1;
      {
        int c = tid;
        wr0 = *(const uint4*)&wGe[(size_t)((c >> 4) * 64 + nq * 16 + (c & 15)) * 8];
      }
      {
        int c = 512 + tid;
        wr1 = *(const uint4*)&wGe[(size_t)((c >> 4) * 64 + nq * 16 + (c & 15)) * 8];
      }
      if (tid < 128)
        wr2 = *(const uint4*)&wT8e[(size_t)((tid >> 4) * 64 + nq * 16 + (tid & 15)) * 8];
    }
    f32x4 acc[8];
#pragma unroll
    for (int g = 0; g < 8; ++g) acc[g] = (f32x4){0.f, 0.f, 0.f, 0.f};
#pragma unroll
    for (int g = 0; g < 8; ++g) {
#pragma unroll
      for (int ch = 0; ch < 3; ++ch) {
        bf16x8 bx = *(const bf16x8*)&shp[SWZ(px[ch], g)];
        bf16x8 aw;
        if (ch < 2) {
          aw = *(const bf16x8*)&shA[((g * 8 + ch * 4 + quad) * 16 + ln) * 8];
        } else {
          aw = (bf16x8){0, 0, 0, 0, 0, 0, 0, 0};
          if (quad == 0) aw = *(const bf16x8*)&shA2[(g * 16 + ln) * 8];
        }
        acc[g] = MFMA16(aw, bx, acc[g]);
      }
    }
    f32x4 P = (f32x4){0.f, 0.f, 0.f, 0.f};
#pragma unroll
    for (int k = 0; k < 8; ++k) {
      P += acc[k];
#pragma unroll
      for (int r = 0; r < 4; ++r) {
        float v = P[r];
        float s = row_reduce16(v);
        float q = row_reduce16(v * v);
        if (ln == 15) {
          atomicAdd(&sC[coq][k * 16 + quad * 4 + r], s);
          atomicAdd(&qC[coq][k * 16 + quad * 4 + r], q);
        }
      }
    }
    __syncthreads();  // all reads of shA/shA2 for this coq done
    if (coq < 3) {    // write prefetched regs -> LDS
      *(uint4*)&shA[(size_t)tid * 8] = wr0;
      *(uint4*)&shA[(size_t)(512 + tid) * 8] = wr1;
      if (tid < 128) *(uint4*)&shA2[tid * 8] = wr2;
      __syncthreads();
    }
  }
  __syncthreads();
  const int blk = blockIdx.y * 8 + blockIdx.x;  // 0..511
#pragma unroll 1
  for (int coq = 0; coq < 4; ++coq) {
    const size_t base = ((size_t)(edge * 4 + coq) * 512 + blk) * 256;
    if (tid < 128) pC[base + tid] = sC[coq][tid];
    else if (tid < 256) pC[base + 128 + (tid - 128)] = qC[coq][tid - 128];
  }
}

// redCprepE (batched): grid (64, 2): c, z(edge). finalizeC + fold g -> wE.
__global__ __launch_bounds__(256) void redCprepE_k(const float* __restrict__ pC,
                                                   const float* __restrict__ w2a,
                                                   const float* __restrict__ w2b,
                                                   const float* __restrict__ a1,
                                                   const float* __restrict__ a2,
                                                   float* __restrict__ stBase,
                                                   u16* __restrict__ wEbase,
                                                   float* __restrict__ cm) {
  const int tid = threadIdx.x, c = blockIdx.x, z = blockIdx.y;
  const int coq = c >> 4, cl = c & 15;
  const float* w2 = z ? w2b : w2a;
  float* stE = stBase + z * 2048;
  u16* wE = wEbase + z * 36864;
  float s[8], q[8];
#pragma unroll
  for (int k = 0; k < 8; ++k) { s[k] = 0.f; q[k] = 0.f; }
  for (int i = tid; i < 512; i += 256) {
    const float* pb = pC + ((size_t)(z * 4 + coq) * 512 + i) * 256;
#pragma unroll
    for (int k = 0; k < 8; ++k) {
      s[k] += pb[k * 16 + cl];
      q[k] += pb[128 + k * 16 + cl];
    }
  }
#pragma unroll
  for (int k = 0; k < 8; ++k) {
#pragma unroll
    for (int off = 32; off; off >>= 1) { s[k] += __shfl_xor(s[k], off); q[k] += __shfl_xor(q[k], off); }
  }
  __shared__ float red[4][16];
  __shared__ float gL[8];
  int wv = tid >> 6;
  if ((tid & 63) == 0) {
#pragma unroll
    for (int k = 0; k < 8; ++k) { red[wv][k * 2] = s[k]; red[wv][k * 2 + 1] = q[k]; }
  }
  __syncthreads();
  if (tid == 0) {
    float suf = 0.f, bias = 0.f;
    for (int k = 7; k >= 0; --k) {
      float S = red[0][k * 2] + red[1][k * 2] + red[2][k * 2] + red[3][k * 2];
      float Q = red[0][k * 2 + 1] + red[1][k * 2 + 1] + red[2][k * 2 + 1] + red[3][k * 2 + 1];
      float mu = S * (1.f / NRED);
      float var = Q * (1.f / NRED) - mu * mu;
      float rr = rsqrtf(var + EPS);
      bias -= a2[k] * mu * rr;
      suf += a2[k] * rr;
      gL[k] = suf;
    }
    stE[128 + c] = bias;
    if (z == 0) {
      int g = c >> 3;
      float m1 = 0.f, m2 = 0.f;
      for (int i = g; i < 8; ++i) { m1 += a1[i]; m2 += a2[i]; }
      cm[c] = m1 * m2;
    }
  }
  __syncthreads();
  for (int idx = tid; idx < 576; idx += 256) {
    int tap = idx >> 6, ci = idx & 63;
    wE[(tap * 64 + c) * 64 + ci] = f2bf(w2[(c * 64 + ci) * 9 + tap] * gL[ci >> 3]);
  }
}

// ---------------- convE (modes 0,1): conv2 + epilogue ------------------------
// A-fragments streamed from global per tap (same coalesced layout as convA).
template <int MODE>
__global__ __launch_bounds__(256, 4) void convE_k(const u16* __restrict__ t,
                                                  const float* __restrict__ stE,
                                                  const u16* __restrict__ wEp,
                                                  u16* __restrict__ d1,
                                                  u16* __restrict__ d2,
                                                  const float* __restrict__ cm) {
  __shared__ __align__(16) u16 shp[PATCH];
  __shared__ float cmL[64], biasL[64];
  const int tid = threadIdx.x;
  const int b = blockIdx.y, R0 = blockIdx.x * 2;
  if (tid < 64) { cmL[tid] = cm[tid]; biasL[tid] = stE[128 + tid]; }
  stage_affine(t + (size_t)b * IMST + (size_t)R0 * 2176, shp, tid, R0, stE);
  const int lane = tid & 63, w = tid >> 6;
  const int ln = lane & 15, quad = lane >> 4;
  const int lr = w >> 1, mh = w & 1;
  const u16* wbase = wEp + (size_t)((mh * 2) * 16 + ln) * 64 + quad * 8;
  __syncthreads();
  f32x4 acc[2][2];
#pragma unroll
  for (int m2 = 0; m2 < 2; ++m2)
#pragma unroll
    for (int nf = 0; nf < 2; ++nf) acc[m2][nf] = (f32x4){0.f, 0.f, 0.f, 0.f};
#pragma unroll 3
  for (int tap = 0; tap < 9; ++tap) {
    const int dy = tap / 3, dx = tap % 3;
    const int px0 = (lr + dy) * 34 + ln + dx;
    bf16x8 A[2][2];
#pragma unroll
    for (int m2 = 0; m2 < 2; ++m2)
#pragma unroll
      for (int h = 0; h < 2; ++h)
        A[m2][h] = *(const bf16x8*)&wbase[(size_t)(tap * 64 + m2 * 16) * 64 + h * 32];
#pragma unroll
    for (int h = 0; h < 2; ++h) {
      const int oct = h * 4 + quad;
      bf16x8 b0 = *(const bf16x8*)&shp[SWZ(px0, oct)];
      bf16x8 b1 = *(const bf16x8*)&shp[SWZ(px0 + 16, oct)];
      acc[0][0] = MFMA16(A[0][h], b0, acc[0][0]);
      acc[0][1] = MFMA16(A[0][h], b1, acc[0][1]);
      acc[1][0] = MFMA16(A[1][h], b0, acc[1][0]);
      acc[1][1] = MFMA16(A[1][h], b1, acc[1][1]);
    }
  }
  const int R = R0 + lr;
#pragma unroll
  for (int m2 = 0; m2 < 2; ++m2) {
    const int cob = (mh * 2 + m2) * 16 + quad * 4;
#pragma unroll
    for (int nf = 0; nf < 2; ++nf) {
      const int C = nf * 16 + ln;
      const size_t haloPx = (size_t)b * IMST + (size_t)((R + 1) * 34 + C + 1) * 64 + cob;
      float v[4];
#pragma unroll
      for (int r = 0; r < 4; ++r) v[r] = acc[m2][nf][r] + biasL[cob + r];
      if (MODE == 0) {
        uint2 pk, pkr;
        pk.x = pk2(v[0], v[1]); pk.y = pk2(v[2], v[3]);
        pkr.x = pk2(fmaxf(v[0], 0.f), fmaxf(v[1], 0.f));
        pkr.y = pk2(fmaxf(v[2], 0.f), fmaxf(v[3], 0.f));
        *(uint2*)&d1[haloPx] = pk;    // n1T (raw, for pool)
        *(uint2*)&d2[haloPx] = pkr;   // n1r (relu, e2 input)
      } else {
        float ps[4] = {0.f, 0.f, 0.f, 0.f};
        const size_t pb2 = (size_t)b * IMST + (size_t)(R * 34 + C) * 64 + cob;
#pragma unroll
        for (int dy = 0; dy < 3; ++dy)
#pragma unroll
          for (int dx = 0; dx < 3; ++dx) {
            uint2 u = *(const uint2*)&d2[pb2 + (size_t)(dy * 34 + dx) * 64];  // n1T
            ps[0] += bf2f((u16)(u.x & 0xffff));
            ps[1] += bf2f((u16)(u.x >> 16));
            ps[2] += bf2f((u16)(u.y & 0xffff));
            ps[3] += bf2f((u16)(u.y >> 16));
          }
        float rows = 3.f - (R == 0 ? 1.f : 0.f) - (R == 31 ? 1.f : 0.f);
        float cols = 3.f - (C == 0 ? 1.f : 0.f) - (C == 31 ? 1.f : 0.f);
        float inv = 1.f / (rows * cols);
        uint2 pkr;
        float t0v = fmaxf(v[0] + ps[0] * inv * cmL[cob], 0.f);
        float t1v = fmaxf(v[1] + ps[1] * inv * cmL[cob + 1], 0.f);
        float t2v = fmaxf(v[2] + ps[2] * inv * cmL[cob + 2], 0.f);
        float t3v = fmaxf(v[3] + ps[3] * inv * cmL[cob + 3], 0.f);
        pkr.x = pk2(t0v, t1v); pkr.y = pk2(t2v, t3v);
        *(uint2*)&d1[haloPx] = pkr;   // n2r
      }
    }
  }
}

// ---------------- convE23: fused final two convs + output --------------------
__global__ __launch_bounds__(256, 4) void convE23_k(const u16* __restrict__ t0,
                                                    const u16* __restrict__ t1,
                                                    const float* __restrict__ stBase,
                                                    const u16* __restrict__ wE2,
                                                    const u16* __restrict__ wE3,
                                                    float* __restrict__ outp,
                                                    const float* __restrict__ x,
                                                    const float* __restrict__ cm) {
  __shared__ __align__(16) u16 shp2[2 * PATCH];
  __shared__ float cmL[64], biasL[64];
  const int tid = threadIdx.x;
  const int b = blockIdx.y, R0 = blockIdx.x * 2;
  if (tid < 64) {
    cmL[tid] = cm[tid];
    biasL[tid] = stBase[128 + tid] + stBase[2048 + 128 + tid];
  }
  stage_affine(t0 + (size_t)b * IMST + (size_t)R0 * 2176, shp2, tid, R0, stBase);
  stage_affine(t1 + (size_t)b * IMST + (size_t)R0 * 2176, shp2 + PATCH, tid, R0, stBase + 2048);
  __syncthreads();
  const int lane = tid & 63, w = tid >> 6;
  const int ln = lane & 15, quad = lane >> 4;
  const int lr = w >> 1, mh = w & 1;
  f32x4 acc[2][2];
#pragma unroll
  for (int m2 = 0; m2 < 2; ++m2)
#pragma unroll
    for (int nf = 0; nf < 2; ++nf) acc[m2][nf] = (f32x4){0.f, 0.f, 0.f, 0.f};
#pragma unroll 1
  for (int ei = 0; ei < 2; ++ei) {
    const u16* wEp = ei ? wE3 : wE2;
    const u16* sp = &shp2[ei * PATCH];
    const u16* wbase = wEp + (size_t)((mh * 2) * 16 + ln) * 64 + quad * 8;
#pragma unroll 3
    for (int tap = 0; tap < 9; ++tap) {
      const int dy = tap / 3, dx = tap % 3;
      const int px0 = (lr + dy) * 34 + ln + dx;
      bf16x8 A[2][2];
#pragma unroll
      for (int m2 = 0; m2 < 2; ++m2)
#pragma unroll
        for (int h = 0; h < 2; ++h)
          A[m2][h] = *(const bf16x8*)&wbase[(size_t)(tap * 64 + m2 * 16) * 64 + h * 32];
#pragma unroll
      for (int h = 0; h < 2; ++h) {
        const int oct = h * 4 + quad;
        bf16x8 b0 = *(const bf16x8*)&sp[SWZ(px0, oct)];
        bf16x8 b1 = *(const bf16x8*)&sp[SWZ(px0 + 16, oct)];
        acc[0][0] = MFMA16(A[0][h], b0, acc[0][0]);
        acc[0][1] = MFMA16(A[0][h], b1, acc[0][1]);
        acc[1][0] = MFMA16(A[1][h], b0, acc[1][0]);
        acc[1][1] = MFMA16(A[1][h], b1, acc[1][1]);
      }
    }
  }
  const int R = R0 + lr;
#pragma unroll
  for (int m2 = 0; m2 < 2; ++m2) {
    const int cob = (mh * 2 + m2) * 16 + quad * 4;
#pragma unroll
    for (int nf = 0; nf < 2; ++nf) {
      const int C = nf * 16 + ln;
      size_t base = (size_t)b * 65536 + (size_t)cob * 1024 + R * 32 + C;
#pragma unroll
      for (int r = 0; r < 4; ++r)
        outp[base + (size_t)r * 1024] =
            acc[m2][nf][r] + biasL[cob + r] + x[base + (size_t)r * 1024] * cmL[cob + r];
    }
  }
}

extern "C" void kernel_launch(void* const* d_in, const int* in_sizes, int n_in,
                              void* d_out, int out_size, void* d_ws, size_t ws_size,
                              hipStream_t stream) {
  const float* x  = (const float*)d_in[0];
  const float* a1 = (const float*)d_in[1];
  const float* a2 = (const float*)d_in[2];
  const float* W1[4] = {(const float*)d_in[3], (const float*)d_in[5],
                        (const float*)d_in[7], (const float*)d_in[9]};
  const float* W2[4] = {(const float*)d_in[4], (const float*)d_in[6],
                        (const float*)d_in[8], (const float*)d_in[10]};
  float* out = (float*)d_out;
  char* ws = (char*)d_ws;
  const size_t HB = (size_t)IMST * 64 * 2;  // 9,469,952 B per halo buffer
  u16* xT  = (u16*)ws;
  u16* t0  = (u16*)(ws + HB);
  u16* t1  = (u16*)(ws + 2 * HB);
  u16* n1T = (u16*)(ws + 3 * HB);
  u16* n1r = (u16*)(ws + 4 * HB);
  u16* n2r = (u16*)(ws + 5 * HB);
  char* p = ws + 6 * HB;
  float* st  = (float*)p;            p += 8256 * 4;
  u16* wT1   = (u16*)p;              p += 4 * 36864 * 2;
  u16* wG64  = (u16*)p;              p += 4 * 32768 * 2;
  u16* wT8   = (u16*)p;              p += 4 * 4096 * 2;
  u16* wE    = (u16*)p;              p += 4 * 36864 * 2;
  float* pA  = (float*)p;            p += 2 * 1024 * 128 * 4;
  float* pC  = (float*)p;            // 8 * 512 * 256 * 4 = 4 MB
  float* cm  = st + 8192;

  pack_wT1_k<<<36, 256, 0, stream>>>(W1[0], W1[1], W1[2], W1[3], wT1);
  pack_wG_k<<<dim3(72, 4), 256, 0, stream>>>(W2[0], W2[1], W2[2], W2[3], wG64, wT8);
  transpose_k<<<1024, 256, 0, stream>>>(x, xT);
  zero_halo_k<<<64, 160, 0, stream>>>(n1T);

  dim3 gA(16, 64, 2), gC(8, 64, 2), gE(16, 64);
  // batch edges 0+1 (both consume xT)
  convA_k<<<gA, 256, 0, stream>>>(xT, xT, wT1, wT1 + 36864, t0, t1, pA);
  reducerA_k<<<dim3(64, 2), 256, 0, stream>>>(pA, a1, st);
  convC_k<<<gC, 512, 0, stream>>>(t0, t1, wG64, wT8, st, pC);
  redCprepE_k<<<dim3(64, 2), 256, 0, stream>>>(pC, W2[0], W2[1], a1, a2, st, wE, cm);
  convE_k<0><<<gE, 256, 0, stream>>>(t0, st, wE, n1T, n1r, cm);
  convE_k<1><<<gE, 256, 0, stream>>>(t1, st + 2048, wE + 36864, n2r, n1T, cm);
  // batch edges 2+3 (consume n1r, n2r)
  convA_k<<<gA, 256, 0, stream>>>(n1r, n2r, wT1 + 2 * 36864, wT1 + 3 * 36864, t0, t1, pA);
  reducerA_k<<<dim3(64, 2), 256, 0, stream>>>(pA, a1, st + 4096);
  convC_k<<<gC, 512, 0, stream>>>(t0, t1, wG64 + 2 * 32768, wT8 + 2 * 4096, st + 4096, pC);
  redCprepE_k<<<dim3(64, 2), 256, 0, stream>>>(pC, W2[2], W2[3], a1, a2, st + 4096,
                                               wE + 2 * 36864, cm);
  convE23_k<<<gE, 256, 0, stream>>>(t0, t1, st + 4096, wE + 2 * 36864, wE + 3 * 36864,
                                    out, x, cm);
}

// Round 9
// 430.948 us; speedup vs baseline: 1.3017x; 1.0330x over previous
//
#include <hip/hip_runtime.h>

#define EPS 1e-5f
#define NRED 65536.0f   // B*H*W = 64*32*32
#define IMST 73984      // 34*34*64 halo image stride (elements)
#define PATCH 8704      // 136 px * 64 ci (swizzled, no pad)
#define PATCH6 13056    // 204 px * 64 ci (6-row patch for convC)

typedef short bf16x8 __attribute__((ext_vector_type(8)));
typedef float f32x4 __attribute__((ext_vector_type(4)));
typedef unsigned short u16;

#define MFMA16(a, b, c) __builtin_amdgcn_mfma_f32_16x16x32_bf16(a, b, c, 0, 0, 0)
// XOR-swizzled LDS patch addressing: kills bank conflicts with zero padding.
#define SWZ(px, oct) ((px) * 64 + (((oct) ^ ((px) & 7)) * 8))

__device__ __forceinline__ u16 f2bf(float x) {  // RNE f32->bf16
  union { float f; unsigned u; } v; v.f = x;
  unsigned r = v.u + 0x7FFF + ((v.u >> 16) & 1);
  return (u16)(r >> 16);
}
__device__ __forceinline__ float bf2f(u16 h) {
  union { unsigned u; float f; } v; v.u = ((unsigned)h) << 16;
  return v.f;
}
__device__ __forceinline__ unsigned pk2(float a, float b) {
  return (unsigned)f2bf(a) | ((unsigned)f2bf(b) << 16);
}

// DPP row-shift reduce over 16-lane rows; sum valid in ln==15. Pure VALU.
template <int CTRL>
__device__ __forceinline__ float dpp_mov(float x) {
  int xi = __builtin_bit_cast(int, x);
  int r = __builtin_amdgcn_update_dpp(0, xi, CTRL, 0xF, 0xF, true);
  return __builtin_bit_cast(float, r);
}
__device__ __forceinline__ float row_reduce16(float x) {
  x += dpp_mov<0x111>(x);
  x += dpp_mov<0x112>(x);
  x += dpp_mov<0x114>(x);
  x += dpp_mov<0x118>(x);
  return x;
}

// ---- swizzled patch staging (4 rows x 34 cols x 64 ci) ----------------------
__device__ __forceinline__ void stage_mask(const u16* __restrict__ src,
                                           u16* __restrict__ shp, int tid, int R0) {
#pragma unroll
  for (int i = 0; i < 5; ++i) {
    int c = i * 256 + tid;
    if (i == 4 && tid >= 64) break;
    int px = c >> 3, oct = c & 7;
    int prow = px / 34, pcol = px - prow * 34;
    bool halo = (R0 + prow == 0) || (R0 + prow == 33) || (pcol == 0) || (pcol == 33);
    uint4 v = {0u, 0u, 0u, 0u};
    if (!halo) v = *(const uint4*)&src[(size_t)c * 8];
    *(uint4*)&shp[SWZ(px, oct)] = v;
  }
}

// Affine staging: h = t*s1[ci]+b1[ci] interior, 0 halo (renorm fused).
__device__ __forceinline__ void stage_affine(const u16* __restrict__ src,
                                             u16* __restrict__ shp, int tid, int R0,
                                             const float* __restrict__ stE) {
  const int oct0 = tid & 7;
  float s[8], bb[8];
#pragma unroll
  for (int j = 0; j < 8; ++j) { s[j] = stE[oct0 * 8 + j]; bb[j] = stE[64 + oct0 * 8 + j]; }
#pragma unroll
  for (int i = 0; i < 5; ++i) {
    int c = i * 256 + tid;
    if (i == 4 && tid >= 64) break;
    int px = c >> 3, oct = c & 7;
    int prow = px / 34, pcol = px - prow * 34;
    bool halo = (R0 + prow == 0) || (R0 + prow == 33) || (pcol == 0) || (pcol == 33);
    uint4 o = {0u, 0u, 0u, 0u};
    if (!halo) {
      uint4 u = *(const uint4*)&src[(size_t)c * 8];
      unsigned uv[4] = {u.x, u.y, u.z, u.w};
      unsigned rv[4];
#pragma unroll
      for (int p2 = 0; p2 < 4; ++p2) {
        float lo = bf2f((u16)(uv[p2] & 0xffff)) * s[p2 * 2] + bb[p2 * 2];
        float hi = bf2f((u16)(uv[p2] >> 16)) * s[p2 * 2 + 1] + bb[p2 * 2 + 1];
        rv[p2] = pk2(lo, hi);
      }
      o.x = rv[0]; o.y = rv[1]; o.z = rv[2]; o.w = rv[3];
    }
    *(uint4*)&shp[SWZ(px, oct)] = o;
  }
}

// st layout: per edge e at st+e*2048: [0,64) s1 | [64,128) b1 | [128,192) bias2.

__global__ void pack_wT1_k(const float* __restrict__ w0, const float* __restrict__ w1,
                           const float* __restrict__ w2, const float* __restrict__ w3,
                           u16* __restrict__ wT1) {
  int e = blockIdx.x / 9, tap = blockIdx.x % 9;
  const float* w = e == 0 ? w0 : e == 1 ? w1 : e == 2 ? w2 : w3;
  u16* dst = wT1 + e * 36864 + tap * 4096;
  for (int idx = threadIdx.x; idx < 4096; idx += 256) {
    int co = idx >> 6, ci = idx & 63;
    dst[idx] = f2bf(w[(co * 64 + ci) * 9 + tap]);
  }
}

// wG64[e][g*8+tap(0..7)][co64][cig8] and wT8[e][g][co64][cig8] (tap 8)
__global__ void pack_wG_k(const float* __restrict__ w0, const float* __restrict__ w1,
                          const float* __restrict__ w2, const float* __restrict__ w3,
                          u16* __restrict__ wG64, u16* __restrict__ wT8) {
  int e = blockIdx.y;
  const float* w = e == 0 ? w0 : e == 1 ? w1 : e == 2 ? w2 : w3;
  int bx = blockIdx.x;  // 0..71
  int g, tap;
  u16* dst;
  if (bx < 64) { g = bx >> 3; tap = bx & 7; dst = wG64 + e * 32768 + bx * 512; }
  else         { g = bx - 64; tap = 8;      dst = wT8 + e * 4096 + g * 512; }
  for (int idx = threadIdx.x; idx < 512; idx += 256) {
    int co = idx >> 3, cig = idx & 7;
    dst[idx] = f2bf(w[(co * 64 + g * 8 + cig) * 9 + tap]);
  }
}

// x (NCHW f32) -> xT = bf16(relu(x)) halo pixel-major (interior only).
__global__ __launch_bounds__(256) void transpose_k(const float* __restrict__ x,
                                                   u16* __restrict__ xT) {
  __shared__ __align__(16) u16 sh[64 * 72];
  const int tid = threadIdx.x;
  const int b = blockIdx.x >> 4, slab = blockIdx.x & 15;
  const int ln = tid & 63, w = tid >> 6;
  const float* xb = x + (size_t)b * 65536 + slab * 64;
#pragma unroll
  for (int i = 0; i < 16; ++i) {
    int ci = w + i * 4;
    float v = xb[ci * 1024 + ln];
    sh[ln * 72 + ci] = f2bf(fmaxf(v, 0.f));
  }
  __syncthreads();
  u16* dst = xT + (size_t)b * IMST;
#pragma unroll
  for (int j = 0; j < 2; ++j) {
    int idx = tid + j * 256;
    int p = idx >> 3, oct = idx & 7;
    int gp = slab * 64 + p;
    int R = gp >> 5, C = gp & 31;
    *(uint4*)&dst[((R + 1) * 34 + C + 1) * 64 + oct * 8] = *(const uint4*)&sh[p * 72 + oct * 8];
  }
}

// zero halo strips of n1T (pool reads raw global n1T incl. halo).
__global__ void zero_halo_k(u16* __restrict__ buf) {
  int b = blockIdx.x, tid = threadIdx.x;
  if (tid >= 132) return;
  int R, C;
  if (tid < 34) { R = 0; C = tid; }
  else if (tid < 68) { R = 33; C = tid - 34; }
  else if (tid < 100) { R = tid - 67; C = 0; }
  else { R = tid - 99; C = 33; }
  u16* p = buf + (size_t)b * IMST + (size_t)(R * 34 + C) * 64;
  uint4 z = {0u, 0u, 0u, 0u};
#pragma unroll
  for (int i = 0; i < 8; ++i) *(uint4*)&p[i * 8] = z;
}

// ---------------- convA (2-edge batched): t = conv3x3(xin, W1) + stats -------
// A-fragments streamed from global per tap (coalesced [tap][co][ci] layout,
// L2-resident 147KB) instead of 144-VGPR register cache.
__global__ __launch_bounds__(256, 4) void convA_k(const u16* __restrict__ in0,
                                                  const u16* __restrict__ in1,
                                                  const u16* __restrict__ wTa,
                                                  const u16* __restrict__ wTb,
                                                  u16* __restrict__ t0,
                                                  u16* __restrict__ t1,
                                                  float* __restrict__ pA) {
  __shared__ __align__(16) u16 shp[PATCH];
  __shared__ float sA[64], qA[64];
  const int tid = threadIdx.x;
  const int b = blockIdx.y, R0 = blockIdx.x * 2, z = blockIdx.z;
  const u16* xin = z ? in1 : in0;
  const u16* wT = z ? wTb : wTa;
  u16* t = z ? t1 : t0;
  if (tid < 64) { sA[tid] = 0.f; qA[tid] = 0.f; }
  stage_mask(xin + (size_t)b * IMST + (size_t)R0 * 2176, shp, tid, R0);
  const int lane = tid & 63, w = tid >> 6;
  const int ln = lane & 15, quad = lane >> 4;
  const int lr = w >> 1, mh = w & 1;
  const u16* wbase = wT + (size_t)((mh * 2) * 16 + ln) * 64 + quad * 8;
  __syncthreads();
  f32x4 acc[2][2];
#pragma unroll
  for (int m2 = 0; m2 < 2; ++m2)
#pragma unroll
    for (int nf = 0; nf < 2; ++nf) acc[m2][nf] = (f32x4){0.f, 0.f, 0.f, 0.f};
#pragma unroll 3
  for (int tap = 0; tap < 9; ++tap) {
    const int dy = tap / 3, dx = tap % 3;
    const int px0 = (lr + dy) * 34 + ln + dx;
    bf16x8 A[2][2];
#pragma unroll
    for (int m2 = 0; m2 < 2; ++m2)
#pragma unroll
      for (int h = 0; h < 2; ++h)
        A[m2][h] = *(const bf16x8*)&wbase[(size_t)(tap * 64 + m2 * 16) * 64 + h * 32];
#pragma unroll
    for (int h = 0; h < 2; ++h) {
      const int oct = h * 4 + quad;
      bf16x8 b0 = *(const bf16x8*)&shp[SWZ(px0, oct)];
      bf16x8 b1 = *(const bf16x8*)&shp[SWZ(px0 + 16, oct)];
      acc[0][0] = MFMA16(A[0][h], b0, acc[0][0]);
      acc[0][1] = MFMA16(A[0][h], b1, acc[0][1]);
      acc[1][0] = MFMA16(A[1][h], b0, acc[1][0]);
      acc[1][1] = MFMA16(A[1][h], b1, acc[1][1]);
    }
  }
  const int R = R0 + lr;
#pragma unroll
  for (int m2 = 0; m2 < 2; ++m2) {
    const int cob = (mh * 2 + m2) * 16 + quad * 4;
#pragma unroll
    for (int nf = 0; nf < 2; ++nf) {
      u16* tb = t + (size_t)b * IMST + (size_t)((R + 1) * 34 + nf * 16 + ln + 1) * 64 + cob;
      uint2 pk;
      pk.x = pk2(acc[m2][nf][0], acc[m2][nf][1]);
      pk.y = pk2(acc[m2][nf][2], acc[m2][nf][3]);
      *(uint2*)tb = pk;
    }
#pragma unroll
    for (int r = 0; r < 4; ++r) {
      float v0 = acc[m2][0][r], v1 = acc[m2][1][r];
      float s = row_reduce16(v0) + row_reduce16(v1);
      float q = row_reduce16(v0 * v0) + row_reduce16(v1 * v1);
      if (ln == 15) {
        atomicAdd(&sA[cob + r], s);
        atomicAdd(&qA[cob + r], q);
      }
    }
  }
  __syncthreads();
  const int blk = z * 1024 + blockIdx.y * 16 + blockIdx.x;
  if (tid < 64) pA[blk * 128 + tid] = sA[tid];
  else if (tid < 128) pA[blk * 128 + tid] = qA[tid - 64];
}

// reducerA (batched): grid (64, 2); writes s1/b1 into stBase + z*2048.
__global__ __launch_bounds__(256) void reducerA_k(const float* __restrict__ pA,
                                                  const float* __restrict__ a1,
                                                  float* __restrict__ stBase) {
  const int tid = threadIdx.x, c = blockIdx.x, z = blockIdx.y;
  const float* pAe = pA + (size_t)z * 1024 * 128;
  float s = 0.f, q = 0.f;
  for (int i = tid; i < 1024; i += 256) {
    s += pAe[i * 128 + c];
    q += pAe[i * 128 + 64 + c];
  }
#pragma unroll
  for (int off = 32; off; off >>= 1) { s += __shfl_xor(s, off); q += __shfl_xor(q, off); }
  __shared__ float red[8];
  int wv = tid >> 6;
  if ((tid & 63) == 0) { red[wv] = s; red[4 + wv] = q; }
  __syncthreads();
  if (tid == 0) {
    float S = red[0] + red[1] + red[2] + red[3];
    float Q = red[4] + red[5] + red[6] + red[7];
    int g = c >> 3;
    float m = 0.f;
    for (int i = g; i < 8; ++i) m += a1[i];
    float mu = S * (1.f / NRED);
    float var = Q * (1.f / NRED) - mu * mu;
    float r = rsqrtf(var + EPS);
    float* stE = stBase + z * 2048;
    stE[c] = r * m;
    stE[64 + c] = -mu * r * m;
  }
}

// ---------------- convC: 4-row tile, 8 waves, T14 async shA restage ----------
// grid (8, 64, 2): z = edge. Block 512 thr = 8 waves over 4 out rows x 32 cols.
// Patch 6x34 (26KB) staged once; shA(coq+1) global loads issued into regs
// BEFORE coq's compute (latency hidden under MFMA+stats), ds_write after the
// post-compute barrier. LDS 48.6KB. (512,4): r7's (512,6) forced 40-VGPR spill
// (WRITE_SIZE 40MB); (512,4) caps 128 -> clean 52-VGPR alloc (r8: 72.2us).
__global__ __launch_bounds__(512, 4) void convC_k(const u16* __restrict__ t0,
                                                  const u16* __restrict__ t1,
                                                  const u16* __restrict__ wG64,
                                                  const u16* __restrict__ wT8,
                                                  const float* __restrict__ stBase,
                                                  float* __restrict__ pC) {
  __shared__ __align__(16) u16 shp[PATCH6];       // 26112 B
  __shared__ __align__(16) u16 shA[64 * 16 * 8];  // 16384 B (one co-quarter)
  __shared__ __align__(16) u16 shA2[8 * 16 * 8];  // 2048 B
  __shared__ float sC[4][128], qC[4][128];        // 4096 B
  const int tid = threadIdx.x;
  const int b = blockIdx.y, R0 = blockIdx.x * 4;
  const int edge = blockIdx.z;
  const u16* t = edge ? t1 : t0;
  const float* stE = stBase + edge * 2048;
  const u16* wGe = wG64 + edge * 32768;
  const u16* wT8e = wT8 + edge * 4096;
  ((float*)sC)[tid] = 0.f;
  ((float*)qC)[tid] = 0.f;
  // ---- stage 6-row affine patch (1632 chunks, 512 threads) ----
  {
    const int oct0 = tid & 7;
    float sc[8], bc[8];
#pragma unroll
    for (int j = 0; j < 8; ++j) { sc[j] = stE[oct0 * 8 + j]; bc[j] = stE[64 + oct0 * 8 + j]; }
    const u16* src = t + (size_t)b * IMST + (size_t)R0 * 2176;
#pragma unroll
    for (int i = 0; i < 4; ++i) {
      int c = i * 512 + tid;
      if (i == 3 && tid >= 96) break;
      int px = c >> 3, oct = c & 7;
      int prow = px / 34, pcol = px - prow * 34;
      bool halo = (R0 + prow == 0) || (R0 + prow == 33) || (pcol == 0) || (pcol == 33);
      uint4 o = {0u, 0u, 0u, 0u};
      if (!halo) {
        uint4 u = *(const uint4*)&src[(size_t)c * 8];
        unsigned uv[4] = {u.x, u.y, u.z, u.w};
        unsigned rv[4];
#pragma unroll
        for (int p2 = 0; p2 < 4; ++p2) {
          float lo = bf2f((u16)(uv[p2] & 0xffff)) * sc[p2 * 2] + bc[p2 * 2];
          float hi = bf2f((u16)(uv[p2] >> 16)) * sc[p2 * 2 + 1] + bc[p2 * 2 + 1];
          rv[p2] = pk2(lo, hi);
        }
        o.x = rv[0]; o.y = rv[1]; o.z = rv[2]; o.w = rv[3];
      }
      *(uint4*)&shp[SWZ(px, oct)] = o;
    }
  }
  // ---- stage shA/shA2 for coq=0 (1024 chunks / 128 chunks) ----
#pragma unroll
  for (int i = 0; i < 2; ++i) {
    int c = i * 512 + tid;
    int row = c >> 4, col = c & 15;
    *(uint4*)&shA[c * 8] = *(const uint4*)&wGe[(size_t)(row * 64 + col) * 8];
  }
  if (tid < 128) {
    int g = tid >> 4, col = tid & 15;
    *(uint4*)&shA2[tid * 8] = *(const uint4*)&wT8e[(size_t)(g * 64 + col) * 8];
  }
  __syncthreads();
  const int lane = tid & 63, w = tid >> 6;
  const int ln = lane & 15, quad = lane >> 4;
  const int lrow = w >> 1, colbase = (w & 1) * 16;
  int px[3];
#pragma unroll
  for (int ch = 0; ch < 3; ++ch) {
    int tp = ch * 4 + quad; if (tp > 8) tp = 8;
    px[ch] = (lrow + tp / 3) * 34 + colbase + ln + tp % 3;
  }
#pragma unroll 1
  for (int coq = 0; coq < 4; ++coq) {
    // T14: issue next co-quarter's weight loads into regs before compute
    uint4 wr0, wr1, wr2;
    if (coq < 3) {
      const int nq = coq + 1;
      {
        int c = tid;
        wr0 = *(const uint4*)&wGe[(size_t)((c >> 4) * 64 + nq * 16 + (c & 15)) * 8];
      }
      {
        int c = 512 + tid;
        wr1 = *(const uint4*)&wGe[(size_t)((c >> 4) * 64 + nq * 16 + (c & 15)) * 8];
      }
      if (tid < 128)
        wr2 = *(const uint4*)&wT8e[(size_t)((tid >> 4) * 64 + nq * 16 + (tid & 15)) * 8];
    }
    f32x4 acc[8];
#pragma unroll
    for (int g = 0; g < 8; ++g) acc[g] = (f32x4){0.f, 0.f, 0.f, 0.f};
#pragma unroll
    for (int g = 0; g < 8; ++g) {
#pragma unroll
      for (int ch = 0; ch < 3; ++ch) {
        bf16x8 bx = *(const bf16x8*)&shp[SWZ(px[ch], g)];
        bf16x8 aw;
        if (ch < 2) {
          aw = *(const bf16x8*)&shA[((g * 8 + ch * 4 + quad) * 16 + ln) * 8];
        } else {
          aw = (bf16x8){0, 0, 0, 0, 0, 0, 0, 0};
          if (quad == 0) aw = *(const bf16x8*)&shA2[(g * 16 + ln) * 8];
        }
        acc[g] = MFMA16(aw, bx, acc[g]);
      }
    }
    f32x4 P = (f32x4){0.f, 0.f, 0.f, 0.f};
#pragma unroll
    for (int k = 0; k < 8; ++k) {
      P += acc[k];
#pragma unroll
      for (int r = 0; r < 4; ++r) {
        float v = P[r];
        float s = row_reduce16(v);
        float q = row_reduce16(v * v);
        if (ln == 15) {
          atomicAdd(&sC[coq][k * 16 + quad * 4 + r], s);
          atomicAdd(&qC[coq][k * 16 + quad * 4 + r], q);
        }
      }
    }
    __syncthreads();  // all reads of shA/shA2 for this coq done
    if (coq < 3) {    // write prefetched regs -> LDS
      *(uint4*)&shA[(size_t)tid * 8] = wr0;
      *(uint4*)&shA[(size_t)(512 + tid) * 8] = wr1;
      if (tid < 128) *(uint4*)&shA2[tid * 8] = wr2;
      __syncthreads();
    }
  }
  __syncthreads();
  const int blk = blockIdx.y * 8 + blockIdx.x;  // 0..511
#pragma unroll 1
  for (int coq = 0; coq < 4; ++coq) {
    const size_t base = ((size_t)(edge * 4 + coq) * 512 + blk) * 256;
    if (tid < 128) pC[base + tid] = sC[coq][tid];
    else if (tid < 256) pC[base + 128 + (tid - 128)] = qC[coq][tid - 128];
  }
}

// redCprepE (batched): grid (64, 2): c, z(edge). finalizeC + fold g -> wE.
__global__ __launch_bounds__(256) void redCprepE_k(const float* __restrict__ pC,
                                                   const float* __restrict__ w2a,
                                                   const float* __restrict__ w2b,
                                                   const float* __restrict__ a1,
                                                   const float* __restrict__ a2,
                                                   float* __restrict__ stBase,
                                                   u16* __restrict__ wEbase,
                                                   float* __restrict__ cm) {
  const int tid = threadIdx.x, c = blockIdx.x, z = blockIdx.y;
  const int coq = c >> 4, cl = c & 15;
  const float* w2 = z ? w2b : w2a;
  float* stE = stBase + z * 2048;
  u16* wE = wEbase + z * 36864;
  float s[8], q[8];
#pragma unroll
  for (int k = 0; k < 8; ++k) { s[k] = 0.f; q[k] = 0.f; }
  for (int i = tid; i < 512; i += 256) {
    const float* pb = pC + ((size_t)(z * 4 + coq) * 512 + i) * 256;
#pragma unroll
    for (int k = 0; k < 8; ++k) {
      s[k] += pb[k * 16 + cl];
      q[k] += pb[128 + k * 16 + cl];
    }
  }
#pragma unroll
  for (int k = 0; k < 8; ++k) {
#pragma unroll
    for (int off = 32; off; off >>= 1) { s[k] += __shfl_xor(s[k], off); q[k] += __shfl_xor(q[k], off); }
  }
  __shared__ float red[4][16];
  __shared__ float gL[8];
  int wv = tid >> 6;
  if ((tid & 63) == 0) {
#pragma unroll
    for (int k = 0; k < 8; ++k) { red[wv][k * 2] = s[k]; red[wv][k * 2 + 1] = q[k]; }
  }
  __syncthreads();
  if (tid == 0) {
    float suf = 0.f, bias = 0.f;
    for (int k = 7; k >= 0; --k) {
      float S = red[0][k * 2] + red[1][k * 2] + red[2][k * 2] + red[3][k * 2];
      float Q = red[0][k * 2 + 1] + red[1][k * 2 + 1] + red[2][k * 2 + 1] + red[3][k * 2 + 1];
      float mu = S * (1.f / NRED);
      float var = Q * (1.f / NRED) - mu * mu;
      float rr = rsqrtf(var + EPS);
      bias -= a2[k] * mu * rr;
      suf += a2[k] * rr;
      gL[k] = suf;
    }
    stE[128 + c] = bias;
    if (z == 0) {
      int g = c >> 3;
      float m1 = 0.f, m2 = 0.f;
      for (int i = g; i < 8; ++i) { m1 += a1[i]; m2 += a2[i]; }
      cm[c] = m1 * m2;
    }
  }
  __syncthreads();
  for (int idx = tid; idx < 576; idx += 256) {
    int tap = idx >> 6, ci = idx & 63;
    wE[(tap * 64 + c) * 64 + ci] = f2bf(w2[(c * 64 + ci) * 9 + tap] * gL[ci >> 3]);
  }
}

// ---------------- convE (modes 0,1): conv2 + epilogue ------------------------
// A-fragments streamed from global per tap (same coalesced layout as convA).
// MODE 1: n1T pool neighborhood (4x34x64, halo strips already zeroed in mem)
// staged raw into LDS shn -> 36 scattered 8B global gathers per thread become
// LDS reads (latency attack; the gathers were 128B-stride, 1/16 line use).
template <int MODE>
__global__ __launch_bounds__(256, 4) void convE_k(const u16* __restrict__ t,
                                                  const float* __restrict__ stE,
                                                  const u16* __restrict__ wEp,
                                                  u16* __restrict__ d1,
                                                  u16* __restrict__ d2,
                                                  const float* __restrict__ cm) {
  __shared__ __align__(16) u16 shp[PATCH];
  __shared__ __align__(16) u16 shn[MODE == 1 ? PATCH : 8];
  __shared__ float cmL[64], biasL[64];
  const int tid = threadIdx.x;
  const int b = blockIdx.y, R0 = blockIdx.x * 2;
  if (tid < 64) { cmL[tid] = cm[tid]; biasL[tid] = stE[128 + tid]; }
  stage_affine(t + (size_t)b * IMST + (size_t)R0 * 2176, shp, tid, R0, stE);
  if constexpr (MODE == 1) {
    // raw copy of n1T rows R0..R0+3 (halo coords), cols 0..33: values incl.
    // zeroed halo strips are already correct in memory.
    const u16* nsrc = d2 + (size_t)b * IMST + (size_t)R0 * 2176;
#pragma unroll
    for (int i = 0; i < 5; ++i) {
      int c = i * 256 + tid;
      if (i == 4 && tid >= 64) break;
      int px = c >> 3, oct = c & 7;
      *(uint4*)&shn[SWZ(px, oct)] = *(const uint4*)&nsrc[(size_t)c * 8];
    }
  }
  const int lane = tid & 63, w = tid >> 6;
  const int ln = lane & 15, quad = lane >> 4;
  const int lr = w >> 1, mh = w & 1;
  const u16* wbase = wEp + (size_t)((mh * 2) * 16 + ln) * 64 + quad * 8;
  __syncthreads();
  f32x4 acc[2][2];
#pragma unroll
  for (int m2 = 0; m2 < 2; ++m2)
#pragma unroll
    for (int nf = 0; nf < 2; ++nf) acc[m2][nf] = (f32x4){0.f, 0.f, 0.f, 0.f};
#pragma unroll 3
  for (int tap = 0; tap < 9; ++tap) {
    const int dy = tap / 3, dx = tap % 3;
    const int px0 = (lr + dy) * 34 + ln + dx;
    bf16x8 A[2][2];
#pragma unroll
    for (int m2 = 0; m2 < 2; ++m2)
#pragma unroll
      for (int h = 0; h < 2; ++h)
        A[m2][h] = *(const bf16x8*)&wbase[(size_t)(tap * 64 + m2 * 16) * 64 + h * 32];
#pragma unroll
    for (int h = 0; h < 2; ++h) {
      const int oct = h * 4 + quad;
      bf16x8 b0 = *(const bf16x8*)&shp[SWZ(px0, oct)];
      bf16x8 b1 = *(const bf16x8*)&shp[SWZ(px0 + 16, oct)];
      acc[0][0] = MFMA16(A[0][h], b0, acc[0][0]);
      acc[0][1] = MFMA16(A[0][h], b1, acc[0][1]);
      acc[1][0] = MFMA16(A[1][h], b0, acc[1][0]);
      acc[1][1] = MFMA16(A[1][h], b1, acc[1][1]);
    }
  }
  const int R = R0 + lr;
#pragma unroll
  for (int m2 = 0; m2 < 2; ++m2) {
    const int cob = (mh * 2 + m2) * 16 + quad * 4;
#pragma unroll
    for (int nf = 0; nf < 2; ++nf) {
      const int C = nf * 16 + ln;
      const size_t haloPx = (size_t)b * IMST + (size_t)((R + 1) * 34 + C + 1) * 64 + cob;
      float v[4];
#pragma unroll
      for (int r = 0; r < 4; ++r) v[r] = acc[m2][nf][r] + biasL[cob + r];
      if (MODE == 0) {
        uint2 pk, pkr;
        pk.x = pk2(v[0], v[1]); pk.y = pk2(v[2], v[3]);
        pkr.x = pk2(fmaxf(v[0], 0.f), fmaxf(v[1], 0.f));
        pkr.y = pk2(fmaxf(v[2], 0.f), fmaxf(v[3], 0.f));
        *(uint2*)&d1[haloPx] = pk;    // n1T (raw, for pool)
        *(uint2*)&d2[haloPx] = pkr;   // n1r (relu, e2 input)
      } else {
        float ps[4] = {0.f, 0.f, 0.f, 0.f};
#pragma unroll
        for (int dy = 0; dy < 3; ++dy)
#pragma unroll
          for (int dx = 0; dx < 3; ++dx) {
            // halo-local: patch row lr+dy (0..3), col C+dx (0..33)
            const int ppx = (lr + dy) * 34 + C + dx;
            uint2 u = *(const uint2*)&shn[SWZ(ppx, cob >> 3) + (cob & 7)];
            ps[0] += bf2f((u16)(u.x & 0xffff));
            ps[1] += bf2f((u16)(u.x >> 16));
            ps[2] += bf2f((u16)(u.y & 0xffff));
            ps[3] += bf2f((u16)(u.y >> 16));
          }
        float rows = 3.f - (R == 0 ? 1.f : 0.f) - (R == 31 ? 1.f : 0.f);
        float cols = 3.f - (C == 0 ? 1.f : 0.f) - (C == 31 ? 1.f : 0.f);
        float inv = 1.f / (rows * cols);
        uint2 pkr;
        float t0v = fmaxf(v[0] + ps[0] * inv * cmL[cob], 0.f);
        float t1v = fmaxf(v[1] + ps[1] * inv * cmL[cob + 1], 0.f);
        float t2v = fmaxf(v[2] + ps[2] * inv * cmL[cob + 2], 0.f);
        float t3v = fmaxf(v[3] + ps[3] * inv * cmL[cob + 3], 0.f);
        pkr.x = pk2(t0v, t1v); pkr.y = pk2(t2v, t3v);
        *(uint2*)&d1[haloPx] = pkr;   // n2r
      }
    }
  }
}

// ---------------- convE23: fused final two convs + output --------------------
__global__ __launch_bounds__(256, 4) void convE23_k(const u16* __restrict__ t0,
                                                    const u16* __restrict__ t1,
                                                    const float* __restrict__ stBase,
                                                    const u16* __restrict__ wE2,
                                                    const u16* __restrict__ wE3,
                                                    float* __restrict__ outp,
                                                    const float* __restrict__ x,
                                                    const float* __restrict__ cm) {
  __shared__ __align__(16) u16 shp2[2 * PATCH];
  __shared__ float cmL[64], biasL[64];
  const int tid = threadIdx.x;
  const int b = blockIdx.y, R0 = blockIdx.x * 2;
  if (tid < 64) {
    cmL[tid] = cm[tid];
    biasL[tid] = stBase[128 + tid] + stBase[2048 + 128 + tid];
  }
  stage_affine(t0 + (size_t)b * IMST + (size_t)R0 * 2176, shp2, tid, R0, stBase);
  stage_affine(t1 + (size_t)b * IMST + (size_t)R0 * 2176, shp2 + PATCH, tid, R0, stBase + 2048);
  __syncthreads();
  const int lane = tid & 63, w = tid >> 6;
  const int ln = lane & 15, quad = lane >> 4;
  const int lr = w >> 1, mh = w & 1;
  f32x4 acc[2][2];
#pragma unroll
  for (int m2 = 0; m2 < 2; ++m2)
#pragma unroll
    for (int nf = 0; nf < 2; ++nf) acc[m2][nf] = (f32x4){0.f, 0.f, 0.f, 0.f};
#pragma unroll 1
  for (int ei = 0; ei < 2; ++ei) {
    const u16* wEp = ei ? wE3 : wE2;
    const u16* sp = &shp2[ei * PATCH];
    const u16* wbase = wEp + (size_t)((mh * 2) * 16 + ln) * 64 + quad * 8;
#pragma unroll 3
    for (int tap = 0; tap < 9; ++tap) {
      const int dy = tap / 3, dx = tap % 3;
      const int px0 = (lr + dy) * 34 + ln + dx;
      bf16x8 A[2][2];
#pragma unroll
      for (int m2 = 0; m2 < 2; ++m2)
#pragma unroll
        for (int h = 0; h < 2; ++h)
          A[m2][h] = *(const bf16x8*)&wbase[(size_t)(tap * 64 + m2 * 16) * 64 + h * 32];
#pragma unroll
      for (int h = 0; h < 2; ++h) {
        const int oct = h * 4 + quad;
        bf16x8 b0 = *(const bf16x8*)&sp[SWZ(px0, oct)];
        bf16x8 b1 = *(const bf16x8*)&sp[SWZ(px0 + 16, oct)];
        acc[0][0] = MFMA16(A[0][h], b0, acc[0][0]);
        acc[0][1] = MFMA16(A[0][h], b1, acc[0][1]);
        acc[1][0] = MFMA16(A[1][h], b0, acc[1][0]);
        acc[1][1] = MFMA16(A[1][h], b1, acc[1][1]);
      }
    }
  }
  const int R = R0 + lr;
#pragma unroll
  for (int m2 = 0; m2 < 2; ++m2) {
    const int cob = (mh * 2 + m2) * 16 + quad * 4;
#pragma unroll
    for (int nf = 0; nf < 2; ++nf) {
      const int C = nf * 16 + ln;
      size_t base = (size_t)b * 65536 + (size_t)cob * 1024 + R * 32 + C;
#pragma unroll
      for (int r = 0; r < 4; ++r)
        outp[base + (size_t)r * 1024] =
            acc[m2][nf][r] + biasL[cob + r] + x[base + (size_t)r * 1024] * cmL[cob + r];
    }
  }
}

extern "C" void kernel_launch(void* const* d_in, const int* in_sizes, int n_in,
                              void* d_out, int out_size, void* d_ws, size_t ws_size,
                              hipStream_t stream) {
  const float* x  = (const float*)d_in[0];
  const float* a1 = (const float*)d_in[1];
  const float* a2 = (const float*)d_in[2];
  const float* W1[4] = {(const float*)d_in[3], (const float*)d_in[5],
                        (const float*)d_in[7], (const float*)d_in[9]};
  const float* W2[4] = {(const float*)d_in[4], (const float*)d_in[6],
                        (const float*)d_in[8], (const float*)d_in[10]};
  float* out = (float*)d_out;
  char* ws = (char*)d_ws;
  const size_t HB = (size_t)IMST * 64 * 2;  // 9,469,952 B per halo buffer
  u16* xT  = (u16*)ws;
  u16* t0  = (u16*)(ws + HB);
  u16* t1  = (u16*)(ws + 2 * HB);
  u16* n1T = (u16*)(ws + 3 * HB);
  u16* n1r = (u16*)(ws + 4 * HB);
  u16* n2r = (u16*)(ws + 5 * HB);
  char* p = ws + 6 * HB;
  float* st  = (float*)p;            p += 8256 * 4;
  u16* wT1   = (u16*)p;              p += 4 * 36864 * 2;
  u16* wG64  = (u16*)p;              p += 4 * 32768 * 2;
  u16* wT8   = (u16*)p;              p += 4 * 4096 * 2;
  u16* wE    = (u16*)p;              p += 4 * 36864 * 2;
  float* pA  = (float*)p;            p += 2 * 1024 * 128 * 4;
  float* pC  = (float*)p;            // 8 * 512 * 256 * 4 = 4 MB
  float* cm  = st + 8192;

  pack_wT1_k<<<36, 256, 0, stream>>>(W1[0], W1[1], W1[2], W1[3], wT1);
  pack_wG_k<<<dim3(72, 4), 256, 0, stream>>>(W2[0], W2[1], W2[2], W2[3], wG64, wT8);
  transpose_k<<<1024, 256, 0, stream>>>(x, xT);
  zero_halo_k<<<64, 160, 0, stream>>>(n1T);

  dim3 gA(16, 64, 2), gC(8, 64, 2), gE(16, 64);
  // batch edges 0+1 (both consume xT)
  convA_k<<<gA, 256, 0, stream>>>(xT, xT, wT1, wT1 + 36864, t0, t1, pA);
  reducerA_k<<<dim3(64, 2), 256, 0, stream>>>(pA, a1, st);
  convC_k<<<gC, 512, 0, stream>>>(t0, t1, wG64, wT8, st, pC);
  redCprepE_k<<<dim3(64, 2), 256, 0, stream>>>(pC, W2[0], W2[1], a1, a2, st, wE, cm);
  convE_k<0><<<gE, 256, 0, stream>>>(t0, st, wE, n1T, n1r, cm);
  convE_k<1><<<gE, 256, 0, stream>>>(t1, st + 2048, wE + 36864, n2r, n1T, cm);
  // batch edges 2+3 (consume n1r, n2r)
  convA_k<<<gA, 256, 0, stream>>>(n1r, n2r, wT1 + 2 * 36864, wT1 + 3 * 36864, t0, t1, pA);
  reducerA_k<<<dim3(64, 2), 256, 0, stream>>>(pA, a1, st + 4096);
  convC_k<<<gC, 512, 0, stream>>>(t0, t1, wG64 + 2 * 32768, wT8 + 2 * 4096, st + 4096, pC);
  redCprepE_k<<<dim3(64, 2), 256, 0, stream>>>(pC, W2[2], W2[3], a1, a2, st + 4096,
                                               wE + 2 * 36864, cm);
  convE23_k<<<gE, 256, 0, stream>>>(t0, t1, st + 4096, wE + 2 * 36864, wE + 3 * 36864,
                                    out, x, cm);
}